// Round 1
// baseline (512.126 us; speedup 1.0000x reference)
//
#include <hip/hip_runtime.h>
#include <hip/hip_bf16.h>

#define B_   2
#define T_   2048
#define D_   2048
#define H_   16
#define DH_  128
#define TD3_ 6144   // 3*D

typedef __attribute__((ext_vector_type(8))) short   short8;
typedef __attribute__((ext_vector_type(4))) float   f32x4;
typedef __attribute__((ext_vector_type(4))) float   f4v;
typedef __attribute__((ext_vector_type(4))) unsigned short u16x4;

static __device__ __forceinline__ unsigned short f2bf(float f) {
  unsigned int u = __builtin_bit_cast(unsigned int, f);
  u += 0x7FFFu + ((u >> 16) & 1u);
  return (unsigned short)(u >> 16);
}

static __device__ __forceinline__ void gload_lds16(const unsigned short* g, unsigned short* l) {
  __builtin_amdgcn_global_load_lds((const __attribute__((address_space(1))) void*)g,
                                   (__attribute__((address_space(3))) void*)l, 16, 0, 0);
}

// ---------------- fp32 -> bf16 elementwise cast (vectorized) ----------------
__global__ __launch_bounds__(256) void convert_f32_bf16(const float* __restrict__ X,
                                                        unsigned short* __restrict__ Y, int n4) {
  for (int i = blockIdx.x * blockDim.x + threadIdx.x; i < n4; i += gridDim.x * blockDim.x) {
    f4v v = ((const f4v*)X)[i];
    u16x4 o;
    o[0] = f2bf(v[0]); o[1] = f2bf(v[1]); o[2] = f2bf(v[2]); o[3] = f2bf(v[3]);
    ((u16x4*)Y)[i] = o;
  }
}

// ---------------- transpose fp32 [K][N] -> bf16 [N][K] ----------------
__global__ __launch_bounds__(256) void transpose_f32_bf16(const float* __restrict__ W,
                                                          unsigned short* __restrict__ WT,
                                                          int K, int N) {
  __shared__ float tile[32][33];
  int n0 = blockIdx.x * 32, k0 = blockIdx.y * 32;
  int tx = threadIdx.x & 31, ty = threadIdx.x >> 5;   // ty 0..7
#pragma unroll
  for (int r = 0; r < 4; r++)
    tile[ty + 8 * r][tx] = W[(size_t)(k0 + ty + 8 * r) * N + n0 + tx];
  __syncthreads();
#pragma unroll
  for (int r = 0; r < 4; r++)
    WT[(size_t)(n0 + ty + 8 * r) * K + k0 + tx] = f2bf(tile[tx][ty + 8 * r]);
}

// ---------------- bf16 GEMM: C[M][N] = A[M][K] * BT[N][K]^T ----------------
// m97 structure: 128x128 tile, BK=64, 256 threads (4 waves, 2x2), global_load_lds w=16
template <int OUTBF>
__global__ __launch_bounds__(256) void gemm_bt(const unsigned short* __restrict__ A,
                                               const unsigned short* __restrict__ BT,
                                               void* __restrict__ C, int M, int N, int K) {
  __shared__ unsigned short lA[128 * 64];
  __shared__ unsigned short lB[128 * 64];
  const int tid = threadIdx.x;
  const int m0 = blockIdx.y * 128, n0 = blockIdx.x * 128;
  const int w = tid >> 6, l = tid & 63, lr = l & 15, lg = l >> 4;
  const int wm = w >> 1, wn = w & 1;
  f32x4 acc[4][4] = {};

  const int sr = tid >> 3;        // 0..31 (row within 32-row chunk)
  const int sc = (tid & 7) * 8;   // col (elements)

  for (int kt = 0; kt < K; kt += 64) {
    __syncthreads();   // previous compute done before overwriting LDS
#pragma unroll
    for (int c = 0; c < 4; c++) {
      const int row = c * 32 + sr;
      gload_lds16(A  + (size_t)(m0 + row) * K + kt + sc, &lA[row * 64 + sc]);
      gload_lds16(BT + (size_t)(n0 + row) * K + kt + sc, &lB[row * 64 + sc]);
    }
    __syncthreads();   // staged (compiler drains vmcnt before barrier)
#pragma unroll
    for (int kk = 0; kk < 2; kk++) {
      short8 af[4], bfr[4];
#pragma unroll
      for (int mi = 0; mi < 4; mi++)
        af[mi] = *(const short8*)&lA[(wm * 64 + mi * 16 + lr) * 64 + kk * 32 + lg * 8];
#pragma unroll
      for (int ni = 0; ni < 4; ni++)
        bfr[ni] = *(const short8*)&lB[(wn * 64 + ni * 16 + lr) * 64 + kk * 32 + lg * 8];
#pragma unroll
      for (int mi = 0; mi < 4; mi++)
#pragma unroll
        for (int ni = 0; ni < 4; ni++)
          acc[mi][ni] = __builtin_amdgcn_mfma_f32_16x16x32_bf16(af[mi], bfr[ni], acc[mi][ni], 0, 0, 0);
    }
  }

#pragma unroll
  for (int mi = 0; mi < 4; mi++)
#pragma unroll
    for (int ni = 0; ni < 4; ni++)
#pragma unroll
      for (int i = 0; i < 4; i++) {
        const int row = m0 + wm * 64 + mi * 16 + lg * 4 + i;
        const int col = n0 + wn * 64 + ni * 16 + lr;
        if (OUTBF) ((unsigned short*)C)[(size_t)row * N + col] = f2bf(acc[mi][ni][i]);
        else       ((float*)C)[(size_t)row * N + col] = acc[mi][ni][i];
      }
}

// ---------------- flash attention (causal), bf16 in/out ----------------
// grid (T/64, H, B), 256 threads = 4 waves, each wave owns 16 q-rows.
__global__ __launch_bounds__(256) void attn_fa(const unsigned short* __restrict__ qkv,
                                               unsigned short* __restrict__ out) {
  const int qt = blockIdx.x, h = blockIdx.y, b = blockIdx.z;
  const int q0 = qt * 64;
  const int tid = threadIdx.x, w = tid >> 6, l = tid & 63, lr = l & 15, lg = l >> 4;

  const unsigned short* Qb = qkv + (size_t)b * T_ * TD3_ + h * DH_;
  const unsigned short* Kb = Qb + D_;
  const unsigned short* Vb = Qb + 2 * D_;

  __shared__ unsigned short vt[128 * 72];        // V^T, block-rotation swizzled
  __shared__ unsigned short plds[4 * 16 * 72];   // per-wave P tiles, padded stride 72

  // Q fragments for this wave's 16 rows (full DH=128 -> 4 k-chunks)
  short8 qf[4];
  {
    const unsigned short* qrow = Qb + (size_t)(q0 + w * 16 + lr) * TD3_;
#pragma unroll
    for (int ks = 0; ks < 4; ks++)
      qf[ks] = *(const short8*)(qrow + ks * 32 + lg * 8);
  }

  f32x4 oacc[8] = {};
  float mrun[4], lsum[4];
#pragma unroll
  for (int i = 0; i < 4; i++) { mrun[i] = -__builtin_inff(); lsum[i] = 0.f; }
  const float scale = 0.08838834764831845f;   // 1/sqrt(128)

  const int ntiles = q0 / 64 + 1;
  for (int t = 0; t < ntiles; t++) {
    const int kv0 = t * 64;
    const bool diag = (kv0 == q0);

    // ---- stage V^T into LDS (rotation swizzle breaks 8-row write conflicts) ----
    __syncthreads();
#pragma unroll
    for (int it = 0; it < 4; it++) {
      const int idx = it * 256 + tid;       // 0..1023
      const int kv  = idx >> 4;             // 0..63
      const int dh0 = (idx & 15) << 3;      // 0..120
      short8 vv = *(const short8*)(Vb + (size_t)(kv0 + kv) * TD3_ + dh0);
      const int blkw = ((kv >> 3) + (dh0 >> 3)) & 7;
      const int colw = blkw * 8 + (kv & 7);
#pragma unroll
      for (int j = 0; j < 8; j++) vt[(dh0 + j) * 72 + colw] = (unsigned short)vv[j];
    }
    __syncthreads();

    // ---- S = Q K^T (K fragments direct from global; L2-served) ----
    f32x4 s[4] = {};
#pragma unroll
    for (int nf = 0; nf < 4; nf++) {
      const unsigned short* krow = Kb + (size_t)(kv0 + nf * 16 + lr) * TD3_;
#pragma unroll
      for (int ks = 0; ks < 4; ks++) {
        short8 kf = *(const short8*)(krow + ks * 32 + lg * 8);
        s[nf] = __builtin_amdgcn_mfma_f32_16x16x32_bf16(qf[ks], kf, s[nf], 0, 0, 0);
      }
    }

    // ---- scale + causal mask + online softmax ----
    float sv[4][4];
    float pmax[4];
#pragma unroll
    for (int i = 0; i < 4; i++) pmax[i] = -__builtin_inff();
#pragma unroll
    for (int nf = 0; nf < 4; nf++)
#pragma unroll
      for (int i = 0; i < 4; i++) {
        float x = s[nf][i] * scale;
        if (diag) {
          const int qr = w * 16 + lg * 4 + i;   // row rel. to q0
          const int kc = nf * 16 + lr;          // col rel. to kv0
          if (kc > qr) x = -__builtin_inff();
        }
        sv[nf][i] = x;
        pmax[i] = fmaxf(pmax[i], x);
      }
#pragma unroll
    for (int m = 1; m < 16; m <<= 1)
#pragma unroll
      for (int i = 0; i < 4; i++) pmax[i] = fmaxf(pmax[i], __shfl_xor(pmax[i], m));

    float alpha[4], rsum[4];
#pragma unroll
    for (int i = 0; i < 4; i++) {
      const float mn = fmaxf(mrun[i], pmax[i]);
      alpha[i] = __expf(mrun[i] - mn);
      mrun[i] = mn;
      rsum[i] = 0.f;
    }
#pragma unroll
    for (int nf = 0; nf < 4; nf++)
#pragma unroll
      for (int i = 0; i < 4; i++) {
        const float p = __expf(sv[nf][i] - mrun[i]);
        rsum[i] += p;
        plds[(w * 16 + lg * 4 + i) * 72 + nf * 16 + lr] = f2bf(p);
      }
#pragma unroll
    for (int m = 1; m < 16; m <<= 1)
#pragma unroll
      for (int i = 0; i < 4; i++) rsum[i] += __shfl_xor(rsum[i], m);
#pragma unroll
    for (int i = 0; i < 4; i++) lsum[i] = lsum[i] * alpha[i] + rsum[i];
#pragma unroll
    for (int nf = 0; nf < 8; nf++)
#pragma unroll
      for (int i = 0; i < 4; i++) oacc[nf][i] *= alpha[i];

    __syncthreads();   // P visible (also orders vt reuse across waves)

    // ---- O += P V ----
#pragma unroll
    for (int kk = 0; kk < 2; kk++) {
      const short8 pa = *(const short8*)&plds[(w * 16 + lr) * 72 + kk * 32 + lg * 8];
#pragma unroll
      for (int nf = 0; nf < 8; nf++) {
        const int dh = nf * 16 + lr;
        const int blkr = ((kk * 4 + lg) + (dh >> 3)) & 7;
        const short8 vb = *(const short8*)&vt[dh * 72 + blkr * 8];
        oacc[nf] = __builtin_amdgcn_mfma_f32_16x16x32_bf16(pa, vb, oacc[nf], 0, 0, 0);
      }
    }
  }

  // ---- normalize + write bf16 [b][t][h][dh] ----
  unsigned short* orow = out + ((size_t)b * T_ + q0 + w * 16) * D_ + h * DH_;
#pragma unroll
  for (int nf = 0; nf < 8; nf++)
#pragma unroll
    for (int i = 0; i < 4; i++)
      orow[(size_t)(lg * 4 + i) * D_ + nf * 16 + lr] = f2bf(oacc[nf][i] / lsum[i]);
}

extern "C" void kernel_launch(void* const* d_in, const int* in_sizes, int n_in,
                              void* d_out, int out_size, void* d_ws, size_t ws_size,
                              hipStream_t stream) {
  const float* x    = (const float*)d_in[0];
  const float* wqkv = (const float*)d_in[1];
  const float* wo   = (const float*)d_in[2];
  float* out = (float*)d_out;

  char* ws = (char*)d_ws;
  unsigned short* xb     = (unsigned short*)(ws);               // 16.8 MB (reused as attn out)
  unsigned short* wqkvt  = (unsigned short*)(ws + 16777216);    // 25.2 MB
  unsigned short* wot    = (unsigned short*)(ws + 41943040);    //  8.4 MB
  unsigned short* qkv    = (unsigned short*)(ws + 50331648);    // 50.3 MB
  unsigned short* attn   = xb;   // xb is dead after GEMM1

  convert_f32_bf16<<<2048, 256, 0, stream>>>(x, xb, B_ * T_ * D_ / 4);
  transpose_f32_bf16<<<dim3(TD3_ / 32, D_ / 32), 256, 0, stream>>>(wqkv, wqkvt, D_, TD3_);
  transpose_f32_bf16<<<dim3(D_ / 32, D_ / 32), 256, 0, stream>>>(wo, wot, D_, D_);

  gemm_bt<1><<<dim3(TD3_ / 128, (B_ * T_) / 128), 256, 0, stream>>>(xb, wqkvt, qkv,
                                                                    B_ * T_, TD3_, D_);
  attn_fa<<<dim3(T_ / 64, H_, B_), 256, 0, stream>>>(qkv, attn);
  gemm_bt<0><<<dim3(D_ / 128, (B_ * T_) / 128), 256, 0, stream>>>(attn, wot, out,
                                                                  B_ * T_, D_, D_);
}

// Round 2
// 398.396 us; speedup vs baseline: 1.2855x; 1.2855x over previous
//
#include <hip/hip_runtime.h>
#include <hip/hip_bf16.h>

#define B_   2
#define T_   2048
#define D_   2048
#define H_   16
#define DH_  128
#define TD3_ 6144   // 3*D

typedef __attribute__((ext_vector_type(8))) short   short8;
typedef __attribute__((ext_vector_type(8))) unsigned short ushort8v;
typedef __attribute__((ext_vector_type(4))) float   f32x4;
typedef __attribute__((ext_vector_type(4))) float   f4v;
typedef __attribute__((ext_vector_type(4))) unsigned short u16x4;

static __device__ __forceinline__ unsigned short f2bf(float f) {
  unsigned int u = __builtin_bit_cast(unsigned int, f);
  u += 0x7FFFu + ((u >> 16) & 1u);
  return (unsigned short)(u >> 16);
}
static __device__ __forceinline__ float bf2f(unsigned short u) {
  return __builtin_bit_cast(float, (unsigned int)u << 16);
}

static __device__ __forceinline__ void gload_lds16(const unsigned short* g, unsigned short* l) {
  __builtin_amdgcn_global_load_lds((const __attribute__((address_space(1))) void*)g,
                                   (__attribute__((address_space(3))) void*)l, 16, 0, 0);
}

// ---------------- fp32 -> bf16 elementwise cast (vectorized) ----------------
__global__ __launch_bounds__(256) void convert_f32_bf16(const float* __restrict__ X,
                                                        unsigned short* __restrict__ Y, int n4) {
  for (int i = blockIdx.x * blockDim.x + threadIdx.x; i < n4; i += gridDim.x * blockDim.x) {
    f4v v = ((const f4v*)X)[i];
    u16x4 o;
    o[0] = f2bf(v[0]); o[1] = f2bf(v[1]); o[2] = f2bf(v[2]); o[3] = f2bf(v[3]);
    ((u16x4*)Y)[i] = o;
  }
}

// ---------------- transpose fp32 [K][N] -> bf16 [N][K] ----------------
__global__ __launch_bounds__(256) void transpose_f32_bf16(const float* __restrict__ W,
                                                          unsigned short* __restrict__ WT,
                                                          int K, int N) {
  __shared__ float tile[32][33];
  int n0 = blockIdx.x * 32, k0 = blockIdx.y * 32;
  int tx = threadIdx.x & 31, ty = threadIdx.x >> 5;   // ty 0..7
#pragma unroll
  for (int r = 0; r < 4; r++)
    tile[ty + 8 * r][tx] = W[(size_t)(k0 + ty + 8 * r) * N + n0 + tx];
  __syncthreads();
#pragma unroll
  for (int r = 0; r < 4; r++)
    WT[(size_t)(n0 + ty + 8 * r) * K + k0 + tx] = f2bf(tile[tx][ty + 8 * r]);
}

// ---------------- bf16 GEMM: C[M][N] = A[M][K] * BT[N][K]^T ----------------
template <int OUTBF>
__global__ __launch_bounds__(256) void gemm_bt(const unsigned short* __restrict__ A,
                                               const unsigned short* __restrict__ BT,
                                               void* __restrict__ C, int M, int N, int K) {
  __shared__ unsigned short lA[128 * 64];
  __shared__ unsigned short lB[128 * 64];
  const int tid = threadIdx.x;
  const int m0 = blockIdx.y * 128, n0 = blockIdx.x * 128;
  const int w = tid >> 6, l = tid & 63, lr = l & 15, lg = l >> 4;
  const int wm = w >> 1, wn = w & 1;
  f32x4 acc[4][4] = {};

  const int sr = tid >> 3;
  const int sc = (tid & 7) * 8;

  for (int kt = 0; kt < K; kt += 64) {
    __syncthreads();
#pragma unroll
    for (int c = 0; c < 4; c++) {
      const int row = c * 32 + sr;
      gload_lds16(A  + (size_t)(m0 + row) * K + kt + sc, &lA[row * 64 + sc]);
      gload_lds16(BT + (size_t)(n0 + row) * K + kt + sc, &lB[row * 64 + sc]);
    }
    __syncthreads();
#pragma unroll
    for (int kk = 0; kk < 2; kk++) {
      short8 af[4], bfr[4];
#pragma unroll
      for (int mi = 0; mi < 4; mi++)
        af[mi] = *(const short8*)&lA[(wm * 64 + mi * 16 + lr) * 64 + kk * 32 + lg * 8];
#pragma unroll
      for (int ni = 0; ni < 4; ni++)
        bfr[ni] = *(const short8*)&lB[(wn * 64 + ni * 16 + lr) * 64 + kk * 32 + lg * 8];
#pragma unroll
      for (int mi = 0; mi < 4; mi++)
#pragma unroll
        for (int ni = 0; ni < 4; ni++)
          acc[mi][ni] = __builtin_amdgcn_mfma_f32_16x16x32_bf16(af[mi], bfr[ni], acc[mi][ni], 0, 0, 0);
    }
  }

#pragma unroll
  for (int mi = 0; mi < 4; mi++)
#pragma unroll
    for (int ni = 0; ni < 4; ni++)
#pragma unroll
      for (int i = 0; i < 4; i++) {
        const int row = m0 + wm * 64 + mi * 16 + lg * 4 + i;
        const int col = n0 + wn * 64 + ni * 16 + lr;
        if (OUTBF) ((unsigned short*)C)[(size_t)row * N + col] = f2bf(acc[mi][ni][i]);
        else       ((float*)C)[(size_t)row * N + col] = acc[mi][ni][i];
      }
}

// ---------------- flash attention (causal), QBLK=128, KVBLK=64 ----------------
// grid (T/128, H, B), 256 threads = 4 waves, each wave owns 32 q-rows.
__global__ __launch_bounds__(256, 2) void attn_fa(const unsigned short* __restrict__ qkv,
                                                  unsigned short* __restrict__ out) {
  const int qtl = (T_ / 128 - 1) - blockIdx.x;   // descending work for load balance
  const int h = blockIdx.y, b = blockIdx.z;
  const int q0 = qtl * 128;
  const int tid = threadIdx.x, w = tid >> 6, l = tid & 63, lr = l & 15, lg = l >> 4;

  const unsigned short* Qb = qkv + (size_t)b * T_ * TD3_ + h * DH_;
  const unsigned short* Kb = Qb + D_;
  const unsigned short* Vb = Qb + 2 * D_;

  __shared__ unsigned short klds[64 * 128];      // K rows, XOR-swizzled chunks
  __shared__ unsigned short vt[128 * 72];        // V^T, padded stride 72
  __shared__ unsigned short plds[4][32 * 72];    // per-wave P, padded stride 72

  const float scale = 0.08838834764831845f;      // 1/sqrt(128)

  // Q fragments (pre-scaled by 1/sqrt(DH)): wave rows [w*32, w*32+32)
  short8 qf[2][4];
#pragma unroll
  for (int mi = 0; mi < 2; mi++) {
    const unsigned short* qrow = Qb + (size_t)(q0 + w * 32 + mi * 16 + lr) * TD3_;
#pragma unroll
    for (int ks = 0; ks < 4; ks++) {
      ushort8v qv = *(const ushort8v*)(qrow + ks * 32 + lg * 8);
      short8 qs;
#pragma unroll
      for (int j = 0; j < 8; j++) qs[j] = (short)f2bf(bf2f(qv[j]) * scale);
      qf[mi][ks] = qs;
    }
  }

  f32x4 oacc[2][8] = {};
  float mrun[2][4], lsum[2][4];
#pragma unroll
  for (int mi = 0; mi < 2; mi++)
#pragma unroll
    for (int i = 0; i < 4; i++) { mrun[mi][i] = -__builtin_inff(); lsum[mi][i] = 0.f; }

  const int nt = q0 / 64 + 2;
  for (int t = 0; t < nt; t++) {
    const int kv0 = t * 64;

    __syncthreads();   // previous tile's LDS reads done

    // ---- stage K[64][128] via global_load_lds, XOR-swizzle on SOURCE ----
#pragma unroll
    for (int it = 0; it < 4; it++) {
      const int n = it * 256 + tid;          // 16B chunk id, 0..1023
      const int kv = n >> 4, ch = n & 15;
      gload_lds16(Kb + (size_t)(kv0 + kv) * TD3_ + ((ch ^ (kv & 7)) << 3),
                  &klds[n * 8]);
    }
    // ---- stage V^T: coalesced column reads -> register pack -> ds_write_b128 ----
#pragma unroll
    for (int p = 0; p < 4; p++) {
      const int kvc = (tid >> 7) + p * 2;    // kv chunk of 8
      const int dh  = tid & 127;
      const unsigned short* vcol = Vb + (size_t)(kv0 + kvc * 8) * TD3_ + dh;
      ushort8v tv;
#pragma unroll
      for (int j = 0; j < 8; j++) tv[j] = vcol[(size_t)j * TD3_];
      *(ushort8v*)&vt[dh * 72 + kvc * 8] = tv;
    }
    __syncthreads();   // staged

    const bool active = (kv0 <= q0 + w * 32 + 31);
    if (active) {
      // ---- S = Q K^T from swizzled LDS ----
      f32x4 s[2][4] = {};
#pragma unroll
      for (int nf = 0; nf < 4; nf++) {
        const int kv = nf * 16 + lr;
#pragma unroll
        for (int ks = 0; ks < 4; ks++) {
          short8 kf = *(const short8*)&klds[kv * 128 + (((ks * 4 + lg) ^ (lr & 7)) << 3)];
#pragma unroll
          for (int mi = 0; mi < 2; mi++)
            s[mi][nf] = __builtin_amdgcn_mfma_f32_16x16x32_bf16(qf[mi][ks], kf, s[mi][nf], 0, 0, 0);
        }
      }

      // ---- causal mask + online softmax (pre-scaled Q => no scale here) ----
      const bool needmask = (kv0 + 63 > q0 + w * 32);
      float pmax[2][4];
#pragma unroll
      for (int mi = 0; mi < 2; mi++)
#pragma unroll
        for (int i = 0; i < 4; i++) pmax[mi][i] = -__builtin_inff();
#pragma unroll
      for (int mi = 0; mi < 2; mi++)
#pragma unroll
        for (int nf = 0; nf < 4; nf++)
#pragma unroll
          for (int i = 0; i < 4; i++) {
            float x = s[mi][nf][i];
            if (needmask) {
              const int qr = w * 32 + mi * 16 + lg * 4 + i;
              const int kc = nf * 16 + lr;
              if (kv0 + kc > q0 + qr) x = -__builtin_inff();
            }
            s[mi][nf][i] = x;
            pmax[mi][i] = fmaxf(pmax[mi][i], x);
          }
#pragma unroll
      for (int m = 1; m < 16; m <<= 1)
#pragma unroll
        for (int mi = 0; mi < 2; mi++)
#pragma unroll
          for (int i = 0; i < 4; i++) pmax[mi][i] = fmaxf(pmax[mi][i], __shfl_xor(pmax[mi][i], m));

      float alpha[2][4], rsum[2][4];
#pragma unroll
      for (int mi = 0; mi < 2; mi++)
#pragma unroll
        for (int i = 0; i < 4; i++) {
          const float mn = fmaxf(mrun[mi][i], pmax[mi][i]);
          alpha[mi][i] = __expf(mrun[mi][i] - mn);
          mrun[mi][i] = mn;
          rsum[mi][i] = 0.f;
        }
#pragma unroll
      for (int mi = 0; mi < 2; mi++)
#pragma unroll
        for (int nf = 0; nf < 4; nf++)
#pragma unroll
          for (int i = 0; i < 4; i++) {
            const float p = __expf(s[mi][nf][i] - mrun[mi][i]);
            rsum[mi][i] += p;
            plds[w][(mi * 16 + lg * 4 + i) * 72 + nf * 16 + lr] = f2bf(p);
          }
#pragma unroll
      for (int m = 1; m < 16; m <<= 1)
#pragma unroll
        for (int mi = 0; mi < 2; mi++)
#pragma unroll
          for (int i = 0; i < 4; i++) rsum[mi][i] += __shfl_xor(rsum[mi][i], m);
#pragma unroll
      for (int mi = 0; mi < 2; mi++)
#pragma unroll
        for (int i = 0; i < 4; i++) lsum[mi][i] = lsum[mi][i] * alpha[mi][i] + rsum[mi][i];
#pragma unroll
      for (int mi = 0; mi < 2; mi++)
#pragma unroll
        for (int nf = 0; nf < 8; nf++)
#pragma unroll
          for (int i = 0; i < 4; i++) oacc[mi][nf][i] *= alpha[mi][i];

      // ---- O += P V  (P from own wave's LDS; V^T rows from vt) ----
#pragma unroll
      for (int kk = 0; kk < 2; kk++) {
        short8 pa[2];
#pragma unroll
        for (int mi = 0; mi < 2; mi++)
          pa[mi] = *(const short8*)&plds[w][(mi * 16 + lr) * 72 + kk * 32 + lg * 8];
#pragma unroll
        for (int nf = 0; nf < 8; nf++) {
          const short8 vb = *(const short8*)&vt[(nf * 16 + lr) * 72 + kk * 32 + lg * 8];
#pragma unroll
          for (int mi = 0; mi < 2; mi++)
            oacc[mi][nf] = __builtin_amdgcn_mfma_f32_16x16x32_bf16(pa[mi], vb, oacc[mi][nf], 0, 0, 0);
        }
      }
    }
  }

  // ---- normalize + write bf16 [b][t][h][dh] ----
  float rinv[2][4];
#pragma unroll
  for (int mi = 0; mi < 2; mi++)
#pragma unroll
    for (int i = 0; i < 4; i++) rinv[mi][i] = 1.f / lsum[mi][i];
#pragma unroll
  for (int mi = 0; mi < 2; mi++) {
    unsigned short* orow = out + ((size_t)b * T_ + q0 + w * 32 + mi * 16 + lg * 4) * D_ + h * DH_;
#pragma unroll
    for (int nf = 0; nf < 8; nf++)
#pragma unroll
      for (int i = 0; i < 4; i++)
        orow[(size_t)i * D_ + nf * 16 + lr] = f2bf(oacc[mi][nf][i] * rinv[mi][i]);
  }
}

extern "C" void kernel_launch(void* const* d_in, const int* in_sizes, int n_in,
                              void* d_out, int out_size, void* d_ws, size_t ws_size,
                              hipStream_t stream) {
  const float* x    = (const float*)d_in[0];
  const float* wqkv = (const float*)d_in[1];
  const float* wo   = (const float*)d_in[2];
  float* out = (float*)d_out;

  char* ws = (char*)d_ws;
  unsigned short* xb     = (unsigned short*)(ws);               // 16.8 MB (reused as attn out)
  unsigned short* wqkvt  = (unsigned short*)(ws + 16777216);    // 25.2 MB
  unsigned short* wot    = (unsigned short*)(ws + 41943040);    //  8.4 MB
  unsigned short* qkv    = (unsigned short*)(ws + 50331648);    // 50.3 MB
  unsigned short* attn   = xb;   // xb is dead after GEMM1

  convert_f32_bf16<<<2048, 256, 0, stream>>>(x, xb, B_ * T_ * D_ / 4);
  transpose_f32_bf16<<<dim3(TD3_ / 32, D_ / 32), 256, 0, stream>>>(wqkv, wqkvt, D_, TD3_);
  transpose_f32_bf16<<<dim3(D_ / 32, D_ / 32), 256, 0, stream>>>(wo, wot, D_, D_);

  gemm_bt<1><<<dim3(TD3_ / 128, (B_ * T_) / 128), 256, 0, stream>>>(xb, wqkvt, qkv,
                                                                    B_ * T_, TD3_, D_);
  attn_fa<<<dim3(T_ / 128, H_, B_), 256, 0, stream>>>(qkv, attn);
  gemm_bt<0><<<dim3(D_ / 128, (B_ * T_) / 128), 256, 0, stream>>>(attn, wot, out,
                                                                  B_ * T_, D_, D_);
}

// Round 4
// 350.465 us; speedup vs baseline: 1.4613x; 1.1368x over previous
//
#include <hip/hip_runtime.h>
#include <hip/hip_bf16.h>

#define B_   2
#define T_   2048
#define D_   2048
#define H_   16
#define DH_  128
#define TD3_ 6144   // 3*D

typedef __attribute__((ext_vector_type(8))) short   short8;
typedef __attribute__((ext_vector_type(8))) unsigned short ushort8v;
typedef __attribute__((ext_vector_type(4))) float   f32x4;
typedef __attribute__((ext_vector_type(4))) float   f4v;
typedef __attribute__((ext_vector_type(4))) unsigned short u16x4;

static __device__ __forceinline__ unsigned short f2bf(float f) {
  unsigned int u = __builtin_bit_cast(unsigned int, f);
  u += 0x7FFFu + ((u >> 16) & 1u);
  return (unsigned short)(u >> 16);
}
static __device__ __forceinline__ float bf2f(unsigned short u) {
  return __builtin_bit_cast(float, (unsigned int)u << 16);
}

static __device__ __forceinline__ void gload_lds16(const unsigned short* g, unsigned short* l) {
  __builtin_amdgcn_global_load_lds((const __attribute__((address_space(1))) void*)g,
                                   (__attribute__((address_space(3))) void*)l, 16, 0, 0);
}

// ---------------- fp32 -> bf16 elementwise cast (vectorized) ----------------
__global__ __launch_bounds__(256) void convert_f32_bf16(const float* __restrict__ X,
                                                        unsigned short* __restrict__ Y, int n4) {
  for (int i = blockIdx.x * blockDim.x + threadIdx.x; i < n4; i += gridDim.x * blockDim.x) {
    f4v v = ((const f4v*)X)[i];
    u16x4 o;
    o[0] = f2bf(v[0]); o[1] = f2bf(v[1]); o[2] = f2bf(v[2]); o[3] = f2bf(v[3]);
    ((u16x4*)Y)[i] = o;
  }
}

// ---------------- transpose fp32 [K][N] -> bf16 [N][K] ----------------
__global__ __launch_bounds__(256) void transpose_f32_bf16(const float* __restrict__ W,
                                                          unsigned short* __restrict__ WT,
                                                          int K, int N) {
  __shared__ float tile[32][33];
  int n0 = blockIdx.x * 32, k0 = blockIdx.y * 32;
  int tx = threadIdx.x & 31, ty = threadIdx.x >> 5;
#pragma unroll
  for (int r = 0; r < 4; r++)
    tile[ty + 8 * r][tx] = W[(size_t)(k0 + ty + 8 * r) * N + n0 + tx];
  __syncthreads();
#pragma unroll
  for (int r = 0; r < 4; r++)
    WT[(size_t)(n0 + ty + 8 * r) * K + k0 + tx] = f2bf(tile[tx][ty + 8 * r]);
}

// ---------------- generic bf16 GEMM (used for output projection) ----------------
template <int OUTBF>
__global__ __launch_bounds__(256) void gemm_bt(const unsigned short* __restrict__ A,
                                               const unsigned short* __restrict__ BT,
                                               void* __restrict__ C, int M, int N, int K) {
  __shared__ unsigned short lA[128 * 64];
  __shared__ unsigned short lB[128 * 64];
  const int tid = threadIdx.x;
  const int m0 = blockIdx.y * 128, n0 = blockIdx.x * 128;
  const int w = tid >> 6, l = tid & 63, lr = l & 15, lg = l >> 4;
  const int wm = w >> 1, wn = w & 1;
  f32x4 acc[4][4] = {};

  const int sr = tid >> 3;
  const int sc = (tid & 7) * 8;

  for (int kt = 0; kt < K; kt += 64) {
    __syncthreads();
#pragma unroll
    for (int c = 0; c < 4; c++) {
      const int row = c * 32 + sr;
      gload_lds16(A  + (size_t)(m0 + row) * K + kt + sc, &lA[row * 64 + sc]);
      gload_lds16(BT + (size_t)(n0 + row) * K + kt + sc, &lB[row * 64 + sc]);
    }
    __syncthreads();
#pragma unroll
    for (int kk = 0; kk < 2; kk++) {
      short8 af[4], bfr[4];
#pragma unroll
      for (int mi = 0; mi < 4; mi++)
        af[mi] = *(const short8*)&lA[(wm * 64 + mi * 16 + lr) * 64 + kk * 32 + lg * 8];
#pragma unroll
      for (int ni = 0; ni < 4; ni++)
        bfr[ni] = *(const short8*)&lB[(wn * 64 + ni * 16 + lr) * 64 + kk * 32 + lg * 8];
#pragma unroll
      for (int mi = 0; mi < 4; mi++)
#pragma unroll
        for (int ni = 0; ni < 4; ni++)
          acc[mi][ni] = __builtin_amdgcn_mfma_f32_16x16x32_bf16(af[mi], bfr[ni], acc[mi][ni], 0, 0, 0);
    }
  }

#pragma unroll
  for (int mi = 0; mi < 4; mi++)
#pragma unroll
    for (int ni = 0; ni < 4; ni++)
#pragma unroll
      for (int i = 0; i < 4; i++) {
        const int row = m0 + wm * 64 + mi * 16 + lg * 4 + i;
        const int col = n0 + wn * 64 + ni * 16 + lr;
        if (OUTBF) ((unsigned short*)C)[(size_t)row * N + col] = f2bf(acc[mi][ni][i]);
        else       ((float*)C)[(size_t)row * N + col] = acc[mi][ni][i];
      }
}

// ---------------- QKV GEMM: writes Q,K normal; V transposed [b][h][dh][T] ----------------
__global__ __launch_bounds__(256) void gemm_qkv(const unsigned short* __restrict__ A,
                                                const unsigned short* __restrict__ BT,
                                                unsigned short* __restrict__ qg,
                                                unsigned short* __restrict__ kg,
                                                unsigned short* __restrict__ vtg,
                                                int M, int N, int K) {
  __shared__ unsigned short lA[128 * 64];
  __shared__ unsigned short lB[128 * 64];
  const int tid = threadIdx.x;
  const int m0 = blockIdx.y * 128, n0 = blockIdx.x * 128;
  const int w = tid >> 6, l = tid & 63, lr = l & 15, lg = l >> 4;
  const int wm = w >> 1, wn = w & 1;
  f32x4 acc[4][4] = {};

  const int sr = tid >> 3;
  const int sc = (tid & 7) * 8;

  for (int kt = 0; kt < K; kt += 64) {
    __syncthreads();
#pragma unroll
    for (int c = 0; c < 4; c++) {
      const int row = c * 32 + sr;
      gload_lds16(A  + (size_t)(m0 + row) * K + kt + sc, &lA[row * 64 + sc]);
      gload_lds16(BT + (size_t)(n0 + row) * K + kt + sc, &lB[row * 64 + sc]);
    }
    __syncthreads();
#pragma unroll
    for (int kk = 0; kk < 2; kk++) {
      short8 af[4], bfr[4];
#pragma unroll
      for (int mi = 0; mi < 4; mi++)
        af[mi] = *(const short8*)&lA[(wm * 64 + mi * 16 + lr) * 64 + kk * 32 + lg * 8];
#pragma unroll
      for (int ni = 0; ni < 4; ni++)
        bfr[ni] = *(const short8*)&lB[(wn * 64 + ni * 16 + lr) * 64 + kk * 32 + lg * 8];
#pragma unroll
      for (int mi = 0; mi < 4; mi++)
#pragma unroll
        for (int ni = 0; ni < 4; ni++)
          acc[mi][ni] = __builtin_amdgcn_mfma_f32_16x16x32_bf16(af[mi], bfr[ni], acc[mi][ni], 0, 0, 0);
    }
  }

#pragma unroll
  for (int mi = 0; mi < 4; mi++)
#pragma unroll
    for (int ni = 0; ni < 4; ni++) {
      const int col = n0 + wn * 64 + ni * 16 + lr;
      const int third = col >> 11;        // 0=Q, 1=K, 2=V (D_=2048)
      const int nc = col & (D_ - 1);
#pragma unroll
      for (int i = 0; i < 4; i++) {
        const int row = m0 + wm * 64 + mi * 16 + lg * 4 + i;   // = b*T + t
        const unsigned short val = f2bf(acc[mi][ni][i]);
        if (third == 0)      qg[(size_t)row * D_ + nc] = val;
        else if (third == 1) kg[(size_t)row * D_ + nc] = val;
        else {
          const int bb = row >> 11, t = row & (T_ - 1);
          vtg[(((size_t)bb * H_ + (nc >> 7)) * DH_ + (nc & 127)) * T_ + t] = val;
        }
      }
    }
}

// ---------------- flash attention (causal), QBLK=128, KVBLK=64, 2-phase pipeline ----------------
// grid (T/128, H, B), 256 threads = 4 waves, each wave owns 32 q-rows.
// LDS: 32K (K dbuf) + 32K (V^T dbuf) + 16K (P) = 80 KiB -> 2 blocks/CU.
__global__ __launch_bounds__(256, 2) void attn_fa(const unsigned short* __restrict__ qg,
                                                  const unsigned short* __restrict__ kg,
                                                  const unsigned short* __restrict__ vtg,
                                                  unsigned short* __restrict__ out) {
  const int x = blockIdx.x, h = blockIdx.y, b = blockIdx.z;
  // complementary pairing: blocks c and c+256 (same x, b=0/1) sum to uniform work
  const int qtl = b ? x : (T_ / 128 - 1 - x);
  const int q0 = qtl * 128;
  const int tid = threadIdx.x, w = tid >> 6, l = tid & 63, lr = l & 15, lg = l >> 4;

  const unsigned short* Qb = qg + (size_t)b * T_ * D_ + h * DH_;
  const unsigned short* Kb = kg + (size_t)b * T_ * D_ + h * DH_;
  const unsigned short* Vt = vtg + ((size_t)b * H_ + h) * DH_ * T_;

  __shared__ unsigned short klds[2][64 * 128];   // K rows, XOR-src-swizzled 16B chunks
  __shared__ unsigned short vt[2][128 * 64];     // V^T rows (dh-major), XOR-src-swizzled
  __shared__ unsigned short plds[4][32 * 64];    // per-wave P, XOR-chunk-swizzled (stride 64)

  const float scale = 0.08838834764831845f;      // 1/sqrt(128)

  // Q fragments, pre-scaled
  short8 qf[2][4];
#pragma unroll
  for (int mi = 0; mi < 2; mi++) {
    const unsigned short* qrow = Qb + (size_t)(q0 + w * 32 + mi * 16 + lr) * D_;
#pragma unroll
    for (int ks = 0; ks < 4; ks++) {
      ushort8v qv = *(const ushort8v*)(qrow + ks * 32 + lg * 8);
      short8 qs;
#pragma unroll
      for (int j = 0; j < 8; j++) qs[j] = (short)f2bf(bf2f(qv[j]) * scale);
      qf[mi][ks] = qs;
    }
  }

  f32x4 oacc[2][8] = {};
  float mrun[2][4], lsum[2][4];
#pragma unroll
  for (int mi = 0; mi < 2; mi++)
#pragma unroll
    for (int i = 0; i < 4; i++) { mrun[mi][i] = -__builtin_inff(); lsum[mi][i] = 0.f; }

  auto STAGE = [&](int buf, int kv0) {
#pragma unroll
    for (int it = 0; it < 4; it++) {
      const int n = it * 256 + tid;                 // 16B chunk id, 0..1023
      { const int kv = n >> 4, ch = n & 15;         // K: 64 rows x 16 chunks
        gload_lds16(Kb + (size_t)(kv0 + kv) * D_ + ((ch ^ (kv & 7)) << 3),
                    &klds[buf][n * 8]); }
      { const int dh = n >> 3, ch = n & 7;          // V^T: 128 rows x 8 chunks
        gload_lds16(Vt + (size_t)dh * T_ + kv0 + ((ch ^ (dh & 7)) << 3),
                    &vt[buf][n * 8]); }
    }
  };

  const int nt = 2 * qtl + 2;
  STAGE(0, 0);
  __syncthreads();

  for (int t = 0; t < nt; t++) {
    const int buf = t & 1;
    if (t + 1 < nt) STAGE(buf ^ 1, (t + 1) * 64);   // in flight during compute

    const int kv0 = t * 64;
    const bool active = (kv0 <= q0 + w * 32 + 31);
    if (active) {
      // ---- S = Q K^T ----
      f32x4 s[2][4] = {};
      __builtin_amdgcn_s_setprio(1);
#pragma unroll
      for (int nf = 0; nf < 4; nf++) {
        const int kv = nf * 16 + lr;
#pragma unroll
        for (int ks = 0; ks < 4; ks++) {
          short8 kf = *(const short8*)&klds[buf][kv * 128 + (((ks * 4 + lg) ^ (lr & 7)) << 3)];
#pragma unroll
          for (int mi = 0; mi < 2; mi++)
            s[mi][nf] = __builtin_amdgcn_mfma_f32_16x16x32_bf16(qf[mi][ks], kf, s[mi][nf], 0, 0, 0);
        }
      }
      __builtin_amdgcn_s_setprio(0);

      // ---- causal mask + online softmax ----
      const bool needmask = (kv0 + 63 > q0 + w * 32);
      float pmax[2][4];
#pragma unroll
      for (int mi = 0; mi < 2; mi++)
#pragma unroll
        for (int i = 0; i < 4; i++) pmax[mi][i] = -__builtin_inff();
#pragma unroll
      for (int mi = 0; mi < 2; mi++)
#pragma unroll
        for (int nf = 0; nf < 4; nf++)
#pragma unroll
          for (int i = 0; i < 4; i++) {
            float xv = s[mi][nf][i];
            if (needmask) {
              const int qr = w * 32 + mi * 16 + lg * 4 + i;
              const int kc = nf * 16 + lr;
              if (kv0 + kc > q0 + qr) xv = -__builtin_inff();
            }
            s[mi][nf][i] = xv;
            pmax[mi][i] = fmaxf(pmax[mi][i], xv);
          }
#pragma unroll
      for (int m = 1; m < 16; m <<= 1)
#pragma unroll
        for (int mi = 0; mi < 2; mi++)
#pragma unroll
          for (int i = 0; i < 4; i++) pmax[mi][i] = fmaxf(pmax[mi][i], __shfl_xor(pmax[mi][i], m));

      float alpha[2][4], rsum[2][4];
#pragma unroll
      for (int mi = 0; mi < 2; mi++)
#pragma unroll
        for (int i = 0; i < 4; i++) {
          const float mn = fmaxf(mrun[mi][i], pmax[mi][i]);
          alpha[mi][i] = __expf(mrun[mi][i] - mn);
          mrun[mi][i] = mn;
          rsum[mi][i] = 0.f;
        }
      // P write: row-major stride 64 with XOR-16B-chunk swizzle (elem ^= (row&7)<<3)
#pragma unroll
      for (int mi = 0; mi < 2; mi++)
#pragma unroll
        for (int nf = 0; nf < 4; nf++)
#pragma unroll
          for (int i = 0; i < 4; i++) {
            const float p = __expf(s[mi][nf][i] - mrun[mi][i]);
            rsum[mi][i] += p;
            const int prow = mi * 16 + lg * 4 + i;
            plds[w][prow * 64 + ((nf * 16 + lr) ^ ((prow & 7) << 3))] = f2bf(p);
          }
#pragma unroll
      for (int m = 1; m < 16; m <<= 1)
#pragma unroll
        for (int mi = 0; mi < 2; mi++)
#pragma unroll
          for (int i = 0; i < 4; i++) rsum[mi][i] += __shfl_xor(rsum[mi][i], m);
#pragma unroll
      for (int mi = 0; mi < 2; mi++)
#pragma unroll
        for (int i = 0; i < 4; i++) lsum[mi][i] = lsum[mi][i] * alpha[mi][i] + rsum[mi][i];
#pragma unroll
      for (int mi = 0; mi < 2; mi++)
#pragma unroll
        for (int nf = 0; nf < 8; nf++)
#pragma unroll
          for (int i = 0; i < 4; i++) oacc[mi][nf][i] *= alpha[mi][i];

      // ---- O += P V ----
      __builtin_amdgcn_s_setprio(1);
#pragma unroll
      for (int kk = 0; kk < 2; kk++) {
        short8 pa[2];
#pragma unroll
        for (int mi = 0; mi < 2; mi++) {
          const int prow = mi * 16 + lr;
          pa[mi] = *(const short8*)&plds[w][prow * 64 + (((kk * 32 + lg * 8)) ^ ((prow & 7) << 3))];
        }
#pragma unroll
        for (int nf = 0; nf < 8; nf++) {
          const short8 vb = *(const short8*)&vt[buf][(nf * 16 + lr) * 64 + (((kk * 4 + lg) ^ (lr & 7)) << 3)];
#pragma unroll
          for (int mi = 0; mi < 2; mi++)
            oacc[mi][nf] = __builtin_amdgcn_mfma_f32_16x16x32_bf16(pa[mi], vb, oacc[mi][nf], 0, 0, 0);
        }
      }
      __builtin_amdgcn_s_setprio(0);
    }
    __syncthreads();   // drains staging; tile t+1 ready; buffer t-1 safe to overwrite
  }

  // ---- normalize + write bf16 [b][t][h][dh] ----
  float rinv[2][4];
#pragma unroll
  for (int mi = 0; mi < 2; mi++)
#pragma unroll
    for (int i = 0; i < 4; i++) rinv[mi][i] = 1.f / lsum[mi][i];
#pragma unroll
  for (int mi = 0; mi < 2; mi++) {
    unsigned short* orow = out + ((size_t)b * T_ + q0 + w * 32 + mi * 16 + lg * 4) * D_ + h * DH_;
#pragma unroll
    for (int nf = 0; nf < 8; nf++)
#pragma unroll
      for (int i = 0; i < 4; i++)
        orow[(size_t)i * D_ + nf * 16 + lr] = f2bf(oacc[mi][nf][i] * rinv[mi][i]);
  }
}

extern "C" void kernel_launch(void* const* d_in, const int* in_sizes, int n_in,
                              void* d_out, int out_size, void* d_ws, size_t ws_size,
                              hipStream_t stream) {
  const float* x    = (const float*)d_in[0];
  const float* wqkv = (const float*)d_in[1];
  const float* wo   = (const float*)d_in[2];
  float* out = (float*)d_out;

  char* ws = (char*)d_ws;
  unsigned short* xb    = (unsigned short*)(ws);               // 16.8 MB (reused as attn out)
  unsigned short* wqkvt = (unsigned short*)(ws + 16777216);    // 25.2 MB
  unsigned short* wot   = (unsigned short*)(ws + 41943040);    //  8.4 MB
  unsigned short* qg    = (unsigned short*)(ws + 50331648);    // 16.8 MB
  unsigned short* kg    = (unsigned short*)(ws + 67108864);    // 16.8 MB
  unsigned short* vtg   = (unsigned short*)(ws + 83886080);    // 16.8 MB  (end 100.7 MB)
  unsigned short* attn  = xb;   // xb dead after GEMM1

  convert_f32_bf16<<<2048, 256, 0, stream>>>(x, xb, B_ * T_ * D_ / 4);
  transpose_f32_bf16<<<dim3(TD3_ / 32, D_ / 32), 256, 0, stream>>>(wqkv, wqkvt, D_, TD3_);
  transpose_f32_bf16<<<dim3(D_ / 32, D_ / 32), 256, 0, stream>>>(wo, wot, D_, D_);

  gemm_qkv<<<dim3(TD3_ / 128, (B_ * T_) / 128), 256, 0, stream>>>(xb, wqkvt, qg, kg, vtg,
                                                                  B_ * T_, TD3_, D_);
  attn_fa<<<dim3(T_ / 128, H_, B_), 256, 0, stream>>>(qg, kg, vtg, attn);
  gemm_bt<0><<<dim3(D_ / 128, (B_ * T_) / 128), 256, 0, stream>>>(attn, wot, out,
                                                                  B_ * T_, D_, D_);
}

// Round 5
// 326.066 us; speedup vs baseline: 1.5706x; 1.0748x over previous
//
#include <hip/hip_runtime.h>
#include <hip/hip_bf16.h>

#define B_   2
#define T_   2048
#define D_   2048
#define H_   16
#define DH_  128
#define TD3_ 6144   // 3*D

typedef __attribute__((ext_vector_type(8))) short   short8;
typedef __attribute__((ext_vector_type(8))) unsigned short ushort8v;
typedef __attribute__((ext_vector_type(4))) float   f32x4;
typedef __attribute__((ext_vector_type(4))) float   f4v;
typedef __attribute__((ext_vector_type(4))) unsigned short u16x4;

static __device__ __forceinline__ unsigned short f2bf(float f) {
  unsigned int u = __builtin_bit_cast(unsigned int, f);
  u += 0x7FFFu + ((u >> 16) & 1u);
  return (unsigned short)(u >> 16);
}
static __device__ __forceinline__ float bf2f(unsigned short u) {
  return __builtin_bit_cast(float, (unsigned int)u << 16);
}

static __device__ __forceinline__ void gload_lds16(const unsigned short* g, unsigned short* l) {
  __builtin_amdgcn_global_load_lds((const __attribute__((address_space(1))) void*)g,
                                   (__attribute__((address_space(3))) void*)l, 16, 0, 0);
}

// ---------------- fp32 -> bf16 elementwise cast (vectorized) ----------------
__global__ __launch_bounds__(256) void convert_f32_bf16(const float* __restrict__ X,
                                                        unsigned short* __restrict__ Y, int n4) {
  for (int i = blockIdx.x * blockDim.x + threadIdx.x; i < n4; i += gridDim.x * blockDim.x) {
    f4v v = ((const f4v*)X)[i];
    u16x4 o;
    o[0] = f2bf(v[0]); o[1] = f2bf(v[1]); o[2] = f2bf(v[2]); o[3] = f2bf(v[3]);
    ((u16x4*)Y)[i] = o;
  }
}

// ---------------- transpose fp32 [K][N] -> bf16 [N][K] ----------------
__global__ __launch_bounds__(256) void transpose_f32_bf16(const float* __restrict__ W,
                                                          unsigned short* __restrict__ WT,
                                                          int K, int N) {
  __shared__ float tile[32][33];
  int n0 = blockIdx.x * 32, k0 = blockIdx.y * 32;
  int tx = threadIdx.x & 31, ty = threadIdx.x >> 5;
#pragma unroll
  for (int r = 0; r < 4; r++)
    tile[ty + 8 * r][tx] = W[(size_t)(k0 + ty + 8 * r) * N + n0 + tx];
  __syncthreads();
#pragma unroll
  for (int r = 0; r < 4; r++)
    WT[(size_t)(n0 + ty + 8 * r) * K + k0 + tx] = f2bf(tile[tx][ty + 8 * r]);
}

// ---------------- V transpose: qkv V-third [b][t][h*DH+dh] -> vtg [b][h][dh][t] ----------------
__global__ __launch_bounds__(256) void vtr_kernel(const unsigned short* __restrict__ qkv,
                                                  unsigned short* __restrict__ vtg) {
  __shared__ unsigned short tile[64][68];   // +4 pad: ~2-way banks on both sides
  const int t0 = blockIdx.x * 64;
  const int h = blockIdx.y >> 1, dh0 = (blockIdx.y & 1) * 64;
  const int b = blockIdx.z;
  const int tid = threadIdx.x;
  const unsigned short* src = qkv + (size_t)b * T_ * TD3_ + 2 * D_ + h * DH_ + dh0;
  {
    const int r = tid >> 3, cc = (tid & 7) * 8;
#pragma unroll
    for (int k = 0; k < 2; k++) {
      ushort8v v = *(const ushort8v*)(src + (size_t)(t0 + k * 32 + r) * TD3_ + cc);
      *(ushort8v*)&tile[k * 32 + r][cc] = v;
    }
  }
  __syncthreads();
  unsigned short* dst = vtg + ((size_t)(b * H_ + h) * DH_ + dh0) * T_ + t0;
  {
    const int d = tid >> 3, tc = (tid & 7) * 8;
#pragma unroll
    for (int k = 0; k < 2; k++) {
      ushort8v v;
#pragma unroll
      for (int j = 0; j < 8; j++) v[j] = tile[tc + j][k * 32 + d];
      *(ushort8v*)(dst + (size_t)(k * 32 + d) * T_ + tc) = v;
    }
  }
}

// ---------------- bf16 GEMM: C[M][N] = A[M][K] * BT[N][K]^T ----------------
template <int OUTBF>
__global__ __launch_bounds__(256) void gemm_bt(const unsigned short* __restrict__ A,
                                               const unsigned short* __restrict__ BT,
                                               void* __restrict__ C, int M, int N, int K) {
  __shared__ unsigned short lA[128 * 64];
  __shared__ unsigned short lB[128 * 64];
  const int tid = threadIdx.x;
  const int m0 = blockIdx.y * 128, n0 = blockIdx.x * 128;
  const int w = tid >> 6, l = tid & 63, lr = l & 15, lg = l >> 4;
  const int wm = w >> 1, wn = w & 1;
  f32x4 acc[4][4] = {};

  const int sr = tid >> 3;
  const int sc = (tid & 7) * 8;

  for (int kt = 0; kt < K; kt += 64) {
    __syncthreads();
#pragma unroll
    for (int c = 0; c < 4; c++) {
      const int row = c * 32 + sr;
      gload_lds16(A  + (size_t)(m0 + row) * K + kt + sc, &lA[row * 64 + sc]);
      gload_lds16(BT + (size_t)(n0 + row) * K + kt + sc, &lB[row * 64 + sc]);
    }
    __syncthreads();
#pragma unroll
    for (int kk = 0; kk < 2; kk++) {
      short8 af[4], bfr[4];
#pragma unroll
      for (int mi = 0; mi < 4; mi++)
        af[mi] = *(const short8*)&lA[(wm * 64 + mi * 16 + lr) * 64 + kk * 32 + lg * 8];
#pragma unroll
      for (int ni = 0; ni < 4; ni++)
        bfr[ni] = *(const short8*)&lB[(wn * 64 + ni * 16 + lr) * 64 + kk * 32 + lg * 8];
#pragma unroll
      for (int mi = 0; mi < 4; mi++)
#pragma unroll
        for (int ni = 0; ni < 4; ni++)
          acc[mi][ni] = __builtin_amdgcn_mfma_f32_16x16x32_bf16(af[mi], bfr[ni], acc[mi][ni], 0, 0, 0);
    }
  }

#pragma unroll
  for (int mi = 0; mi < 4; mi++)
#pragma unroll
    for (int ni = 0; ni < 4; ni++)
#pragma unroll
      for (int i = 0; i < 4; i++) {
        const int row = m0 + wm * 64 + mi * 16 + lg * 4 + i;
        const int col = n0 + wn * 64 + ni * 16 + lr;
        if (OUTBF) ((unsigned short*)C)[(size_t)row * N + col] = f2bf(acc[mi][ni][i]);
        else       ((float*)C)[(size_t)row * N + col] = acc[mi][ni][i];
      }
}

// ---------------- flash attention (causal), QBLK=128, KVBLK=64, 2-phase pipeline ----------------
// grid (T/128, H, B), 256 threads = 4 waves, each wave owns 32 q-rows.
// LDS: 32K (K dbuf) + 32K (V^T dbuf) + 16K (P) = 80 KiB -> 2 blocks/CU.
__global__ __launch_bounds__(256, 2) void attn_fa(const unsigned short* __restrict__ qkv,
                                                  const unsigned short* __restrict__ vtg,
                                                  unsigned short* __restrict__ out) {
  const int x = blockIdx.x, h = blockIdx.y, b = blockIdx.z;
  // complementary pairing: blocks c and c+256 (same x, b=0/1) sum to uniform work
  const int qtl = b ? x : (T_ / 128 - 1 - x);
  const int q0 = qtl * 128;
  const int tid = threadIdx.x, w = tid >> 6, l = tid & 63, lr = l & 15, lg = l >> 4;

  const unsigned short* Qb = qkv + (size_t)b * T_ * TD3_ + h * DH_;
  const unsigned short* Kb = Qb + D_;
  const unsigned short* Vt = vtg + ((size_t)b * H_ + h) * DH_ * T_;

  __shared__ unsigned short klds[2][64 * 128];   // K rows, XOR-src-swizzled 16B chunks
  __shared__ unsigned short vt[2][128 * 64];     // V^T rows (dh-major), XOR-src-swizzled
  __shared__ unsigned short plds[4][32 * 64];    // per-wave P, XOR-chunk-swizzled (stride 64)

  const float scale = 0.08838834764831845f;      // 1/sqrt(128)

  // Q fragments, pre-scaled
  short8 qf[2][4];
#pragma unroll
  for (int mi = 0; mi < 2; mi++) {
    const unsigned short* qrow = Qb + (size_t)(q0 + w * 32 + mi * 16 + lr) * TD3_;
#pragma unroll
    for (int ks = 0; ks < 4; ks++) {
      ushort8v qv = *(const ushort8v*)(qrow + ks * 32 + lg * 8);
      short8 qs;
#pragma unroll
      for (int j = 0; j < 8; j++) qs[j] = (short)f2bf(bf2f(qv[j]) * scale);
      qf[mi][ks] = qs;
    }
  }

  f32x4 oacc[2][8] = {};
  float mrun[2][4], lsum[2][4];
#pragma unroll
  for (int mi = 0; mi < 2; mi++)
#pragma unroll
    for (int i = 0; i < 4; i++) { mrun[mi][i] = -__builtin_inff(); lsum[mi][i] = 0.f; }

  auto STAGE = [&](int buf, int kv0) {
#pragma unroll
    for (int it = 0; it < 4; it++) {
      const int n = it * 256 + tid;                 // 16B chunk id, 0..1023
      { const int kv = n >> 4, ch = n & 15;         // K: 64 rows x 16 chunks
        gload_lds16(Kb + (size_t)(kv0 + kv) * TD3_ + ((ch ^ (kv & 7)) << 3),
                    &klds[buf][n * 8]); }
      { const int dh = n >> 3, ch = n & 7;          // V^T: 128 rows x 8 chunks
        gload_lds16(Vt + (size_t)dh * T_ + kv0 + ((ch ^ (dh & 7)) << 3),
                    &vt[buf][n * 8]); }
    }
  };

  const int nt = 2 * qtl + 2;
  STAGE(0, 0);
  __syncthreads();

  for (int t = 0; t < nt; t++) {
    const int buf = t & 1;
    if (t + 1 < nt) STAGE(buf ^ 1, (t + 1) * 64);   // in flight during compute

    const int kv0 = t * 64;
    const bool active = (kv0 <= q0 + w * 32 + 31);
    if (active) {
      // ---- S = Q K^T ----
      f32x4 s[2][4] = {};
      __builtin_amdgcn_s_setprio(1);
#pragma unroll
      for (int nf = 0; nf < 4; nf++) {
        const int kv = nf * 16 + lr;
#pragma unroll
        for (int ks = 0; ks < 4; ks++) {
          short8 kf = *(const short8*)&klds[buf][kv * 128 + (((ks * 4 + lg) ^ (lr & 7)) << 3)];
#pragma unroll
          for (int mi = 0; mi < 2; mi++)
            s[mi][nf] = __builtin_amdgcn_mfma_f32_16x16x32_bf16(qf[mi][ks], kf, s[mi][nf], 0, 0, 0);
        }
      }
      __builtin_amdgcn_s_setprio(0);

      // ---- causal mask + online softmax ----
      const bool needmask = (kv0 + 63 > q0 + w * 32);
      float pmax[2][4];
#pragma unroll
      for (int mi = 0; mi < 2; mi++)
#pragma unroll
        for (int i = 0; i < 4; i++) pmax[mi][i] = -__builtin_inff();
#pragma unroll
      for (int mi = 0; mi < 2; mi++)
#pragma unroll
        for (int nf = 0; nf < 4; nf++)
#pragma unroll
          for (int i = 0; i < 4; i++) {
            float xv = s[mi][nf][i];
            if (needmask) {
              const int qr = w * 32 + mi * 16 + lg * 4 + i;
              const int kc = nf * 16 + lr;
              if (kv0 + kc > q0 + qr) xv = -__builtin_inff();
            }
            s[mi][nf][i] = xv;
            pmax[mi][i] = fmaxf(pmax[mi][i], xv);
          }
#pragma unroll
      for (int m = 1; m < 16; m <<= 1)
#pragma unroll
        for (int mi = 0; mi < 2; mi++)
#pragma unroll
          for (int i = 0; i < 4; i++) pmax[mi][i] = fmaxf(pmax[mi][i], __shfl_xor(pmax[mi][i], m));

      float alpha[2][4], rsum[2][4];
#pragma unroll
      for (int mi = 0; mi < 2; mi++)
#pragma unroll
        for (int i = 0; i < 4; i++) {
          const float mn = fmaxf(mrun[mi][i], pmax[mi][i]);
          alpha[mi][i] = __expf(mrun[mi][i] - mn);
          mrun[mi][i] = mn;
          rsum[mi][i] = 0.f;
        }
      // P write: row-major stride 64 with XOR-16B-chunk swizzle (elem ^= (row&7)<<3)
#pragma unroll
      for (int mi = 0; mi < 2; mi++)
#pragma unroll
        for (int nf = 0; nf < 4; nf++)
#pragma unroll
          for (int i = 0; i < 4; i++) {
            const float p = __expf(s[mi][nf][i] - mrun[mi][i]);
            rsum[mi][i] += p;
            const int prow = mi * 16 + lg * 4 + i;
            plds[w][prow * 64 + ((nf * 16 + lr) ^ ((prow & 7) << 3))] = f2bf(p);
          }
#pragma unroll
      for (int m = 1; m < 16; m <<= 1)
#pragma unroll
        for (int mi = 0; mi < 2; mi++)
#pragma unroll
          for (int i = 0; i < 4; i++) rsum[mi][i] += __shfl_xor(rsum[mi][i], m);
#pragma unroll
      for (int mi = 0; mi < 2; mi++)
#pragma unroll
        for (int i = 0; i < 4; i++) lsum[mi][i] = lsum[mi][i] * alpha[mi][i] + rsum[mi][i];
#pragma unroll
      for (int mi = 0; mi < 2; mi++)
#pragma unroll
        for (int nf = 0; nf < 8; nf++)
#pragma unroll
          for (int i = 0; i < 4; i++) oacc[mi][nf][i] *= alpha[mi][i];

      // ---- O += P V ----
      __builtin_amdgcn_s_setprio(1);
#pragma unroll
      for (int kk = 0; kk < 2; kk++) {
        short8 pa[2];
#pragma unroll
        for (int mi = 0; mi < 2; mi++) {
          const int prow = mi * 16 + lr;
          pa[mi] = *(const short8*)&plds[w][prow * 64 + (((kk * 32 + lg * 8)) ^ ((prow & 7) << 3))];
        }
#pragma unroll
        for (int nf = 0; nf < 8; nf++) {
          const short8 vb = *(const short8*)&vt[buf][(nf * 16 + lr) * 64 + (((kk * 4 + lg) ^ (lr & 7)) << 3)];
#pragma unroll
          for (int mi = 0; mi < 2; mi++)
            oacc[mi][nf] = __builtin_amdgcn_mfma_f32_16x16x32_bf16(pa[mi], vb, oacc[mi][nf], 0, 0, 0);
        }
      }
      __builtin_amdgcn_s_setprio(0);
    }
    __syncthreads();   // drains staging; tile t+1 ready; buffer t-1 safe to overwrite
  }

  // ---- normalize + write bf16 [b][t][h][dh] ----
  float rinv[2][4];
#pragma unroll
  for (int mi = 0; mi < 2; mi++)
#pragma unroll
    for (int i = 0; i < 4; i++) rinv[mi][i] = 1.f / lsum[mi][i];
#pragma unroll
  for (int mi = 0; mi < 2; mi++) {
    unsigned short* orow = out + ((size_t)b * T_ + q0 + w * 32 + mi * 16 + lg * 4) * D_ + h * DH_;
#pragma unroll
    for (int nf = 0; nf < 8; nf++)
#pragma unroll
      for (int i = 0; i < 4; i++)
        orow[(size_t)i * D_ + nf * 16 + lr] = f2bf(oacc[mi][nf][i] * rinv[mi][i]);
  }
}

extern "C" void kernel_launch(void* const* d_in, const int* in_sizes, int n_in,
                              void* d_out, int out_size, void* d_ws, size_t ws_size,
                              hipStream_t stream) {
  const float* x    = (const float*)d_in[0];
  const float* wqkv = (const float*)d_in[1];
  const float* wo   = (const float*)d_in[2];
  float* out = (float*)d_out;

  char* ws = (char*)d_ws;
  unsigned short* xb    = (unsigned short*)(ws);               // 16.8 MB (reused as attn out)
  unsigned short* wqkvt = (unsigned short*)(ws + 16777216);    // 25.2 MB (dead after gemm1)
  unsigned short* vtg   = (unsigned short*)(ws + 16777216);    // 16.8 MB, overlays wqkvt
  unsigned short* wot   = (unsigned short*)(ws + 41943040);    //  8.4 MB
  unsigned short* qkv   = (unsigned short*)(ws + 50331648);    // 50.3 MB  (end 100.7 MB)
  unsigned short* attn  = xb;   // xb dead after GEMM1

  convert_f32_bf16<<<2048, 256, 0, stream>>>(x, xb, B_ * T_ * D_ / 4);
  transpose_f32_bf16<<<dim3(TD3_ / 32, D_ / 32), 256, 0, stream>>>(wqkv, wqkvt, D_, TD3_);
  transpose_f32_bf16<<<dim3(D_ / 32, D_ / 32), 256, 0, stream>>>(wo, wot, D_, D_);

  gemm_bt<1><<<dim3(TD3_ / 128, (B_ * T_) / 128), 256, 0, stream>>>(xb, wqkvt, qkv,
                                                                    B_ * T_, TD3_, D_);
  vtr_kernel<<<dim3(T_ / 64, H_ * 2, B_), 256, 0, stream>>>(qkv, vtg);
  attn_fa<<<dim3(T_ / 128, H_, B_), 256, 0, stream>>>(qkv, vtg, attn);
  gemm_bt<0><<<dim3(D_ / 128, (B_ * T_) / 128), 256, 0, stream>>>(attn, wot, out,
                                                                  B_ * T_, D_, D_);
}

// Round 7
// 311.853 us; speedup vs baseline: 1.6422x; 1.0456x over previous
//
#include <hip/hip_runtime.h>
#include <hip/hip_bf16.h>

#define B_   2
#define T_   2048
#define D_   2048
#define H_   16
#define DH_  128
#define TD3_ 6144   // 3*D

typedef __attribute__((ext_vector_type(8))) short   short8;
typedef __attribute__((ext_vector_type(8))) unsigned short ushort8v;
typedef __attribute__((ext_vector_type(4))) float   f32x4;
typedef __attribute__((ext_vector_type(4))) float   f4v;
typedef __attribute__((ext_vector_type(4))) unsigned short u16x4;

static __device__ __forceinline__ unsigned short f2bf(float f) {
  unsigned int u = __builtin_bit_cast(unsigned int, f);
  u += 0x7FFFu + ((u >> 16) & 1u);
  return (unsigned short)(u >> 16);
}
static __device__ __forceinline__ float bf2f(unsigned short u) {
  return __builtin_bit_cast(float, (unsigned int)u << 16);
}

static __device__ __forceinline__ void gload_lds16(const unsigned short* g, unsigned short* l) {
  __builtin_amdgcn_global_load_lds((const __attribute__((address_space(1))) void*)g,
                                   (__attribute__((address_space(3))) void*)l, 16, 0, 0);
}

// ---------------- fp32 -> bf16 elementwise cast (vectorized) ----------------
__global__ __launch_bounds__(256) void convert_f32_bf16(const float* __restrict__ X,
                                                        unsigned short* __restrict__ Y, int n4) {
  for (int i = blockIdx.x * blockDim.x + threadIdx.x; i < n4; i += gridDim.x * blockDim.x) {
    f4v v = ((const f4v*)X)[i];
    u16x4 o;
    o[0] = f2bf(v[0]); o[1] = f2bf(v[1]); o[2] = f2bf(v[2]); o[3] = f2bf(v[3]);
    ((u16x4*)Y)[i] = o;
  }
}

// ---------------- transpose fp32 [K][N] -> bf16 [N][K] ----------------
__global__ __launch_bounds__(256) void transpose_f32_bf16(const float* __restrict__ W,
                                                          unsigned short* __restrict__ WT,
                                                          int K, int N) {
  __shared__ float tile[32][33];
  int n0 = blockIdx.x * 32, k0 = blockIdx.y * 32;
  int tx = threadIdx.x & 31, ty = threadIdx.x >> 5;
#pragma unroll
  for (int r = 0; r < 4; r++)
    tile[ty + 8 * r][tx] = W[(size_t)(k0 + ty + 8 * r) * N + n0 + tx];
  __syncthreads();
#pragma unroll
  for (int r = 0; r < 4; r++)
    WT[(size_t)(n0 + ty + 8 * r) * K + k0 + tx] = f2bf(tile[tx][ty + 8 * r]);
}

// ---------------- V transpose: qkv V-third [b][t][h*DH+dh] -> vtg [b][h][dh][t] ----------------
__global__ __launch_bounds__(256) void vtr_kernel(const unsigned short* __restrict__ qkv,
                                                  unsigned short* __restrict__ vtg) {
  __shared__ unsigned short tile[64][68];
  const int t0 = blockIdx.x * 64;
  const int h = blockIdx.y >> 1, dh0 = (blockIdx.y & 1) * 64;
  const int b = blockIdx.z;
  const int tid = threadIdx.x;
  const unsigned short* src = qkv + (size_t)b * T_ * TD3_ + 2 * D_ + h * DH_ + dh0;
  {
    const int r = tid >> 3, cc = (tid & 7) * 8;
#pragma unroll
    for (int k = 0; k < 2; k++) {
      ushort8v v = *(const ushort8v*)(src + (size_t)(t0 + k * 32 + r) * TD3_ + cc);
      *(ushort8v*)&tile[k * 32 + r][cc] = v;
    }
  }
  __syncthreads();
  unsigned short* dst = vtg + ((size_t)(b * H_ + h) * DH_ + dh0) * T_ + t0;
  {
    const int d = tid >> 3, tc = (tid & 7) * 8;
#pragma unroll
    for (int k = 0; k < 2; k++) {
      ushort8v v;
#pragma unroll
      for (int j = 0; j < 8; j++) v[j] = tile[tc + j][k * 32 + d];
      *(ushort8v*)(dst + (size_t)(k * 32 + d) * T_ + tc) = v;
    }
  }
}

// ---------------- 256x256 8-phase bf16 GEMM: C[M][N] = A[M][K] * BT[N][K]^T ----------------
// 512 threads = 8 waves (2M x 4N). BK=64. LDS 128 KiB.
// Region-death staging: ph1 (t+1).B1->buf^1, ph2 (t+1).A1->buf^1,
//                       ph3 (t+2).B0->buf (B[buf] dead), ph4 (t+2).A0->buf (A[buf] dead).
// vmcnt(4) at tile end keeps only the two (t+2) stages in flight.
template <int OUTBF>
__global__ __launch_bounds__(512, 1) void gemm256(const unsigned short* __restrict__ A,
                                                  const unsigned short* __restrict__ BT,
                                                  void* __restrict__ C, int M, int N, int K) {
  __shared__ unsigned short lA[2][2][128 * 64];   // [dbuf][half][row*64+col]
  __shared__ unsigned short lB[2][2][128 * 64];

  const int tid = threadIdx.x;
  const int nwg = gridDim.x;
  const int swz = ((int)blockIdx.x & 7) * (nwg >> 3) + ((int)blockIdx.x >> 3);  // XCD swizzle
  const int nbx = N >> 8;
  const int m0 = (swz / nbx) * 256, n0 = (swz % nbx) * 256;
  const int l = tid & 63, lr = l & 15, lg = l >> 4;
  const int wid = tid >> 6, wm = wid >> 2, wn = wid & 3;
  const int bh = wn >> 1, br0 = (wn & 1) * 64;
  const int nk = K >> 6;

  f32x4 acc[8][4] = {};

  auto stageA = [&](int buf, int h, int kt) {
#pragma unroll
    for (int q = 0; q < 2; q++) {
      const int n = q * 512 + tid;            // 16B chunk id 0..1023
      const int row = n >> 3, ch = n & 7;     // linear LDS dest; inverse-swz source
      gload_lds16(A + (size_t)(m0 + h * 128 + row) * K + kt * 64 + ((ch ^ (row & 7)) << 3),
                  &lA[buf][h][n * 8]);
    }
  };
  auto stageB = [&](int buf, int h, int kt) {
#pragma unroll
    for (int q = 0; q < 2; q++) {
      const int n = q * 512 + tid;
      const int row = n >> 3, ch = n & 7;
      gload_lds16(BT + (size_t)(n0 + h * 128 + row) * K + kt * 64 + ((ch ^ (row & 7)) << 3),
                  &lB[buf][h][n * 8]);
    }
  };

  // ---- prologue: all of tile 0, plus tile 1's {B0, A0} (the "t-1 ph3/ph4" stages) ----
  stageB(0, 0, 0); stageA(0, 0, 0); stageB(0, 1, 0); stageA(0, 1, 0);
  if (nk > 1) {
    stageB(1, 0, 1); stageA(1, 0, 1);
    asm volatile("s_waitcnt vmcnt(4)" ::: "memory");   // tile 0 resident; tile 1 pair in flight
  } else {
    asm volatile("s_waitcnt vmcnt(0)" ::: "memory");
  }
  __builtin_amdgcn_s_barrier();

  short8 a[4][2], b0[2][2], b1[2][2];
  for (int kt = 0; kt < nk; kt++) {
    const int buf = kt & 1;

    // ======== phase 1: read A-quad0 + B-lo; stage (t+1).B1 -> buf^1; MFMA (mh0,nl) ========
#pragma unroll
    for (int mi = 0; mi < 4; mi++)
#pragma unroll
      for (int kk = 0; kk < 2; kk++) {
        const int row = mi * 16 + lr;
        a[mi][kk] = *(const short8*)&lA[buf][wm][row * 64 + (((kk * 4 + lg) ^ (lr & 7)) << 3)];
      }
#pragma unroll
    for (int ni = 0; ni < 2; ni++)
#pragma unroll
      for (int kk = 0; kk < 2; kk++) {
        const int row = br0 + ni * 16 + lr;
        b0[ni][kk] = *(const short8*)&lB[buf][bh][row * 64 + (((kk * 4 + lg) ^ (lr & 7)) << 3)];
      }
    if (kt + 1 < nk) stageB(buf ^ 1, 1, kt + 1);
    __builtin_amdgcn_s_barrier();
    __builtin_amdgcn_s_setprio(1);
#pragma unroll
    for (int mi = 0; mi < 4; mi++)
#pragma unroll
      for (int ni = 0; ni < 2; ni++)
#pragma unroll
        for (int kk = 0; kk < 2; kk++)
          acc[mi][ni] = __builtin_amdgcn_mfma_f32_16x16x32_bf16(a[mi][kk], b0[ni][kk], acc[mi][ni], 0, 0, 0);
    __builtin_amdgcn_s_setprio(0);
    __builtin_amdgcn_s_barrier();

    // ======== phase 2: read B-hi; stage (t+1).A1 -> buf^1; MFMA (mh0,nh) ========
#pragma unroll
    for (int ni = 0; ni < 2; ni++)
#pragma unroll
      for (int kk = 0; kk < 2; kk++) {
        const int row = br0 + (2 + ni) * 16 + lr;
        b1[ni][kk] = *(const short8*)&lB[buf][bh][row * 64 + (((kk * 4 + lg) ^ (lr & 7)) << 3)];
      }
    if (kt + 1 < nk) stageA(buf ^ 1, 1, kt + 1);
    __builtin_amdgcn_s_barrier();
    __builtin_amdgcn_s_setprio(1);
#pragma unroll
    for (int mi = 0; mi < 4; mi++)
#pragma unroll
      for (int ni = 0; ni < 2; ni++)
#pragma unroll
        for (int kk = 0; kk < 2; kk++)
          acc[mi][2 + ni] = __builtin_amdgcn_mfma_f32_16x16x32_bf16(a[mi][kk], b1[ni][kk], acc[mi][2 + ni], 0, 0, 0);
    __builtin_amdgcn_s_setprio(0);
    __builtin_amdgcn_s_barrier();

    // ======== phase 3: read A-quad1; stage (t+2).B0 -> buf (B[buf] reads done ph2); MFMA (mh1,nh) ========
#pragma unroll
    for (int mi = 0; mi < 4; mi++)
#pragma unroll
      for (int kk = 0; kk < 2; kk++) {
        const int row = (4 + mi) * 16 + lr;
        a[mi][kk] = *(const short8*)&lA[buf][wm][row * 64 + (((kk * 4 + lg) ^ (lr & 7)) << 3)];
      }
    if (kt + 2 < nk) stageB(buf, 0, kt + 2);
    __builtin_amdgcn_s_barrier();
    __builtin_amdgcn_s_setprio(1);
#pragma unroll
    for (int mi = 0; mi < 4; mi++)
#pragma unroll
      for (int ni = 0; ni < 2; ni++)
#pragma unroll
        for (int kk = 0; kk < 2; kk++)
          acc[4 + mi][2 + ni] = __builtin_amdgcn_mfma_f32_16x16x32_bf16(a[mi][kk], b1[ni][kk], acc[4 + mi][2 + ni], 0, 0, 0);
    __builtin_amdgcn_s_setprio(0);
    __builtin_amdgcn_s_barrier();

    // ======== phase 4: stage (t+2).A0 -> buf (A[buf] reads done ph3); MFMA (mh1,nl); vmcnt ========
    if (kt + 2 < nk) stageA(buf, 0, kt + 2);
    __builtin_amdgcn_s_barrier();
    __builtin_amdgcn_s_setprio(1);
#pragma unroll
    for (int mi = 0; mi < 4; mi++)
#pragma unroll
      for (int ni = 0; ni < 2; ni++)
#pragma unroll
        for (int kk = 0; kk < 2; kk++)
          acc[4 + mi][ni] = __builtin_amdgcn_mfma_f32_16x16x32_bf16(a[mi][kk], b0[ni][kk], acc[4 + mi][ni], 0, 0, 0);
    __builtin_amdgcn_s_setprio(0);
    if (kt + 2 < nk) asm volatile("s_waitcnt vmcnt(4)" ::: "memory");  // only (t+2).{B0,A0} may fly
    else             asm volatile("s_waitcnt vmcnt(0)" ::: "memory");  // tail: drain
    __builtin_amdgcn_s_barrier();
  }

  // ---- epilogue ----
#pragma unroll
  for (int mi = 0; mi < 8; mi++)
#pragma unroll
    for (int ni = 0; ni < 4; ni++)
#pragma unroll
      for (int i = 0; i < 4; i++) {
        const int row = m0 + wm * 128 + mi * 16 + lg * 4 + i;
        const int col = n0 + wn * 64 + ni * 16 + lr;
        if (OUTBF) ((unsigned short*)C)[(size_t)row * N + col] = f2bf(acc[mi][ni][i]);
        else       ((float*)C)[(size_t)row * N + col] = acc[mi][ni][i];
      }
}

// ---------------- flash attention (causal), QBLK=128, KVBLK=64, 2-phase pipeline ----------------
__global__ __launch_bounds__(256, 2) void attn_fa(const unsigned short* __restrict__ qkv,
                                                  const unsigned short* __restrict__ vtg,
                                                  unsigned short* __restrict__ out) {
  const int x = blockIdx.x, h = blockIdx.y, b = blockIdx.z;
  const int qtl = b ? x : (T_ / 128 - 1 - x);
  const int q0 = qtl * 128;
  const int tid = threadIdx.x, w = tid >> 6, l = tid & 63, lr = l & 15, lg = l >> 4;

  const unsigned short* Qb = qkv + (size_t)b * T_ * TD3_ + h * DH_;
  const unsigned short* Kb = Qb + D_;
  const unsigned short* Vt = vtg + ((size_t)b * H_ + h) * DH_ * T_;

  __shared__ unsigned short klds[2][64 * 128];
  __shared__ unsigned short vt[2][128 * 64];
  __shared__ unsigned short plds[4][32 * 64];

  const float scale = 0.08838834764831845f;

  short8 qf[2][4];
#pragma unroll
  for (int mi = 0; mi < 2; mi++) {
    const unsigned short* qrow = Qb + (size_t)(q0 + w * 32 + mi * 16 + lr) * TD3_;
#pragma unroll
    for (int ks = 0; ks < 4; ks++) {
      ushort8v qv = *(const ushort8v*)(qrow + ks * 32 + lg * 8);
      short8 qs;
#pragma unroll
      for (int j = 0; j < 8; j++) qs[j] = (short)f2bf(bf2f(qv[j]) * scale);
      qf[mi][ks] = qs;
    }
  }

  f32x4 oacc[2][8] = {};
  float mrun[2][4], lsum[2][4];
#pragma unroll
  for (int mi = 0; mi < 2; mi++)
#pragma unroll
    for (int i = 0; i < 4; i++) { mrun[mi][i] = -__builtin_inff(); lsum[mi][i] = 0.f; }

  auto STAGE = [&](int buf, int kv0) {
#pragma unroll
    for (int it = 0; it < 4; it++) {
      const int n = it * 256 + tid;
      { const int kv = n >> 4, ch = n & 15;
        gload_lds16(Kb + (size_t)(kv0 + kv) * TD3_ + ((ch ^ (kv & 7)) << 3),
                    &klds[buf][n * 8]); }
      { const int dh = n >> 3, ch = n & 7;
        gload_lds16(Vt + (size_t)dh * T_ + kv0 + ((ch ^ (dh & 7)) << 3),
                    &vt[buf][n * 8]); }
    }
  };

  const int nt = 2 * qtl + 2;
  STAGE(0, 0);
  __syncthreads();

  for (int t = 0; t < nt; t++) {
    const int buf = t & 1;
    if (t + 1 < nt) STAGE(buf ^ 1, (t + 1) * 64);

    const int kv0 = t * 64;
    const bool active = (kv0 <= q0 + w * 32 + 31);
    if (active) {
      f32x4 s[2][4] = {};
      __builtin_amdgcn_s_setprio(1);
#pragma unroll
      for (int nf = 0; nf < 4; nf++) {
        const int kv = nf * 16 + lr;
#pragma unroll
        for (int ks = 0; ks < 4; ks++) {
          short8 kf = *(const short8*)&klds[buf][kv * 128 + (((ks * 4 + lg) ^ (lr & 7)) << 3)];
#pragma unroll
          for (int mi = 0; mi < 2; mi++)
            s[mi][nf] = __builtin_amdgcn_mfma_f32_16x16x32_bf16(qf[mi][ks], kf, s[mi][nf], 0, 0, 0);
        }
      }
      __builtin_amdgcn_s_setprio(0);

      const bool needmask = (kv0 + 63 > q0 + w * 32);
      float pmax[2][4];
#pragma unroll
      for (int mi = 0; mi < 2; mi++)
#pragma unroll
        for (int i = 0; i < 4; i++) pmax[mi][i] = -__builtin_inff();
#pragma unroll
      for (int mi = 0; mi < 2; mi++)
#pragma unroll
        for (int nf = 0; nf < 4; nf++)
#pragma unroll
          for (int i = 0; i < 4; i++) {
            float xv = s[mi][nf][i];
            if (needmask) {
              const int qr = w * 32 + mi * 16 + lg * 4 + i;
              const int kc = nf * 16 + lr;
              if (kv0 + kc > q0 + qr) xv = -__builtin_inff();
            }
            s[mi][nf][i] = xv;
            pmax[mi][i] = fmaxf(pmax[mi][i], xv);
          }
#pragma unroll
      for (int m = 1; m < 16; m <<= 1)
#pragma unroll
        for (int mi = 0; mi < 2; mi++)
#pragma unroll
          for (int i = 0; i < 4; i++) pmax[mi][i] = fmaxf(pmax[mi][i], __shfl_xor(pmax[mi][i], m));

      float alpha[2][4], rsum[2][4];
#pragma unroll
      for (int mi = 0; mi < 2; mi++)
#pragma unroll
        for (int i = 0; i < 4; i++) {
          const float mn = fmaxf(mrun[mi][i], pmax[mi][i]);
          alpha[mi][i] = __expf(mrun[mi][i] - mn);
          mrun[mi][i] = mn;
          rsum[mi][i] = 0.f;
        }
#pragma unroll
      for (int mi = 0; mi < 2; mi++)
#pragma unroll
        for (int nf = 0; nf < 4; nf++)
#pragma unroll
          for (int i = 0; i < 4; i++) {
            const float p = __expf(s[mi][nf][i] - mrun[mi][i]);
            rsum[mi][i] += p;
            const int prow = mi * 16 + lg * 4 + i;
            plds[w][prow * 64 + ((nf * 16 + lr) ^ ((prow & 7) << 3))] = f2bf(p);
          }
#pragma unroll
      for (int m = 1; m < 16; m <<= 1)
#pragma unroll
        for (int mi = 0; mi < 2; mi++)
#pragma unroll
          for (int i = 0; i < 4; i++) rsum[mi][i] += __shfl_xor(rsum[mi][i], m);
#pragma unroll
      for (int mi = 0; mi < 2; mi++)
#pragma unroll
        for (int i = 0; i < 4; i++) lsum[mi][i] = lsum[mi][i] * alpha[mi][i] + rsum[mi][i];
#pragma unroll
      for (int mi = 0; mi < 2; mi++)
#pragma unroll
        for (int nf = 0; nf < 8; nf++)
#pragma unroll
          for (int i = 0; i < 4; i++) oacc[mi][nf][i] *= alpha[mi][i];

      __builtin_amdgcn_s_setprio(1);
#pragma unroll
      for (int kk = 0; kk < 2; kk++) {
        short8 pa[2];
#pragma unroll
        for (int mi = 0; mi < 2; mi++) {
          const int prow = mi * 16 + lr;
          pa[mi] = *(const short8*)&plds[w][prow * 64 + (((kk * 32 + lg * 8)) ^ ((prow & 7) << 3))];
        }
#pragma unroll
        for (int nf = 0; nf < 8; nf++) {
          const short8 vb = *(const short8*)&vt[buf][(nf * 16 + lr) * 64 + (((kk * 4 + lg) ^ (lr & 7)) << 3)];
#pragma unroll
          for (int mi = 0; mi < 2; mi++)
            oacc[mi][nf] = __builtin_amdgcn_mfma_f32_16x16x32_bf16(pa[mi], vb, oacc[mi][nf], 0, 0, 0);
        }
      }
      __builtin_amdgcn_s_setprio(0);
    }
    __syncthreads();
  }

  float rinv[2][4];
#pragma unroll
  for (int mi = 0; mi < 2; mi++)
#pragma unroll
    for (int i = 0; i < 4; i++) rinv[mi][i] = 1.f / lsum[mi][i];
#pragma unroll
  for (int mi = 0; mi < 2; mi++) {
    unsigned short* orow = out + ((size_t)b * T_ + q0 + w * 32 + mi * 16 + lg * 4) * D_ + h * DH_;
#pragma unroll
    for (int nf = 0; nf < 8; nf++)
#pragma unroll
      for (int i = 0; i < 4; i++)
        orow[(size_t)i * D_ + nf * 16 + lr] = f2bf(oacc[mi][nf][i] * rinv[mi][i]);
  }
}

extern "C" void kernel_launch(void* const* d_in, const int* in_sizes, int n_in,
                              void* d_out, int out_size, void* d_ws, size_t ws_size,
                              hipStream_t stream) {
  const float* x    = (const float*)d_in[0];
  const float* wqkv = (const float*)d_in[1];
  const float* wo   = (const float*)d_in[2];
  float* out = (float*)d_out;

  char* ws = (char*)d_ws;
  unsigned short* xb    = (unsigned short*)(ws);               // 16.8 MB (reused as attn out)
  unsigned short* wqkvt = (unsigned short*)(ws + 16777216);    // 25.2 MB (dead after gemm1)
  unsigned short* vtg   = (unsigned short*)(ws + 16777216);    // 16.8 MB, overlays wqkvt
  unsigned short* wot   = (unsigned short*)(ws + 41943040);    //  8.4 MB
  unsigned short* qkv   = (unsigned short*)(ws + 50331648);    // 50.3 MB  (end 100.7 MB)
  unsigned short* attn  = xb;   // xb dead after GEMM1

  convert_f32_bf16<<<2048, 256, 0, stream>>>(x, xb, B_ * T_ * D_ / 4);
  transpose_f32_bf16<<<dim3(TD3_ / 32, D_ / 32), 256, 0, stream>>>(wqkv, wqkvt, D_, TD3_);
  transpose_f32_bf16<<<dim3(D_ / 32, D_ / 32), 256, 0, stream>>>(wo, wot, D_, D_);

  gemm256<1><<<dim3((TD3_ / 256) * ((B_ * T_) / 256)), 512, 0, stream>>>(xb, wqkvt, qkv,
                                                                         B_ * T_, TD3_, D_);
  vtr_kernel<<<dim3(T_ / 64, H_ * 2, B_), 256, 0, stream>>>(qkv, vtg);
  attn_fa<<<dim3(T_ / 128, H_, B_), 256, 0, stream>>>(qkv, vtg, attn);
  gemm256<0><<<dim3((D_ / 256) * ((B_ * T_) / 256)), 512, 0, stream>>>(attn, wot, out,
                                                                       B_ * T_, D_, D_);
}

// Round 8
// 307.436 us; speedup vs baseline: 1.6658x; 1.0144x over previous
//
#include <hip/hip_runtime.h>
#include <hip/hip_bf16.h>

#define B_   2
#define T_   2048
#define D_   2048
#define H_   16
#define DH_  128
#define TD3_ 6144   // 3*D

typedef __attribute__((ext_vector_type(8))) short   short8;
typedef __attribute__((ext_vector_type(8))) unsigned short ushort8v;
typedef __attribute__((ext_vector_type(4))) float   f32x4;
typedef __attribute__((ext_vector_type(4))) float   f4v;
typedef __attribute__((ext_vector_type(4))) unsigned short u16x4;

static __device__ __forceinline__ unsigned short f2bf(float f) {
  unsigned int u = __builtin_bit_cast(unsigned int, f);
  u += 0x7FFFu + ((u >> 16) & 1u);
  return (unsigned short)(u >> 16);
}
static __device__ __forceinline__ float bf2f(unsigned short u) {
  return __builtin_bit_cast(float, (unsigned int)u << 16);
}

static __device__ __forceinline__ void gload_lds16(const unsigned short* g, unsigned short* l) {
  __builtin_amdgcn_global_load_lds((const __attribute__((address_space(1))) void*)g,
                                   (__attribute__((address_space(3))) void*)l, 16, 0, 0);
}

// ---------------- fp32 -> bf16 elementwise cast (vectorized) ----------------
__global__ __launch_bounds__(256) void convert_f32_bf16(const float* __restrict__ X,
                                                        unsigned short* __restrict__ Y, int n4) {
  for (int i = blockIdx.x * blockDim.x + threadIdx.x; i < n4; i += gridDim.x * blockDim.x) {
    f4v v = ((const f4v*)X)[i];
    u16x4 o;
    o[0] = f2bf(v[0]); o[1] = f2bf(v[1]); o[2] = f2bf(v[2]); o[3] = f2bf(v[3]);
    ((u16x4*)Y)[i] = o;
  }
}

// ---------------- transpose fp32 [K][N] -> bf16 [N][K] ----------------
__global__ __launch_bounds__(256) void transpose_f32_bf16(const float* __restrict__ W,
                                                          unsigned short* __restrict__ WT,
                                                          int K, int N) {
  __shared__ float tile[32][33];
  int n0 = blockIdx.x * 32, k0 = blockIdx.y * 32;
  int tx = threadIdx.x & 31, ty = threadIdx.x >> 5;
#pragma unroll
  for (int r = 0; r < 4; r++)
    tile[ty + 8 * r][tx] = W[(size_t)(k0 + ty + 8 * r) * N + n0 + tx];
  __syncthreads();
#pragma unroll
  for (int r = 0; r < 4; r++)
    WT[(size_t)(n0 + ty + 8 * r) * K + k0 + tx] = f2bf(tile[tx][ty + 8 * r]);
}

// ---------------- V transpose: qkv V-third [b][t][h*DH+dh] -> vtg [b][h][dh][t] ----------------
__global__ __launch_bounds__(256) void vtr_kernel(const unsigned short* __restrict__ qkv,
                                                  unsigned short* __restrict__ vtg) {
  __shared__ unsigned short tile[64][68];
  const int t0 = blockIdx.x * 64;
  const int h = blockIdx.y >> 1, dh0 = (blockIdx.y & 1) * 64;
  const int b = blockIdx.z;
  const int tid = threadIdx.x;
  const unsigned short* src = qkv + (size_t)b * T_ * TD3_ + 2 * D_ + h * DH_ + dh0;
  {
    const int r = tid >> 3, cc = (tid & 7) * 8;
#pragma unroll
    for (int k = 0; k < 2; k++) {
      ushort8v v = *(const ushort8v*)(src + (size_t)(t0 + k * 32 + r) * TD3_ + cc);
      *(ushort8v*)&tile[k * 32 + r][cc] = v;
    }
  }
  __syncthreads();
  unsigned short* dst = vtg + ((size_t)(b * H_ + h) * DH_ + dh0) * T_ + t0;
  {
    const int d = tid >> 3, tc = (tid & 7) * 8;
#pragma unroll
    for (int k = 0; k < 2; k++) {
      ushort8v v;
#pragma unroll
      for (int j = 0; j < 8; j++) v[j] = tile[tc + j][k * 32 + d];
      *(ushort8v*)(dst + (size_t)(k * 32 + d) * T_ + tc) = v;
    }
  }
}

// ---------------- 256x256 8-phase bf16 GEMM (QKV): C bf16 ----------------
// 512 threads = 8 waves (2M x 4N). BK=64. LDS 128 KiB. XCD-chunked tile map:
// each XCD owns N/(8*256) consecutive n-tiles (B panel L2-resident), iterates m.
__global__ __launch_bounds__(512, 1) void gemm256(const unsigned short* __restrict__ A,
                                                  const unsigned short* __restrict__ BT,
                                                  unsigned short* __restrict__ C,
                                                  int M, int N, int K) {
  __shared__ unsigned short lA[2][2][128 * 64];   // [dbuf][half][row*64+col]
  __shared__ unsigned short lB[2][2][128 * 64];

  const int tid = threadIdx.x;
  const int bid = (int)blockIdx.x;
  const int nbx = N >> 8;            // n-tiles
  const int npx = nbx >> 3;          // n-tiles per XCD
  const int xcd = bid & 7, idx = bid >> 3;
  const int n0 = (xcd * npx + idx % npx) * 256;
  const int m0 = (idx / npx) * 256;
  const int l = tid & 63, lr = l & 15, lg = l >> 4;
  const int wid = tid >> 6, wm = wid >> 2, wn = wid & 3;
  const int bh = wn >> 1, br0 = (wn & 1) * 64;
  const int nk = K >> 6;

  f32x4 acc[8][4] = {};

  auto stageA = [&](int buf, int h, int kt) {
#pragma unroll
    for (int q = 0; q < 2; q++) {
      const int n = q * 512 + tid;            // 16B chunk id 0..1023
      const int row = n >> 3, ch = n & 7;     // linear LDS dest; inverse-swz source
      gload_lds16(A + (size_t)(m0 + h * 128 + row) * K + kt * 64 + ((ch ^ (row & 7)) << 3),
                  &lA[buf][h][n * 8]);
    }
  };
  auto stageB = [&](int buf, int h, int kt) {
#pragma unroll
    for (int q = 0; q < 2; q++) {
      const int n = q * 512 + tid;
      const int row = n >> 3, ch = n & 7;
      gload_lds16(BT + (size_t)(n0 + h * 128 + row) * K + kt * 64 + ((ch ^ (row & 7)) << 3),
                  &lB[buf][h][n * 8]);
    }
  };

  // ---- prologue: all of tile 0, plus tile 1's {B0, A0} ----
  stageB(0, 0, 0); stageA(0, 0, 0); stageB(0, 1, 0); stageA(0, 1, 0);
  if (nk > 1) {
    stageB(1, 0, 1); stageA(1, 0, 1);
    asm volatile("s_waitcnt vmcnt(4)" ::: "memory");
  } else {
    asm volatile("s_waitcnt vmcnt(0)" ::: "memory");
  }
  __builtin_amdgcn_s_barrier();

  short8 a[4][2], b0[2][2], b1[2][2];
  for (int kt = 0; kt < nk; kt++) {
    const int buf = kt & 1;

    // ph1: read A-quad0 + B-lo; stage (t+1).B1 -> buf^1; MFMA (mh0,nl)
#pragma unroll
    for (int mi = 0; mi < 4; mi++)
#pragma unroll
      for (int kk = 0; kk < 2; kk++) {
        const int row = mi * 16 + lr;
        a[mi][kk] = *(const short8*)&lA[buf][wm][row * 64 + (((kk * 4 + lg) ^ (lr & 7)) << 3)];
      }
#pragma unroll
    for (int ni = 0; ni < 2; ni++)
#pragma unroll
      for (int kk = 0; kk < 2; kk++) {
        const int row = br0 + ni * 16 + lr;
        b0[ni][kk] = *(const short8*)&lB[buf][bh][row * 64 + (((kk * 4 + lg) ^ (lr & 7)) << 3)];
      }
    if (kt + 1 < nk) stageB(buf ^ 1, 1, kt + 1);
    __builtin_amdgcn_s_barrier();
    __builtin_amdgcn_s_setprio(1);
#pragma unroll
    for (int mi = 0; mi < 4; mi++)
#pragma unroll
      for (int ni = 0; ni < 2; ni++)
#pragma unroll
        for (int kk = 0; kk < 2; kk++)
          acc[mi][ni] = __builtin_amdgcn_mfma_f32_16x16x32_bf16(a[mi][kk], b0[ni][kk], acc[mi][ni], 0, 0, 0);
    __builtin_amdgcn_s_setprio(0);
    __builtin_amdgcn_s_barrier();

    // ph2: read B-hi; stage (t+1).A1 -> buf^1; MFMA (mh0,nh)
#pragma unroll
    for (int ni = 0; ni < 2; ni++)
#pragma unroll
      for (int kk = 0; kk < 2; kk++) {
        const int row = br0 + (2 + ni) * 16 + lr;
        b1[ni][kk] = *(const short8*)&lB[buf][bh][row * 64 + (((kk * 4 + lg) ^ (lr & 7)) << 3)];
      }
    if (kt + 1 < nk) stageA(buf ^ 1, 1, kt + 1);
    __builtin_amdgcn_s_barrier();
    __builtin_amdgcn_s_setprio(1);
#pragma unroll
    for (int mi = 0; mi < 4; mi++)
#pragma unroll
      for (int ni = 0; ni < 2; ni++)
#pragma unroll
        for (int kk = 0; kk < 2; kk++)
          acc[mi][2 + ni] = __builtin_amdgcn_mfma_f32_16x16x32_bf16(a[mi][kk], b1[ni][kk], acc[mi][2 + ni], 0, 0, 0);
    __builtin_amdgcn_s_setprio(0);
    __builtin_amdgcn_s_barrier();

    // ph3: read A-quad1; stage (t+2).B0 -> buf; MFMA (mh1,nh)
#pragma unroll
    for (int mi = 0; mi < 4; mi++)
#pragma unroll
      for (int kk = 0; kk < 2; kk++) {
        const int row = (4 + mi) * 16 + lr;
        a[mi][kk] = *(const short8*)&lA[buf][wm][row * 64 + (((kk * 4 + lg) ^ (lr & 7)) << 3)];
      }
    if (kt + 2 < nk) stageB(buf, 0, kt + 2);
    __builtin_amdgcn_s_barrier();
    __builtin_amdgcn_s_setprio(1);
#pragma unroll
    for (int mi = 0; mi < 4; mi++)
#pragma unroll
      for (int ni = 0; ni < 2; ni++)
#pragma unroll
        for (int kk = 0; kk < 2; kk++)
          acc[4 + mi][2 + ni] = __builtin_amdgcn_mfma_f32_16x16x32_bf16(a[mi][kk], b1[ni][kk], acc[4 + mi][2 + ni], 0, 0, 0);
    __builtin_amdgcn_s_setprio(0);
    __builtin_amdgcn_s_barrier();

    // ph4: stage (t+2).A0 -> buf; MFMA (mh1,nl); vmcnt
    if (kt + 2 < nk) stageA(buf, 0, kt + 2);
    __builtin_amdgcn_s_barrier();
    __builtin_amdgcn_s_setprio(1);
#pragma unroll
    for (int mi = 0; mi < 4; mi++)
#pragma unroll
      for (int ni = 0; ni < 2; ni++)
#pragma unroll
        for (int kk = 0; kk < 2; kk++)
          acc[4 + mi][ni] = __builtin_amdgcn_mfma_f32_16x16x32_bf16(a[mi][kk], b0[ni][kk], acc[4 + mi][ni], 0, 0, 0);
    __builtin_amdgcn_s_setprio(0);
    if (kt + 2 < nk) asm volatile("s_waitcnt vmcnt(4)" ::: "memory");
    else             asm volatile("s_waitcnt vmcnt(0)" ::: "memory");
    __builtin_amdgcn_s_barrier();
  }

#pragma unroll
  for (int mi = 0; mi < 8; mi++)
#pragma unroll
    for (int ni = 0; ni < 4; ni++)
#pragma unroll
      for (int i = 0; i < 4; i++) {
        const int row = m0 + wm * 128 + mi * 16 + lg * 4 + i;
        const int col = n0 + wn * 64 + ni * 16 + lr;
        C[(size_t)row * N + col] = f2bf(acc[mi][ni][i]);
      }
}

// ---------------- 128x256 2-phase bf16 GEMM (output proj): C fp32 ----------------
// 512 threads = 8 waves (2M x 4N), per-wave 64x64. LDS 96 KiB. Grid = (M/128)*(N/256)
// = 256 blocks = 1/CU. Next tile staged at ph1-top into buf^1; drained at tile end.
__global__ __launch_bounds__(512, 1) void gemm_op(const unsigned short* __restrict__ A,
                                                  const unsigned short* __restrict__ BT,
                                                  float* __restrict__ C,
                                                  int M, int N, int K) {
  __shared__ unsigned short lA[2][128 * 64];      // 32 KB
  __shared__ unsigned short lB[2][2][128 * 64];   // 64 KB

  const int tid = threadIdx.x;
  const int bid = (int)blockIdx.x;
  const int xcd = bid & 7, idx = bid >> 3;        // N/256 == 8: n-tile = xcd
  const int n0 = xcd * 256, m0 = idx * 128;
  const int l = tid & 63, lr = l & 15, lg = l >> 4;
  const int wid = tid >> 6, wm = wid >> 2, wn = wid & 3;
  const int bh = wn >> 1, br0 = (wn & 1) * 64;
  const int nk = K >> 6;

  f32x4 acc[4][4] = {};

  auto stageA = [&](int buf, int kt) {
#pragma unroll
    for (int q = 0; q < 2; q++) {
      const int n = q * 512 + tid;                // 1024 chunks = 128 rows x 8
      const int row = n >> 3, ch = n & 7;
      gload_lds16(A + (size_t)(m0 + row) * K + kt * 64 + ((ch ^ (row & 7)) << 3),
                  &lA[buf][n * 8]);
    }
  };
  auto stageB = [&](int buf, int h, int kt) {
#pragma unroll
    for (int q = 0; q < 2; q++) {
      const int n = q * 512 + tid;
      const int row = n >> 3, ch = n & 7;
      gload_lds16(BT + (size_t)(n0 + h * 128 + row) * K + kt * 64 + ((ch ^ (row & 7)) << 3),
                  &lB[buf][h][n * 8]);
    }
  };

  stageB(0, 0, 0); stageB(0, 1, 0); stageA(0, 0);
  asm volatile("s_waitcnt vmcnt(0)" ::: "memory");
  __builtin_amdgcn_s_barrier();

  short8 a[4][2], b0[2][2], b1[2][2];
  for (int kt = 0; kt < nk; kt++) {
    const int buf = kt & 1;

    // ph1: issue all (t+1) stages first (max latency slack), read A + B-lo, MFMA
    if (kt + 1 < nk) { stageB(buf ^ 1, 0, kt + 1); stageB(buf ^ 1, 1, kt + 1); stageA(buf ^ 1, kt + 1); }
#pragma unroll
    for (int mi = 0; mi < 4; mi++)
#pragma unroll
      for (int kk = 0; kk < 2; kk++) {
        const int row = wm * 64 + mi * 16 + lr;
        a[mi][kk] = *(const short8*)&lA[buf][row * 64 + (((kk * 4 + lg) ^ (lr & 7)) << 3)];
      }
#pragma unroll
    for (int ni = 0; ni < 2; ni++)
#pragma unroll
      for (int kk = 0; kk < 2; kk++) {
        const int row = br0 + ni * 16 + lr;
        b0[ni][kk] = *(const short8*)&lB[buf][bh][row * 64 + (((kk * 4 + lg) ^ (lr & 7)) << 3)];
      }
    __builtin_amdgcn_s_barrier();
    __builtin_amdgcn_s_setprio(1);
#pragma unroll
    for (int mi = 0; mi < 4; mi++)
#pragma unroll
      for (int ni = 0; ni < 2; ni++)
#pragma unroll
        for (int kk = 0; kk < 2; kk++)
          acc[mi][ni] = __builtin_amdgcn_mfma_f32_16x16x32_bf16(a[mi][kk], b0[ni][kk], acc[mi][ni], 0, 0, 0);
    __builtin_amdgcn_s_setprio(0);
    __builtin_amdgcn_s_barrier();

    // ph2: read B-hi, MFMA, drain staging, swap
#pragma unroll
    for (int ni = 0; ni < 2; ni++)
#pragma unroll
      for (int kk = 0; kk < 2; kk++) {
        const int row = br0 + (2 + ni) * 16 + lr;
        b1[ni][kk] = *(const short8*)&lB[buf][bh][row * 64 + (((kk * 4 + lg) ^ (lr & 7)) << 3)];
      }
    __builtin_amdgcn_s_barrier();
    __builtin_amdgcn_s_setprio(1);
#pragma unroll
    for (int mi = 0; mi < 4; mi++)
#pragma unroll
      for (int ni = 0; ni < 2; ni++)
#pragma unroll
        for (int kk = 0; kk < 2; kk++)
          acc[mi][2 + ni] = __builtin_amdgcn_mfma_f32_16x16x32_bf16(a[mi][kk], b1[ni][kk], acc[mi][2 + ni], 0, 0, 0);
    __builtin_amdgcn_s_setprio(0);
    asm volatile("s_waitcnt vmcnt(0)" ::: "memory");
    __builtin_amdgcn_s_barrier();
  }

#pragma unroll
  for (int mi = 0; mi < 4; mi++)
#pragma unroll
    for (int ni = 0; ni < 4; ni++)
#pragma unroll
      for (int i = 0; i < 4; i++) {
        const int row = m0 + wm * 64 + mi * 16 + lg * 4 + i;
        const int col = n0 + wn * 64 + ni * 16 + lr;
        C[(size_t)row * N + col] = acc[mi][ni][i];
      }
}

// ---------------- flash attention (causal), QBLK=128, KVBLK=64, 2-phase pipeline ----------------
__global__ __launch_bounds__(256, 2) void attn_fa(const unsigned short* __restrict__ qkv,
                                                  const unsigned short* __restrict__ vtg,
                                                  unsigned short* __restrict__ out) {
  const int x = blockIdx.x, h = blockIdx.y, b = blockIdx.z;
  const int qtl = b ? x : (T_ / 128 - 1 - x);
  const int q0 = qtl * 128;
  const int tid = threadIdx.x, w = tid >> 6, l = tid & 63, lr = l & 15, lg = l >> 4;

  const unsigned short* Qb = qkv + (size_t)b * T_ * TD3_ + h * DH_;
  const unsigned short* Kb = Qb + D_;
  const unsigned short* Vt = vtg + ((size_t)b * H_ + h) * DH_ * T_;

  __shared__ unsigned short klds[2][64 * 128];
  __shared__ unsigned short vt[2][128 * 64];
  __shared__ unsigned short plds[4][32 * 64];

  const float scale = 0.08838834764831845f;

  short8 qf[2][4];
#pragma unroll
  for (int mi = 0; mi < 2; mi++) {
    const unsigned short* qrow = Qb + (size_t)(q0 + w * 32 + mi * 16 + lr) * TD3_;
#pragma unroll
    for (int ks = 0; ks < 4; ks++) {
      ushort8v qv = *(const ushort8v*)(qrow + ks * 32 + lg * 8);
      short8 qs;
#pragma unroll
      for (int j = 0; j < 8; j++) qs[j] = (short)f2bf(bf2f(qv[j]) * scale);
      qf[mi][ks] = qs;
    }
  }

  f32x4 oacc[2][8] = {};
  float mrun[2][4], lsum[2][4];
#pragma unroll
  for (int mi = 0; mi < 2; mi++)
#pragma unroll
    for (int i = 0; i < 4; i++) { mrun[mi][i] = -__builtin_inff(); lsum[mi][i] = 0.f; }

  auto STAGE = [&](int buf, int kv0) {
#pragma unroll
    for (int it = 0; it < 4; it++) {
      const int n = it * 256 + tid;
      { const int kv = n >> 4, ch = n & 15;
        gload_lds16(Kb + (size_t)(kv0 + kv) * TD3_ + ((ch ^ (kv & 7)) << 3),
                    &klds[buf][n * 8]); }
      { const int dh = n >> 3, ch = n & 7;
        gload_lds16(Vt + (size_t)dh * T_ + kv0 + ((ch ^ (dh & 7)) << 3),
                    &vt[buf][n * 8]); }
    }
  };

  const int nt = 2 * qtl + 2;
  STAGE(0, 0);
  __syncthreads();

  for (int t = 0; t < nt; t++) {
    const int buf = t & 1;
    if (t + 1 < nt) STAGE(buf ^ 1, (t + 1) * 64);

    const int kv0 = t * 64;
    const bool active = (kv0 <= q0 + w * 32 + 31);
    if (active) {
      f32x4 s[2][4] = {};
      __builtin_amdgcn_s_setprio(1);
#pragma unroll
      for (int nf = 0; nf < 4; nf++) {
        const int kv = nf * 16 + lr;
#pragma unroll
        for (int ks = 0; ks < 4; ks++) {
          short8 kf = *(const short8*)&klds[buf][kv * 128 + (((ks * 4 + lg) ^ (lr & 7)) << 3)];
#pragma unroll
          for (int mi = 0; mi < 2; mi++)
            s[mi][nf] = __builtin_amdgcn_mfma_f32_16x16x32_bf16(qf[mi][ks], kf, s[mi][nf], 0, 0, 0);
        }
      }
      __builtin_amdgcn_s_setprio(0);

      const bool needmask = (kv0 + 63 > q0 + w * 32);
      float pmax[2][4];
#pragma unroll
      for (int mi = 0; mi < 2; mi++)
#pragma unroll
        for (int i = 0; i < 4; i++) pmax[mi][i] = -__builtin_inff();
#pragma unroll
      for (int mi = 0; mi < 2; mi++)
#pragma unroll
        for (int nf = 0; nf < 4; nf++)
#pragma unroll
          for (int i = 0; i < 4; i++) {
            float xv = s[mi][nf][i];
            if (needmask) {
              const int qr = w * 32 + mi * 16 + lg * 4 + i;
              const int kc = nf * 16 + lr;
              if (kv0 + kc > q0 + qr) xv = -__builtin_inff();
            }
            s[mi][nf][i] = xv;
            pmax[mi][i] = fmaxf(pmax[mi][i], xv);
          }
#pragma unroll
      for (int m = 1; m < 16; m <<= 1)
#pragma unroll
        for (int mi = 0; mi < 2; mi++)
#pragma unroll
          for (int i = 0; i < 4; i++) pmax[mi][i] = fmaxf(pmax[mi][i], __shfl_xor(pmax[mi][i], m));

      float alpha[2][4], rsum[2][4];
#pragma unroll
      for (int mi = 0; mi < 2; mi++)
#pragma unroll
        for (int i = 0; i < 4; i++) {
          const float mn = fmaxf(mrun[mi][i], pmax[mi][i]);
          alpha[mi][i] = __expf(mrun[mi][i] - mn);
          mrun[mi][i] = mn;
          rsum[mi][i] = 0.f;
        }
#pragma unroll
      for (int mi = 0; mi < 2; mi++)
#pragma unroll
        for (int nf = 0; nf < 4; nf++)
#pragma unroll
          for (int i = 0; i < 4; i++) {
            const float p = __expf(s[mi][nf][i] - mrun[mi][i]);
            rsum[mi][i] += p;
            const int prow = mi * 16 + lg * 4 + i;
            plds[w][prow * 64 + ((nf * 16 + lr) ^ ((prow & 7) << 3))] = f2bf(p);
          }
#pragma unroll
      for (int m = 1; m < 16; m <<= 1)
#pragma unroll
        for (int mi = 0; mi < 2; mi++)
#pragma unroll
          for (int i = 0; i < 4; i++) rsum[mi][i] += __shfl_xor(rsum[mi][i], m);
#pragma unroll
      for (int mi = 0; mi < 2; mi++)
#pragma unroll
        for (int i = 0; i < 4; i++) lsum[mi][i] = lsum[mi][i] * alpha[mi][i] + rsum[mi][i];
#pragma unroll
      for (int mi = 0; mi < 2; mi++)
#pragma unroll
        for (int nf = 0; nf < 8; nf++)
#pragma unroll
          for (int i = 0; i < 4; i++) oacc[mi][nf][i] *= alpha[mi][i];

      __builtin_amdgcn_s_setprio(1);
#pragma unroll
      for (int kk = 0; kk < 2; kk++) {
        short8 pa[2];
#pragma unroll
        for (int mi = 0; mi < 2; mi++) {
          const int prow = mi * 16 + lr;
          pa[mi] = *(const short8*)&plds[w][prow * 64 + (((kk * 32 + lg * 8)) ^ ((prow & 7) << 3))];
        }
#pragma unroll
        for (int nf = 0; nf < 8; nf++) {
          const short8 vb = *(const short8*)&vt[buf][(nf * 16 + lr) * 64 + (((kk * 4 + lg) ^ (lr & 7)) << 3)];
#pragma unroll
          for (int mi = 0; mi < 2; mi++)
            oacc[mi][nf] = __builtin_amdgcn_mfma_f32_16x16x32_bf16(pa[mi], vb, oacc[mi][nf], 0, 0, 0);
        }
      }
      __builtin_amdgcn_s_setprio(0);
    }
    __syncthreads();
  }

  float rinv[2][4];
#pragma unroll
  for (int mi = 0; mi < 2; mi++)
#pragma unroll
    for (int i = 0; i < 4; i++) rinv[mi][i] = 1.f / lsum[mi][i];
#pragma unroll
  for (int mi = 0; mi < 2; mi++) {
    unsigned short* orow = out + ((size_t)b * T_ + q0 + w * 32 + mi * 16 + lg * 4) * D_ + h * DH_;
#pragma unroll
    for (int nf = 0; nf < 8; nf++)
#pragma unroll
      for (int i = 0; i < 4; i++)
        orow[(size_t)i * D_ + nf * 16 + lr] = f2bf(oacc[mi][nf][i] * rinv[mi][i]);
  }
}

extern "C" void kernel_launch(void* const* d_in, const int* in_sizes, int n_in,
                              void* d_out, int out_size, void* d_ws, size_t ws_size,
                              hipStream_t stream) {
  const float* x    = (const float*)d_in[0];
  const float* wqkv = (const float*)d_in[1];
  const float* wo   = (const float*)d_in[2];
  float* out = (float*)d_out;

  char* ws = (char*)d_ws;
  unsigned short* xb    = (unsigned short*)(ws);               // 16.8 MB (reused as attn out)
  unsigned short* wqkvt = (unsigned short*)(ws + 16777216);    // 25.2 MB (dead after gemm1)
  unsigned short* vtg   = (unsigned short*)(ws + 16777216);    // 16.8 MB, overlays wqkvt
  unsigned short* wot   = (unsigned short*)(ws + 41943040);    //  8.4 MB
  unsigned short* qkv   = (unsigned short*)(ws + 50331648);    // 50.3 MB  (end 100.7 MB)
  unsigned short* attn  = xb;   // xb dead after GEMM1

  convert_f32_bf16<<<2048, 256, 0, stream>>>(x, xb, B_ * T_ * D_ / 4);
  transpose_f32_bf16<<<dim3(TD3_ / 32, D_ / 32), 256, 0, stream>>>(wqkv, wqkvt, D_, TD3_);
  transpose_f32_bf16<<<dim3(D_ / 32, D_ / 32), 256, 0, stream>>>(wo, wot, D_, D_);

  gemm256<<<dim3((TD3_ / 256) * ((B_ * T_) / 256)), 512, 0, stream>>>(xb, wqkvt, qkv,
                                                                      B_ * T_, TD3_, D_);
  vtr_kernel<<<dim3(T_ / 64, H_ * 2, B_), 256, 0, stream>>>(qkv, vtg);
  attn_fa<<<dim3(T_ / 128, H_, B_), 256, 0, stream>>>(qkv, vtg, attn);
  gemm_op<<<dim3((D_ / 256) * ((B_ * T_) / 128)), 512, 0, stream>>>(attn, wot, out,
                                                                    B_ * T_, D_, D_);
}

// Round 9
// 302.410 us; speedup vs baseline: 1.6935x; 1.0166x over previous
//
#include <hip/hip_runtime.h>
#include <hip/hip_bf16.h>

#define B_   2
#define T_   2048
#define D_   2048
#define H_   16
#define DH_  128
#define TD3_ 6144   // 3*D

typedef __attribute__((ext_vector_type(8))) short   short8;
typedef __attribute__((ext_vector_type(8))) unsigned short ushort8v;
typedef __attribute__((ext_vector_type(4))) float   f32x4;
typedef __attribute__((ext_vector_type(4))) float   f4v;
typedef __attribute__((ext_vector_type(4))) unsigned short u16x4;

static __device__ __forceinline__ unsigned short f2bf(float f) {
  unsigned int u = __builtin_bit_cast(unsigned int, f);
  u += 0x7FFFu + ((u >> 16) & 1u);
  return (unsigned short)(u >> 16);
}
static __device__ __forceinline__ float bf2f(unsigned short u) {
  return __builtin_bit_cast(float, (unsigned int)u << 16);
}

static __device__ __forceinline__ void gload_lds16(const unsigned short* g, unsigned short* l) {
  __builtin_amdgcn_global_load_lds((const __attribute__((address_space(1))) void*)g,
                                   (__attribute__((address_space(3))) void*)l, 16, 0, 0);
}

// ---------------- fp32 -> bf16 elementwise cast (vectorized) ----------------
__global__ __launch_bounds__(256) void convert_f32_bf16(const float* __restrict__ X,
                                                        unsigned short* __restrict__ Y, int n4) {
  for (int i = blockIdx.x * blockDim.x + threadIdx.x; i < n4; i += gridDim.x * blockDim.x) {
    f4v v = ((const f4v*)X)[i];
    u16x4 o;
    o[0] = f2bf(v[0]); o[1] = f2bf(v[1]); o[2] = f2bf(v[2]); o[3] = f2bf(v[3]);
    ((u16x4*)Y)[i] = o;
  }
}

// ---------------- transpose fp32 [K][N] -> bf16 [N][K] ----------------
__global__ __launch_bounds__(256) void transpose_f32_bf16(const float* __restrict__ W,
                                                          unsigned short* __restrict__ WT,
                                                          int K, int N) {
  __shared__ float tile[32][33];
  int n0 = blockIdx.x * 32, k0 = blockIdx.y * 32;
  int tx = threadIdx.x & 31, ty = threadIdx.x >> 5;
#pragma unroll
  for (int r = 0; r < 4; r++)
    tile[ty + 8 * r][tx] = W[(size_t)(k0 + ty + 8 * r) * N + n0 + tx];
  __syncthreads();
#pragma unroll
  for (int r = 0; r < 4; r++)
    WT[(size_t)(n0 + ty + 8 * r) * K + k0 + tx] = f2bf(tile[tx][ty + 8 * r]);
}

// ---------------- V transpose: qkv V-third [b][t][h*DH+dh] -> vtg [b][h][dh][t] ----------------
__global__ __launch_bounds__(256) void vtr_kernel(const unsigned short* __restrict__ qkv,
                                                  unsigned short* __restrict__ vtg) {
  __shared__ unsigned short tile[64][68];
  const int t0 = blockIdx.x * 64;
  const int h = blockIdx.y >> 1, dh0 = (blockIdx.y & 1) * 64;
  const int b = blockIdx.z;
  const int tid = threadIdx.x;
  const unsigned short* src = qkv + (size_t)b * T_ * TD3_ + 2 * D_ + h * DH_ + dh0;
  {
    const int r = tid >> 3, cc = (tid & 7) * 8;
#pragma unroll
    for (int k = 0; k < 2; k++) {
      ushort8v v = *(const ushort8v*)(src + (size_t)(t0 + k * 32 + r) * TD3_ + cc);
      *(ushort8v*)&tile[k * 32 + r][cc] = v;
    }
  }
  __syncthreads();
  unsigned short* dst = vtg + ((size_t)(b * H_ + h) * DH_ + dh0) * T_ + t0;
  {
    const int d = tid >> 3, tc = (tid & 7) * 8;
#pragma unroll
    for (int k = 0; k < 2; k++) {
      ushort8v v;
#pragma unroll
      for (int j = 0; j < 8; j++) v[j] = tile[tc + j][k * 32 + d];
      *(ushort8v*)(dst + (size_t)(k * 32 + d) * T_ + tc) = v;
    }
  }
}

// ---------------- 256x192 8-phase bf16 GEMM (QKV): C bf16 ----------------
// 512 threads = 8 waves (2M x 4N), per-wave 128x48 (acc[8][3]). BK=64. LDS 112 KiB.
// Grid = (M/256)*(N/192) = 16*32 = 512 = exactly 2 rounds at 1 block/CU.
// Region-death: B[buf] dead after ph1 (all frags->regs), A[buf] dead after ph3.
// Stages: ph1 A0(t+1)->buf^1, ph2 A1(t+1)->buf^1 + B0(t+2)->buf,
//         ph3 B1(t+2)->buf, ph4 B2(t+2)->buf. End-of-tile vmcnt(3).
__global__ __launch_bounds__(512, 1) void gemm_qkv192(const unsigned short* __restrict__ A,
                                                      const unsigned short* __restrict__ BT,
                                                      unsigned short* __restrict__ C,
                                                      int M, int N, int K) {
  __shared__ unsigned short lA[2][2][128 * 64];   // 64 KiB
  __shared__ unsigned short lB[2][192 * 64];      // 48 KiB

  const int tid = threadIdx.x;
  const int bid = (int)blockIdx.x;
  const int npx = 4;                              // n-tiles per XCD (N=6144/192/8)
  const int xcd = bid & 7, idx = bid >> 3;
  const int n0 = (xcd * npx + (idx & 3)) * 192;
  const int m0 = (idx >> 2) * 256;
  const int l = tid & 63, lr = l & 15, lg = l >> 4;
  const int wid = tid >> 6, wm = wid >> 2, wn = wid & 3;
  const int nk = K >> 6;

  f32x4 acc[8][3] = {};

  auto stageA = [&](int buf, int h, int kt) {
#pragma unroll
    for (int q = 0; q < 2; q++) {
      const int n = q * 512 + tid;            // 1024 chunks = 128 rows x 8
      const int row = n >> 3, ch = n & 7;
      gload_lds16(A + (size_t)(m0 + h * 128 + row) * K + kt * 64 + ((ch ^ (row & 7)) << 3),
                  &lA[buf][h][n * 8]);
    }
  };
  auto stageBt = [&](int buf, int third, int kt) {
    const int r = tid >> 3, ch = tid & 7;     // 512 chunks = 64 rows x 8
    gload_lds16(BT + (size_t)(n0 + third * 64 + r) * K + kt * 64 + ((ch ^ (r & 7)) << 3),
                &lB[buf][third * 4096 + tid * 8]);
  };

  // ---- prologue: tile0 complete + tile1's B thirds in flight ----
  stageA(0, 0, 0); stageA(0, 1, 0);
  stageBt(0, 0, 0); stageBt(0, 1, 0); stageBt(0, 2, 0);
  if (nk > 1) {
    stageBt(1, 0, 1); stageBt(1, 1, 1); stageBt(1, 2, 1);
    asm volatile("s_waitcnt vmcnt(3)" ::: "memory");
  } else {
    asm volatile("s_waitcnt vmcnt(0)" ::: "memory");
  }
  __builtin_amdgcn_s_barrier();

  short8 a[4][2], b[3][2];
  for (int kt = 0; kt < nk; kt++) {
    const int buf = kt & 1;

    // ph1: read A-quad0 + ALL B frags; stage (t+1).A0 -> buf^1; MFMA acc[0..3][0..1]
#pragma unroll
    for (int mi = 0; mi < 4; mi++)
#pragma unroll
      for (int kk = 0; kk < 2; kk++) {
        const int row = mi * 16 + lr;
        a[mi][kk] = *(const short8*)&lA[buf][wm][row * 64 + (((kk * 4 + lg) ^ (lr & 7)) << 3)];
      }
#pragma unroll
    for (int ni = 0; ni < 3; ni++)
#pragma unroll
      for (int kk = 0; kk < 2; kk++) {
        const int row = wn * 48 + ni * 16 + lr;
        b[ni][kk] = *(const short8*)&lB[buf][row * 64 + (((kk * 4 + lg) ^ (lr & 7)) << 3)];
      }
    if (kt + 1 < nk) stageA(buf ^ 1, 0, kt + 1);
    __builtin_amdgcn_s_barrier();
    __builtin_amdgcn_s_setprio(1);
#pragma unroll
    for (int mi = 0; mi < 4; mi++)
#pragma unroll
      for (int ni = 0; ni < 2; ni++)
#pragma unroll
        for (int kk = 0; kk < 2; kk++)
          acc[mi][ni] = __builtin_amdgcn_mfma_f32_16x16x32_bf16(a[mi][kk], b[ni][kk], acc[mi][ni], 0, 0, 0);
    __builtin_amdgcn_s_setprio(0);
    __builtin_amdgcn_s_barrier();

    // ph2: stage (t+1).A1 -> buf^1 + (t+2).B0 -> buf; MFMA acc[0..3][2]
    if (kt + 1 < nk) stageA(buf ^ 1, 1, kt + 1);
    if (kt + 2 < nk) stageBt(buf, 0, kt + 2);
    __builtin_amdgcn_s_barrier();
    __builtin_amdgcn_s_setprio(1);
#pragma unroll
    for (int mi = 0; mi < 4; mi++)
#pragma unroll
      for (int kk = 0; kk < 2; kk++)
        acc[mi][2] = __builtin_amdgcn_mfma_f32_16x16x32_bf16(a[mi][kk], b[2][kk], acc[mi][2], 0, 0, 0);
    __builtin_amdgcn_s_setprio(0);
    __builtin_amdgcn_s_barrier();

    // ph3: read A-quad1; stage (t+2).B1 -> buf; MFMA acc[4..7][0..1]
#pragma unroll
    for (int mi = 0; mi < 4; mi++)
#pragma unroll
      for (int kk = 0; kk < 2; kk++) {
        const int row = (4 + mi) * 16 + lr;
        a[mi][kk] = *(const short8*)&lA[buf][wm][row * 64 + (((kk * 4 + lg) ^ (lr & 7)) << 3)];
      }
    if (kt + 2 < nk) stageBt(buf, 1, kt + 2);
    __builtin_amdgcn_s_barrier();
    __builtin_amdgcn_s_setprio(1);
#pragma unroll
    for (int mi = 0; mi < 4; mi++)
#pragma unroll
      for (int ni = 0; ni < 2; ni++)
#pragma unroll
        for (int kk = 0; kk < 2; kk++)
          acc[4 + mi][ni] = __builtin_amdgcn_mfma_f32_16x16x32_bf16(a[mi][kk], b[ni][kk], acc[4 + mi][ni], 0, 0, 0);
    __builtin_amdgcn_s_setprio(0);
    __builtin_amdgcn_s_barrier();

    // ph4: stage (t+2).B2 -> buf; MFMA acc[4..7][2]; vmcnt
    if (kt + 2 < nk) stageBt(buf, 2, kt + 2);
    __builtin_amdgcn_s_barrier();
    __builtin_amdgcn_s_setprio(1);
#pragma unroll
    for (int mi = 0; mi < 4; mi++)
#pragma unroll
      for (int kk = 0; kk < 2; kk++)
        acc[4 + mi][2] = __builtin_amdgcn_mfma_f32_16x16x32_bf16(a[mi][kk], b[2][kk], acc[4 + mi][2], 0, 0, 0);
    __builtin_amdgcn_s_setprio(0);
    if (kt + 2 < nk) asm volatile("s_waitcnt vmcnt(3)" ::: "memory");  // only (t+2).B* fly
    else             asm volatile("s_waitcnt vmcnt(0)" ::: "memory");
    __builtin_amdgcn_s_barrier();
  }

#pragma unroll
  for (int mi = 0; mi < 8; mi++)
#pragma unroll
    for (int ni = 0; ni < 3; ni++)
#pragma unroll
      for (int i = 0; i < 4; i++) {
        const int row = m0 + wm * 128 + mi * 16 + lg * 4 + i;
        const int col = n0 + wn * 48 + ni * 16 + lr;
        C[(size_t)row * N + col] = f2bf(acc[mi][ni][i]);
      }
}

// ---------------- 128x256 8-phase bf16 GEMM (output proj): C fp32 ----------------
// 512 threads = 8 waves (2M x 4N), per-wave 64x64 (acc[4][4]). LDS 96 KiB.
// Grid = (M/128)*(N/256) = 32*8 = 256 = exactly 1 block/CU, 1 round.
// Region-death: B[buf] dead after ph2, A[buf] dead after ph3.
// Stages (depth-2, all -> buf): ph3 B0(t+2), ph4 B1(t+2)+A(t+2). vmcnt(6).
__global__ __launch_bounds__(512, 1) void gemm_op8(const unsigned short* __restrict__ A,
                                                   const unsigned short* __restrict__ BT,
                                                   float* __restrict__ C,
                                                   int M, int N, int K) {
  __shared__ unsigned short lA[2][128 * 64];      // 32 KiB
  __shared__ unsigned short lB[2][2][128 * 64];   // 64 KiB

  const int tid = threadIdx.x;
  const int bid = (int)blockIdx.x;
  const int xcd = bid & 7, idx = bid >> 3;        // N/256 == 8 n-tiles: one per XCD
  const int n0 = xcd * 256, m0 = idx * 128;
  const int l = tid & 63, lr = l & 15, lg = l >> 4;
  const int wid = tid >> 6, wm = wid >> 2, wn = wid & 3;
  const int bh = wn >> 1, br0 = (wn & 1) * 64;
  const int nk = K >> 6;

  f32x4 acc[4][4] = {};

  auto stageA = [&](int buf, int kt) {
#pragma unroll
    for (int q = 0; q < 2; q++) {
      const int n = q * 512 + tid;                // 1024 chunks = 128 rows x 8
      const int row = n >> 3, ch = n & 7;
      gload_lds16(A + (size_t)(m0 + row) * K + kt * 64 + ((ch ^ (row & 7)) << 3),
                  &lA[buf][n * 8]);
    }
  };
  auto stageB = [&](int buf, int h, int kt) {
#pragma unroll
    for (int q = 0; q < 2; q++) {
      const int n = q * 512 + tid;
      const int row = n >> 3, ch = n & 7;
      gload_lds16(BT + (size_t)(n0 + h * 128 + row) * K + kt * 64 + ((ch ^ (row & 7)) << 3),
                  &lB[buf][h][n * 8]);
    }
  };

  // ---- prologue: tile0 + tile1 fully staged; keep tile1's 6 ops in flight ----
  stageB(0, 0, 0); stageB(0, 1, 0); stageA(0, 0);
  if (nk > 1) {
    stageB(1, 0, 1); stageB(1, 1, 1); stageA(1, 1);
    asm volatile("s_waitcnt vmcnt(6)" ::: "memory");
  } else {
    asm volatile("s_waitcnt vmcnt(0)" ::: "memory");
  }
  __builtin_amdgcn_s_barrier();

  short8 a[2][2], b0[2][2], b1[2][2];
  for (int kt = 0; kt < nk; kt++) {
    const int buf = kt & 1;

    // ph1: read A-lo + B-lo; MFMA acc[0..1][0..1]
#pragma unroll
    for (int mi = 0; mi < 2; mi++)
#pragma unroll
      for (int kk = 0; kk < 2; kk++) {
        const int row = wm * 64 + mi * 16 + lr;
        a[mi][kk] = *(const short8*)&lA[buf][row * 64 + (((kk * 4 + lg) ^ (lr & 7)) << 3)];
      }
#pragma unroll
    for (int ni = 0; ni < 2; ni++)
#pragma unroll
      for (int kk = 0; kk < 2; kk++) {
        const int row = br0 + ni * 16 + lr;
        b0[ni][kk] = *(const short8*)&lB[buf][bh][row * 64 + (((kk * 4 + lg) ^ (lr & 7)) << 3)];
      }
    __builtin_amdgcn_s_barrier();
    __builtin_amdgcn_s_setprio(1);
#pragma unroll
    for (int mi = 0; mi < 2; mi++)
#pragma unroll
      for (int ni = 0; ni < 2; ni++)
#pragma unroll
        for (int kk = 0; kk < 2; kk++)
          acc[mi][ni] = __builtin_amdgcn_mfma_f32_16x16x32_bf16(a[mi][kk], b0[ni][kk], acc[mi][ni], 0, 0, 0);
    __builtin_amdgcn_s_setprio(0);
    __builtin_amdgcn_s_barrier();

    // ph2: read B-hi; MFMA acc[0..1][2..3]
#pragma unroll
    for (int ni = 0; ni < 2; ni++)
#pragma unroll
      for (int kk = 0; kk < 2; kk++) {
        const int row = br0 + (2 + ni) * 16 + lr;
        b1[ni][kk] = *(const short8*)&lB[buf][bh][row * 64 + (((kk * 4 + lg) ^ (lr & 7)) << 3)];
      }
    __builtin_amdgcn_s_barrier();
    __builtin_amdgcn_s_setprio(1);
#pragma unroll
    for (int mi = 0; mi < 2; mi++)
#pragma unroll
      for (int ni = 0; ni < 2; ni++)
#pragma unroll
        for (int kk = 0; kk < 2; kk++)
          acc[mi][2 + ni] = __builtin_amdgcn_mfma_f32_16x16x32_bf16(a[mi][kk], b1[ni][kk], acc[mi][2 + ni], 0, 0, 0);
    __builtin_amdgcn_s_setprio(0);
    __builtin_amdgcn_s_barrier();

    // ph3: read A-hi; stage (t+2).B0 -> buf; MFMA acc[2..3][2..3]
#pragma unroll
    for (int mi = 0; mi < 2; mi++)
#pragma unroll
      for (int kk = 0; kk < 2; kk++) {
        const int row = wm * 64 + (2 + mi) * 16 + lr;
        a[mi][kk] = *(const short8*)&lA[buf][row * 64 + (((kk * 4 + lg) ^ (lr & 7)) << 3)];
      }
    if (kt + 2 < nk) stageB(buf, 0, kt + 2);
    __builtin_amdgcn_s_barrier();
    __builtin_amdgcn_s_setprio(1);
#pragma unroll
    for (int mi = 0; mi < 2; mi++)
#pragma unroll
      for (int ni = 0; ni < 2; ni++)
#pragma unroll
        for (int kk = 0; kk < 2; kk++)
          acc[2 + mi][2 + ni] = __builtin_amdgcn_mfma_f32_16x16x32_bf16(a[mi][kk], b1[ni][kk], acc[2 + mi][2 + ni], 0, 0, 0);
    __builtin_amdgcn_s_setprio(0);
    __builtin_amdgcn_s_barrier();

    // ph4: stage (t+2).B1 + (t+2).A -> buf; MFMA acc[2..3][0..1]; vmcnt
    if (kt + 2 < nk) { stageB(buf, 1, kt + 2); stageA(buf, kt + 2); }
    __builtin_amdgcn_s_barrier();
    __builtin_amdgcn_s_setprio(1);
#pragma unroll
    for (int mi = 0; mi < 2; mi++)
#pragma unroll
      for (int ni = 0; ni < 2; ni++)
#pragma unroll
        for (int kk = 0; kk < 2; kk++)
          acc[2 + mi][ni] = __builtin_amdgcn_mfma_f32_16x16x32_bf16(a[mi][kk], b0[ni][kk], acc[2 + mi][ni], 0, 0, 0);
    __builtin_amdgcn_s_setprio(0);
    if (kt + 2 < nk) asm volatile("s_waitcnt vmcnt(6)" ::: "memory");  // only (t+2) stages fly
    else             asm volatile("s_waitcnt vmcnt(0)" ::: "memory");
    __builtin_amdgcn_s_barrier();
  }

#pragma unroll
  for (int mi = 0; mi < 4; mi++)
#pragma unroll
    for (int ni = 0; ni < 4; ni++)
#pragma unroll
      for (int i = 0; i < 4; i++) {
        const int row = m0 + wm * 64 + mi * 16 + lg * 4 + i;
        const int col = n0 + wn * 64 + ni * 16 + lr;
        C[(size_t)row * N + col] = acc[mi][ni][i];
      }
}

// ---------------- flash attention (causal), QBLK=128, KVBLK=64, 2-phase pipeline ----------------
__global__ __launch_bounds__(256, 2) void attn_fa(const unsigned short* __restrict__ qkv,
                                                  const unsigned short* __restrict__ vtg,
                                                  unsigned short* __restrict__ out) {
  const int x = blockIdx.x, h = blockIdx.y, b = blockIdx.z;
  const int qtl = b ? x : (T_ / 128 - 1 - x);
  const int q0 = qtl * 128;
  const int tid = threadIdx.x, w = tid >> 6, l = tid & 63, lr = l & 15, lg = l >> 4;

  const unsigned short* Qb = qkv + (size_t)b * T_ * TD3_ + h * DH_;
  const unsigned short* Kb = Qb + D_;
  const unsigned short* Vt = vtg + ((size_t)b * H_ + h) * DH_ * T_;

  __shared__ unsigned short klds[2][64 * 128];
  __shared__ unsigned short vt[2][128 * 64];
  __shared__ unsigned short plds[4][32 * 64];

  const float scale = 0.08838834764831845f;

  short8 qf[2][4];
#pragma unroll
  for (int mi = 0; mi < 2; mi++) {
    const unsigned short* qrow = Qb + (size_t)(q0 + w * 32 + mi * 16 + lr) * TD3_;
#pragma unroll
    for (int ks = 0; ks < 4; ks++) {
      ushort8v qv = *(const ushort8v*)(qrow + ks * 32 + lg * 8);
      short8 qs;
#pragma unroll
      for (int j = 0; j < 8; j++) qs[j] = (short)f2bf(bf2f(qv[j]) * scale);
      qf[mi][ks] = qs;
    }
  }

  f32x4 oacc[2][8] = {};
  float mrun[2][4], lsum[2][4];
#pragma unroll
  for (int mi = 0; mi < 2; mi++)
#pragma unroll
    for (int i = 0; i < 4; i++) { mrun[mi][i] = -__builtin_inff(); lsum[mi][i] = 0.f; }

  auto STAGE = [&](int buf, int kv0) {
#pragma unroll
    for (int it = 0; it < 4; it++) {
      const int n = it * 256 + tid;
      { const int kv = n >> 4, ch = n & 15;
        gload_lds16(Kb + (size_t)(kv0 + kv) * TD3_ + ((ch ^ (kv & 7)) << 3),
                    &klds[buf][n * 8]); }
      { const int dh = n >> 3, ch = n & 7;
        gload_lds16(Vt + (size_t)dh * T_ + kv0 + ((ch ^ (dh & 7)) << 3),
                    &vt[buf][n * 8]); }
    }
  };

  const int nt = 2 * qtl + 2;
  STAGE(0, 0);
  __syncthreads();

  for (int t = 0; t < nt; t++) {
    const int buf = t & 1;
    if (t + 1 < nt) STAGE(buf ^ 1, (t + 1) * 64);

    const int kv0 = t * 64;
    const bool active = (kv0 <= q0 + w * 32 + 31);
    if (active) {
      f32x4 s[2][4] = {};
      __builtin_amdgcn_s_setprio(1);
#pragma unroll
      for (int nf = 0; nf < 4; nf++) {
        const int kv = nf * 16 + lr;
#pragma unroll
        for (int ks = 0; ks < 4; ks++) {
          short8 kf = *(const short8*)&klds[buf][kv * 128 + (((ks * 4 + lg) ^ (lr & 7)) << 3)];
#pragma unroll
          for (int mi = 0; mi < 2; mi++)
            s[mi][nf] = __builtin_amdgcn_mfma_f32_16x16x32_bf16(qf[mi][ks], kf, s[mi][nf], 0, 0, 0);
        }
      }
      __builtin_amdgcn_s_setprio(0);

      const bool needmask = (kv0 + 63 > q0 + w * 32);
      float pmax[2][4];
#pragma unroll
      for (int mi = 0; mi < 2; mi++)
#pragma unroll
        for (int i = 0; i < 4; i++) pmax[mi][i] = -__builtin_inff();
#pragma unroll
      for (int mi = 0; mi < 2; mi++)
#pragma unroll
        for (int nf = 0; nf < 4; nf++)
#pragma unroll
          for (int i = 0; i < 4; i++) {
            float xv = s[mi][nf][i];
            if (needmask) {
              const int qr = w * 32 + mi * 16 + lg * 4 + i;
              const int kc = nf * 16 + lr;
              if (kv0 + kc > q0 + qr) xv = -__builtin_inff();
            }
            s[mi][nf][i] = xv;
            pmax[mi][i] = fmaxf(pmax[mi][i], xv);
          }
#pragma unroll
      for (int m = 1; m < 16; m <<= 1)
#pragma unroll
        for (int mi = 0; mi < 2; mi++)
#pragma unroll
          for (int i = 0; i < 4; i++) pmax[mi][i] = fmaxf(pmax[mi][i], __shfl_xor(pmax[mi][i], m));

      float alpha[2][4], rsum[2][4];
#pragma unroll
      for (int mi = 0; mi < 2; mi++)
#pragma unroll
        for (int i = 0; i < 4; i++) {
          const float mn = fmaxf(mrun[mi][i], pmax[mi][i]);
          alpha[mi][i] = __expf(mrun[mi][i] - mn);
          mrun[mi][i] = mn;
          rsum[mi][i] = 0.f;
        }
#pragma unroll
      for (int mi = 0; mi < 2; mi++)
#pragma unroll
        for (int nf = 0; nf < 4; nf++)
#pragma unroll
          for (int i = 0; i < 4; i++) {
            const float p = __expf(s[mi][nf][i] - mrun[mi][i]);
            rsum[mi][i] += p;
            const int prow = mi * 16 + lg * 4 + i;
            plds[w][prow * 64 + ((nf * 16 + lr) ^ ((prow & 7) << 3))] = f2bf(p);
          }
#pragma unroll
      for (int m = 1; m < 16; m <<= 1)
#pragma unroll
        for (int mi = 0; mi < 2; mi++)
#pragma unroll
          for (int i = 0; i < 4; i++) rsum[mi][i] += __shfl_xor(rsum[mi][i], m);
#pragma unroll
      for (int mi = 0; mi < 2; mi++)
#pragma unroll
        for (int i = 0; i < 4; i++) lsum[mi][i] = lsum[mi][i] * alpha[mi][i] + rsum[mi][i];
#pragma unroll
      for (int mi = 0; mi < 2; mi++)
#pragma unroll
        for (int nf = 0; nf < 8; nf++)
#pragma unroll
          for (int i = 0; i < 4; i++) oacc[mi][nf][i] *= alpha[mi][i];

      __builtin_amdgcn_s_setprio(1);
#pragma unroll
      for (int kk = 0; kk < 2; kk++) {
        short8 pa[2];
#pragma unroll
        for (int mi = 0; mi < 2; mi++) {
          const int prow = mi * 16 + lr;
          pa[mi] = *(const short8*)&plds[w][prow * 64 + (((kk * 32 + lg * 8)) ^ ((prow & 7) << 3))];
        }
#pragma unroll
        for (int nf = 0; nf < 8; nf++) {
          const short8 vb = *(const short8*)&vt[buf][(nf * 16 + lr) * 64 + (((kk * 4 + lg) ^ (lr & 7)) << 3)];
#pragma unroll
          for (int mi = 0; mi < 2; mi++)
            oacc[mi][nf] = __builtin_amdgcn_mfma_f32_16x16x32_bf16(pa[mi], vb, oacc[mi][nf], 0, 0, 0);
        }
      }
      __builtin_amdgcn_s_setprio(0);
    }
    __syncthreads();
  }

  float rinv[2][4];
#pragma unroll
  for (int mi = 0; mi < 2; mi++)
#pragma unroll
    for (int i = 0; i < 4; i++) rinv[mi][i] = 1.f / lsum[mi][i];
#pragma unroll
  for (int mi = 0; mi < 2; mi++) {
    unsigned short* orow = out + ((size_t)b * T_ + q0 + w * 32 + mi * 16 + lg * 4) * D_ + h * DH_;
#pragma unroll
    for (int nf = 0; nf < 8; nf++)
#pragma unroll
      for (int i = 0; i < 4; i++)
        orow[(size_t)i * D_ + nf * 16 + lr] = f2bf(oacc[mi][nf][i] * rinv[mi][i]);
  }
}

extern "C" void kernel_launch(void* const* d_in, const int* in_sizes, int n_in,
                              void* d_out, int out_size, void* d_ws, size_t ws_size,
                              hipStream_t stream) {
  const float* x    = (const float*)d_in[0];
  const float* wqkv = (const float*)d_in[1];
  const float* wo   = (const float*)d_in[2];
  float* out = (float*)d_out;

  char* ws = (char*)d_ws;
  unsigned short* xb    = (unsigned short*)(ws);               // 16.8 MB (reused as attn out)
  unsigned short* wqkvt = (unsigned short*)(ws + 16777216);    // 25.2 MB (dead after gemm1)
  unsigned short* vtg   = (unsigned short*)(ws + 16777216);    // 16.8 MB, overlays wqkvt
  unsigned short* wot   = (unsigned short*)(ws + 41943040);    //  8.4 MB
  unsigned short* qkv   = (unsigned short*)(ws + 50331648);    // 50.3 MB  (end 100.7 MB)
  unsigned short* attn  = xb;   // xb dead after GEMM1

  convert_f32_bf16<<<2048, 256, 0, stream>>>(x, xb, B_ * T_ * D_ / 4);
  transpose_f32_bf16<<<dim3(TD3_ / 32, D_ / 32), 256, 0, stream>>>(wqkv, wqkvt, D_, TD3_);
  transpose_f32_bf16<<<dim3(D_ / 32, D_ / 32), 256, 0, stream>>>(wo, wot, D_, D_);

  gemm_qkv192<<<dim3(512), 512, 0, stream>>>(xb, wqkvt, qkv, B_ * T_, TD3_, D_);
  vtr_kernel<<<dim3(T_ / 64, H_ * 2, B_), 256, 0, stream>>>(qkv, vtg);
  attn_fa<<<dim3(T_ / 128, H_, B_), 256, 0, stream>>>(qkv, vtg, attn);
  gemm_op8<<<dim3(256), 512, 0, stream>>>(attn, wot, out, B_ * T_, D_, D_);
}

// Round 10
// 284.828 us; speedup vs baseline: 1.7980x; 1.0617x over previous
//
#include <hip/hip_runtime.h>
#include <hip/hip_bf16.h>

#define B_   2
#define T_   2048
#define D_   2048
#define H_   16
#define DH_  128
#define TD3_ 6144   // 3*D

typedef __attribute__((ext_vector_type(8))) short   short8;
typedef __attribute__((ext_vector_type(8))) unsigned short ushort8v;
typedef __attribute__((ext_vector_type(4))) float   f32x4;
typedef __attribute__((ext_vector_type(4))) float   f4v;
typedef __attribute__((ext_vector_type(4))) unsigned short u16x4;

static __device__ __forceinline__ unsigned short f2bf(float f) {
  unsigned int u = __builtin_bit_cast(unsigned int, f);
  u += 0x7FFFu + ((u >> 16) & 1u);
  return (unsigned short)(u >> 16);
}
static __device__ __forceinline__ float bf2f(unsigned short u) {
  return __builtin_bit_cast(float, (unsigned int)u << 16);
}

static __device__ __forceinline__ void gload_lds16(const unsigned short* g, unsigned short* l) {
  __builtin_amdgcn_global_load_lds((const __attribute__((address_space(1))) void*)g,
                                   (__attribute__((address_space(3))) void*)l, 16, 0, 0);
}

// ---------------- fp32 -> bf16 elementwise cast (vectorized) ----------------
__global__ __launch_bounds__(256) void convert_f32_bf16(const float* __restrict__ X,
                                                        unsigned short* __restrict__ Y, int n4) {
  for (int i = blockIdx.x * blockDim.x + threadIdx.x; i < n4; i += gridDim.x * blockDim.x) {
    f4v v = ((const f4v*)X)[i];
    u16x4 o;
    o[0] = f2bf(v[0]); o[1] = f2bf(v[1]); o[2] = f2bf(v[2]); o[3] = f2bf(v[3]);
    ((u16x4*)Y)[i] = o;
  }
}

// ---------------- transpose fp32 [K][N] -> bf16 [N][K] ----------------
__global__ __launch_bounds__(256) void transpose_f32_bf16(const float* __restrict__ W,
                                                          unsigned short* __restrict__ WT,
                                                          int K, int N) {
  __shared__ float tile[32][33];
  int n0 = blockIdx.x * 32, k0 = blockIdx.y * 32;
  int tx = threadIdx.x & 31, ty = threadIdx.x >> 5;
#pragma unroll
  for (int r = 0; r < 4; r++)
    tile[ty + 8 * r][tx] = W[(size_t)(k0 + ty + 8 * r) * N + n0 + tx];
  __syncthreads();
#pragma unroll
  for (int r = 0; r < 4; r++)
    WT[(size_t)(n0 + ty + 8 * r) * K + k0 + tx] = f2bf(tile[tx][ty + 8 * r]);
}

// ---------------- V transpose: qkv V-third [b][t][h*DH+dh] -> vtg [b][h][dh][t] ----------------
__global__ __launch_bounds__(256) void vtr_kernel(const unsigned short* __restrict__ qkv,
                                                  unsigned short* __restrict__ vtg) {
  __shared__ unsigned short tile[64][68];
  const int t0 = blockIdx.x * 64;
  const int h = blockIdx.y >> 1, dh0 = (blockIdx.y & 1) * 64;
  const int b = blockIdx.z;
  const int tid = threadIdx.x;
  const unsigned short* src = qkv + (size_t)b * T_ * TD3_ + 2 * D_ + h * DH_ + dh0;
  {
    const int r = tid >> 3, cc = (tid & 7) * 8;
#pragma unroll
    for (int k = 0; k < 2; k++) {
      ushort8v v = *(const ushort8v*)(src + (size_t)(t0 + k * 32 + r) * TD3_ + cc);
      *(ushort8v*)&tile[k * 32 + r][cc] = v;
    }
  }
  __syncthreads();
  unsigned short* dst = vtg + ((size_t)(b * H_ + h) * DH_ + dh0) * T_ + t0;
  {
    const int d = tid >> 3, tc = (tid & 7) * 8;
#pragma unroll
    for (int k = 0; k < 2; k++) {
      ushort8v v;
#pragma unroll
      for (int j = 0; j < 8; j++) v[j] = tile[tc + j][k * 32 + d];
      *(ushort8v*)(dst + (size_t)(k * 32 + d) * T_ + tc) = v;
    }
  }
}

// ---------------- 256x192 2-phase software-pipelined bf16 GEMM (QKV): C bf16 ----------------
// 512 threads = 8 waves (2M x 4N), per-wave 128x48 (acc[8][3]). BK=64. LDS 112 KiB.
// Grid = 512 = exactly 2 rounds at 1 block/CU. All ds_reads issue UNDER an MFMA
// cluster and drain before use one phase later. 3 barriers/K-tile.
// Phase A: stage(t+1)->buf^1; read aQ1(buf); 24 MFMA (aQ0 x bcur); bar.
// Phase B: 16 MFMA (aQ1 x bcur); vmcnt(0); bar (all waves' DMA retired);
//          prefetch aQ0+bnext(t+1, buf^1); 8 MFMA (aQ1 x bcur[2]); bar.
__global__ __launch_bounds__(512, 1) void gemm_qkv192(const unsigned short* __restrict__ A,
                                                      const unsigned short* __restrict__ BT,
                                                      unsigned short* __restrict__ C,
                                                      int M, int N, int K) {
  __shared__ unsigned short lA[2][2][128 * 64];   // 64 KiB
  __shared__ unsigned short lB[2][192 * 64];      // 48 KiB

  const int tid = threadIdx.x;
  const int bid = (int)blockIdx.x;
  const int npx = 4;                              // n-tiles per XCD
  const int xcd = bid & 7, idx = bid >> 3;
  const int n0 = (xcd * npx + (idx & 3)) * 192;
  const int m0 = (idx >> 2) * 256;
  const int l = tid & 63, lr = l & 15, lg = l >> 4;
  const int wid = tid >> 6, wm = wid >> 2, wn = wid & 3;
  const int nk = K >> 6;                          // 32 (even; kt+=2 unroll relies on it)

  f32x4 acc[8][3] = {};
  short8 aQ0[4][2], aQ1[4][2], bX[3][2], bY[3][2];

  auto stageA = [&](int buf, int h, int kt) {
#pragma unroll
    for (int q = 0; q < 2; q++) {
      const int n = q * 512 + tid;
      const int row = n >> 3, ch = n & 7;
      gload_lds16(A + (size_t)(m0 + h * 128 + row) * K + kt * 64 + ((ch ^ (row & 7)) << 3),
                  &lA[buf][h][n * 8]);
    }
  };
  auto stageBt = [&](int buf, int third, int kt) {
    const int r = tid >> 3, ch = tid & 7;
    gload_lds16(BT + (size_t)(n0 + third * 64 + r) * K + kt * 64 + ((ch ^ (r & 7)) << 3),
                &lB[buf][third * 4096 + tid * 8]);
  };

#define QKV_STAGE_ALL(BUF, TT)                                                  \
  { stageA(BUF, 0, TT); stageA(BUF, 1, TT);                                     \
    stageBt(BUF, 0, TT); stageBt(BUF, 1, TT); stageBt(BUF, 2, TT); }

#define QKV_READ_A(DST, BUF, QUAD)                                              \
  _Pragma("unroll")                                                             \
  for (int mi = 0; mi < 4; mi++)                                                \
    _Pragma("unroll")                                                           \
    for (int kk = 0; kk < 2; kk++) {                                            \
      const int row = ((QUAD) * 4 + mi) * 16 + lr;                              \
      DST[mi][kk] = *(const short8*)&lA[BUF][wm][row * 64 +                     \
                      (((kk * 4 + lg) ^ (lr & 7)) << 3)];                       \
    }

#define QKV_READ_B(DST, BUF)                                                    \
  _Pragma("unroll")                                                             \
  for (int ni = 0; ni < 3; ni++)                                                \
    _Pragma("unroll")                                                           \
    for (int kk = 0; kk < 2; kk++) {                                            \
      const int row = wn * 48 + ni * 16 + lr;                                   \
      DST[ni][kk] = *(const short8*)&lB[BUF][row * 64 +                         \
                      (((kk * 4 + lg) ^ (lr & 7)) << 3)];                       \
    }

#define QKV_PHASE_A(BUF, BCUR, TT)                                              \
  {                                                                             \
    if ((TT) + 1 < nk) QKV_STAGE_ALL(1 - (BUF), (TT) + 1);                      \
    QKV_READ_A(aQ1, BUF, 1)                                                     \
    __builtin_amdgcn_s_setprio(1);                                              \
    _Pragma("unroll")                                                           \
    for (int mi = 0; mi < 4; mi++)                                              \
      _Pragma("unroll")                                                         \
      for (int ni = 0; ni < 3; ni++)                                            \
        _Pragma("unroll")                                                       \
        for (int kk = 0; kk < 2; kk++)                                          \
          acc[mi][ni] = __builtin_amdgcn_mfma_f32_16x16x32_bf16(                \
              aQ0[mi][kk], BCUR[ni][kk], acc[mi][ni], 0, 0, 0);                 \
    __builtin_amdgcn_s_setprio(0);                                              \
    __builtin_amdgcn_s_barrier();                                               \
  }

#define QKV_PHASE_B(BUF, BCUR, BNXT, TT)                                        \
  {                                                                             \
    __builtin_amdgcn_s_setprio(1);                                              \
    _Pragma("unroll")                                                           \
    for (int mi = 0; mi < 4; mi++)                                              \
      _Pragma("unroll")                                                         \
      for (int ni = 0; ni < 2; ni++)                                            \
        _Pragma("unroll")                                                       \
        for (int kk = 0; kk < 2; kk++)                                          \
          acc[4 + mi][ni] = __builtin_amdgcn_mfma_f32_16x16x32_bf16(            \
              aQ1[mi][kk], BCUR[ni][kk], acc[4 + mi][ni], 0, 0, 0);             \
    __builtin_amdgcn_s_setprio(0);                                              \
    asm volatile("s_waitcnt vmcnt(0)" ::: "memory");                            \
    __builtin_amdgcn_s_barrier();                                               \
    if ((TT) + 1 < nk) {                                                        \
      QKV_READ_A(aQ0, 1 - (BUF), 0)                                             \
      QKV_READ_B(BNXT, 1 - (BUF))                                               \
    }                                                                           \
    __builtin_amdgcn_s_setprio(1);                                              \
    _Pragma("unroll")                                                           \
    for (int mi = 0; mi < 4; mi++)                                              \
      _Pragma("unroll")                                                         \
      for (int kk = 0; kk < 2; kk++)                                            \
        acc[4 + mi][2] = __builtin_amdgcn_mfma_f32_16x16x32_bf16(               \
            aQ1[mi][kk], BCUR[2][kk], acc[4 + mi][2], 0, 0, 0);                 \
    __builtin_amdgcn_s_setprio(0);                                              \
    __builtin_amdgcn_s_barrier();                                               \
  }

  // ---- prologue: stage tile0, drain, load tile0 frags ----
  QKV_STAGE_ALL(0, 0)
  asm volatile("s_waitcnt vmcnt(0)" ::: "memory");
  __builtin_amdgcn_s_barrier();
  QKV_READ_A(aQ0, 0, 0)
  QKV_READ_B(bX, 0)

  for (int kt = 0; kt < nk; kt += 2) {
    QKV_PHASE_A(0, bX, kt)
    QKV_PHASE_B(0, bX, bY, kt)
    QKV_PHASE_A(1, bY, kt + 1)
    QKV_PHASE_B(1, bY, bX, kt + 1)
  }

#pragma unroll
  for (int mi = 0; mi < 8; mi++)
#pragma unroll
    for (int ni = 0; ni < 3; ni++)
#pragma unroll
      for (int i = 0; i < 4; i++) {
        const int row = m0 + wm * 128 + mi * 16 + lg * 4 + i;
        const int col = n0 + wn * 48 + ni * 16 + lr;
        C[(size_t)row * N + col] = f2bf(acc[mi][ni][i]);
      }
#undef QKV_PHASE_B
#undef QKV_PHASE_A
#undef QKV_READ_B
#undef QKV_READ_A
#undef QKV_STAGE_ALL
}

// ---------------- 128x256 8-phase bf16 GEMM (output proj): C fp32 ----------------
__global__ __launch_bounds__(512, 1) void gemm_op8(const unsigned short* __restrict__ A,
                                                   const unsigned short* __restrict__ BT,
                                                   float* __restrict__ C,
                                                   int M, int N, int K) {
  __shared__ unsigned short lA[2][128 * 64];      // 32 KiB
  __shared__ unsigned short lB[2][2][128 * 64];   // 64 KiB

  const int tid = threadIdx.x;
  const int bid = (int)blockIdx.x;
  const int xcd = bid & 7, idx = bid >> 3;
  const int n0 = xcd * 256, m0 = idx * 128;
  const int l = tid & 63, lr = l & 15, lg = l >> 4;
  const int wid = tid >> 6, wm = wid >> 2, wn = wid & 3;
  const int bh = wn >> 1, br0 = (wn & 1) * 64;
  const int nk = K >> 6;

  f32x4 acc[4][4] = {};

  auto stageA = [&](int buf, int kt) {
#pragma unroll
    for (int q = 0; q < 2; q++) {
      const int n = q * 512 + tid;
      const int row = n >> 3, ch = n & 7;
      gload_lds16(A + (size_t)(m0 + row) * K + kt * 64 + ((ch ^ (row & 7)) << 3),
                  &lA[buf][n * 8]);
    }
  };
  auto stageB = [&](int buf, int h, int kt) {
#pragma unroll
    for (int q = 0; q < 2; q++) {
      const int n = q * 512 + tid;
      const int row = n >> 3, ch = n & 7;
      gload_lds16(BT + (size_t)(n0 + h * 128 + row) * K + kt * 64 + ((ch ^ (row & 7)) << 3),
                  &lB[buf][h][n * 8]);
    }
  };

  stageB(0, 0, 0); stageB(0, 1, 0); stageA(0, 0);
  if (nk > 1) {
    stageB(1, 0, 1); stageB(1, 1, 1); stageA(1, 1);
    asm volatile("s_waitcnt vmcnt(6)" ::: "memory");
  } else {
    asm volatile("s_waitcnt vmcnt(0)" ::: "memory");
  }
  __builtin_amdgcn_s_barrier();

  short8 a[2][2], b0[2][2], b1[2][2];
  for (int kt = 0; kt < nk; kt++) {
    const int buf = kt & 1;

    // ph1: read A-lo + B-lo; MFMA acc[0..1][0..1]
#pragma unroll
    for (int mi = 0; mi < 2; mi++)
#pragma unroll
      for (int kk = 0; kk < 2; kk++) {
        const int row = wm * 64 + mi * 16 + lr;
        a[mi][kk] = *(const short8*)&lA[buf][row * 64 + (((kk * 4 + lg) ^ (lr & 7)) << 3)];
      }
#pragma unroll
    for (int ni = 0; ni < 2; ni++)
#pragma unroll
      for (int kk = 0; kk < 2; kk++) {
        const int row = br0 + ni * 16 + lr;
        b0[ni][kk] = *(const short8*)&lB[buf][bh][row * 64 + (((kk * 4 + lg) ^ (lr & 7)) << 3)];
      }
    __builtin_amdgcn_s_barrier();
    __builtin_amdgcn_s_setprio(1);
#pragma unroll
    for (int mi = 0; mi < 2; mi++)
#pragma unroll
      for (int ni = 0; ni < 2; ni++)
#pragma unroll
        for (int kk = 0; kk < 2; kk++)
          acc[mi][ni] = __builtin_amdgcn_mfma_f32_16x16x32_bf16(a[mi][kk], b0[ni][kk], acc[mi][ni], 0, 0, 0);
    __builtin_amdgcn_s_setprio(0);
    __builtin_amdgcn_s_barrier();

    // ph2: read B-hi; MFMA acc[0..1][2..3]
#pragma unroll
    for (int ni = 0; ni < 2; ni++)
#pragma unroll
      for (int kk = 0; kk < 2; kk++) {
        const int row = br0 + (2 + ni) * 16 + lr;
        b1[ni][kk] = *(const short8*)&lB[buf][bh][row * 64 + (((kk * 4 + lg) ^ (lr & 7)) << 3)];
      }
    __builtin_amdgcn_s_barrier();
    __builtin_amdgcn_s_setprio(1);
#pragma unroll
    for (int mi = 0; mi < 2; mi++)
#pragma unroll
      for (int ni = 0; ni < 2; ni++)
#pragma unroll
        for (int kk = 0; kk < 2; kk++)
          acc[mi][2 + ni] = __builtin_amdgcn_mfma_f32_16x16x32_bf16(a[mi][kk], b1[ni][kk], acc[mi][2 + ni], 0, 0, 0);
    __builtin_amdgcn_s_setprio(0);
    __builtin_amdgcn_s_barrier();

    // ph3: read A-hi; stage (t+2).B0 -> buf; MFMA acc[2..3][2..3]
#pragma unroll
    for (int mi = 0; mi < 2; mi++)
#pragma unroll
      for (int kk = 0; kk < 2; kk++) {
        const int row = wm * 64 + (2 + mi) * 16 + lr;
        a[mi][kk] = *(const short8*)&lA[buf][row * 64 + (((kk * 4 + lg) ^ (lr & 7)) << 3)];
      }
    if (kt + 2 < nk) stageB(buf, 0, kt + 2);
    __builtin_amdgcn_s_barrier();
    __builtin_amdgcn_s_setprio(1);
#pragma unroll
    for (int mi = 0; mi < 2; mi++)
#pragma unroll
      for (int ni = 0; ni < 2; ni++)
#pragma unroll
        for (int kk = 0; kk < 2; kk++)
          acc[2 + mi][2 + ni] = __builtin_amdgcn_mfma_f32_16x16x32_bf16(a[mi][kk], b1[ni][kk], acc[2 + mi][2 + ni], 0, 0, 0);
    __builtin_amdgcn_s_setprio(0);
    __builtin_amdgcn_s_barrier();

    // ph4: stage (t+2).B1 + (t+2).A -> buf; MFMA acc[2..3][0..1]; vmcnt
    if (kt + 2 < nk) { stageB(buf, 1, kt + 2); stageA(buf, kt + 2); }
    __builtin_amdgcn_s_barrier();
    __builtin_amdgcn_s_setprio(1);
#pragma unroll
    for (int mi = 0; mi < 2; mi++)
#pragma unroll
      for (int ni = 0; ni < 2; ni++)
#pragma unroll
        for (int kk = 0; kk < 2; kk++)
          acc[2 + mi][ni] = __builtin_amdgcn_mfma_f32_16x16x32_bf16(a[mi][kk], b0[ni][kk], acc[2 + mi][ni], 0, 0, 0);
    __builtin_amdgcn_s_setprio(0);
    if (kt + 2 < nk) asm volatile("s_waitcnt vmcnt(6)" ::: "memory");
    else             asm volatile("s_waitcnt vmcnt(0)" ::: "memory");
    __builtin_amdgcn_s_barrier();
  }

#pragma unroll
  for (int mi = 0; mi < 4; mi++)
#pragma unroll
    for (int ni = 0; ni < 4; ni++)
#pragma unroll
      for (int i = 0; i < 4; i++) {
        const int row = m0 + wm * 64 + mi * 16 + lg * 4 + i;
        const int col = n0 + wn * 64 + ni * 16 + lr;
        C[(size_t)row * N + col] = acc[mi][ni][i];
      }
}

// ---------------- flash attention (causal), QBLK=128, KVBLK=64, 2-phase pipeline ----------------
__global__ __launch_bounds__(256, 2) void attn_fa(const unsigned short* __restrict__ qkv,
                                                  const unsigned short* __restrict__ vtg,
                                                  unsigned short* __restrict__ out) {
  const int x = blockIdx.x, h = blockIdx.y, b = blockIdx.z;
  const int qtl = b ? x : (T_ / 128 - 1 - x);
  const int q0 = qtl * 128;
  const int tid = threadIdx.x, w = tid >> 6, l = tid & 63, lr = l & 15, lg = l >> 4;

  const unsigned short* Qb = qkv + (size_t)b * T_ * TD3_ + h * DH_;
  const unsigned short* Kb = Qb + D_;
  const unsigned short* Vt = vtg + ((size_t)b * H_ + h) * DH_ * T_;

  __shared__ unsigned short klds[2][64 * 128];
  __shared__ unsigned short vt[2][128 * 64];
  __shared__ unsigned short plds[4][32 * 64];

  const float scale = 0.08838834764831845f;

  short8 qf[2][4];
#pragma unroll
  for (int mi = 0; mi < 2; mi++) {
    const unsigned short* qrow = Qb + (size_t)(q0 + w * 32 + mi * 16 + lr) * TD3_;
#pragma unroll
    for (int ks = 0; ks < 4; ks++) {
      ushort8v qv = *(const ushort8v*)(qrow + ks * 32 + lg * 8);
      short8 qs;
#pragma unroll
      for (int j = 0; j < 8; j++) qs[j] = (short)f2bf(bf2f(qv[j]) * scale);
      qf[mi][ks] = qs;
    }
  }

  f32x4 oacc[2][8] = {};
  float mrun[2][4], lsum[2][4];
#pragma unroll
  for (int mi = 0; mi < 2; mi++)
#pragma unroll
    for (int i = 0; i < 4; i++) { mrun[mi][i] = -__builtin_inff(); lsum[mi][i] = 0.f; }

  auto STAGE = [&](int buf, int kv0) {
#pragma unroll
    for (int it = 0; it < 4; it++) {
      const int n = it * 256 + tid;
      { const int kv = n >> 4, ch = n & 15;
        gload_lds16(Kb + (size_t)(kv0 + kv) * TD3_ + ((ch ^ (kv & 7)) << 3),
                    &klds[buf][n * 8]); }
      { const int dh = n >> 3, ch = n & 7;
        gload_lds16(Vt + (size_t)dh * T_ + kv0 + ((ch ^ (dh & 7)) << 3),
                    &vt[buf][n * 8]); }
    }
  };

  const int nt = 2 * qtl + 2;
  STAGE(0, 0);
  __syncthreads();

  for (int t = 0; t < nt; t++) {
    const int buf = t & 1;
    if (t + 1 < nt) STAGE(buf ^ 1, (t + 1) * 64);

    const int kv0 = t * 64;
    const bool active = (kv0 <= q0 + w * 32 + 31);
    if (active) {
      f32x4 s[2][4] = {};
      __builtin_amdgcn_s_setprio(1);
#pragma unroll
      for (int nf = 0; nf < 4; nf++) {
        const int kv = nf * 16 + lr;
#pragma unroll
        for (int ks = 0; ks < 4; ks++) {
          short8 kf = *(const short8*)&klds[buf][kv * 128 + (((ks * 4 + lg) ^ (lr & 7)) << 3)];
#pragma unroll
          for (int mi = 0; mi < 2; mi++)
            s[mi][nf] = __builtin_amdgcn_mfma_f32_16x16x32_bf16(qf[mi][ks], kf, s[mi][nf], 0, 0, 0);
        }
      }
      __builtin_amdgcn_s_setprio(0);

      const bool needmask = (kv0 + 63 > q0 + w * 32);
      float pmax[2][4];
#pragma unroll
      for (int mi = 0; mi < 2; mi++)
#pragma unroll
        for (int i = 0; i < 4; i++) pmax[mi][i] = -__builtin_inff();
#pragma unroll
      for (int mi = 0; mi < 2; mi++)
#pragma unroll
        for (int nf = 0; nf < 4; nf++)
#pragma unroll
          for (int i = 0; i < 4; i++) {
            float xv = s[mi][nf][i];
            if (needmask) {
              const int qr = w * 32 + mi * 16 + lg * 4 + i;
              const int kc = nf * 16 + lr;
              if (kv0 + kc > q0 + qr) xv = -__builtin_inff();
            }
            s[mi][nf][i] = xv;
            pmax[mi][i] = fmaxf(pmax[mi][i], xv);
          }
#pragma unroll
      for (int m = 1; m < 16; m <<= 1)
#pragma unroll
        for (int mi = 0; mi < 2; mi++)
#pragma unroll
          for (int i = 0; i < 4; i++) pmax[mi][i] = fmaxf(pmax[mi][i], __shfl_xor(pmax[mi][i], m));

      float alpha[2][4], rsum[2][4];
#pragma unroll
      for (int mi = 0; mi < 2; mi++)
#pragma unroll
        for (int i = 0; i < 4; i++) {
          const float mn = fmaxf(mrun[mi][i], pmax[mi][i]);
          alpha[mi][i] = __expf(mrun[mi][i] - mn);
          mrun[mi][i] = mn;
          rsum[mi][i] = 0.f;
        }
#pragma unroll
      for (int mi = 0; mi < 2; mi++)
#pragma unroll
        for (int nf = 0; nf < 4; nf++)
#pragma unroll
          for (int i = 0; i < 4; i++) {
            const float p = __expf(s[mi][nf][i] - mrun[mi][i]);
            rsum[mi][i] += p;
            const int prow = mi * 16 + lg * 4 + i;
            plds[w][prow * 64 + ((nf * 16 + lr) ^ ((prow & 7) << 3))] = f2bf(p);
          }
#pragma unroll
      for (int m = 1; m < 16; m <<= 1)
#pragma unroll
        for (int mi = 0; mi < 2; mi++)
#pragma unroll
          for (int i = 0; i < 4; i++) rsum[mi][i] += __shfl_xor(rsum[mi][i], m);
#pragma unroll
      for (int mi = 0; mi < 2; mi++)
#pragma unroll
        for (int i = 0; i < 4; i++) lsum[mi][i] = lsum[mi][i] * alpha[mi][i] + rsum[mi][i];
#pragma unroll
      for (int mi = 0; mi < 2; mi++)
#pragma unroll
        for (int nf = 0; nf < 8; nf++)
#pragma unroll
          for (int i = 0; i < 4; i++) oacc[mi][nf][i] *= alpha[mi][i];

      __builtin_amdgcn_s_setprio(1);
#pragma unroll
      for (int kk = 0; kk < 2; kk++) {
        short8 pa[2];
#pragma unroll
        for (int mi = 0; mi < 2; mi++) {
          const int prow = mi * 16 + lr;
          pa[mi] = *(const short8*)&plds[w][prow * 64 + (((kk * 32 + lg * 8)) ^ ((prow & 7) << 3))];
        }
#pragma unroll
        for (int nf = 0; nf < 8; nf++) {
          const short8 vb = *(const short8*)&vt[buf][(nf * 16 + lr) * 64 + (((kk * 4 + lg) ^ (lr & 7)) << 3)];
#pragma unroll
          for (int mi = 0; mi < 2; mi++)
            oacc[mi][nf] = __builtin_amdgcn_mfma_f32_16x16x32_bf16(pa[mi], vb, oacc[mi][nf], 0, 0, 0);
        }
      }
      __builtin_amdgcn_s_setprio(0);
    }
    __syncthreads();
  }

  float rinv[2][4];
#pragma unroll
  for (int mi = 0; mi < 2; mi++)
#pragma unroll
    for (int i = 0; i < 4; i++) rinv[mi][i] = 1.f / lsum[mi][i];
#pragma unroll
  for (int mi = 0; mi < 2; mi++) {
    unsigned short* orow = out + ((size_t)b * T_ + q0 + w * 32 + mi * 16 + lg * 4) * D_ + h * DH_;
#pragma unroll
    for (int nf = 0; nf < 8; nf++)
#pragma unroll
      for (int i = 0; i < 4; i++)
        orow[(size_t)i * D_ + nf * 16 + lr] = f2bf(oacc[mi][nf][i] * rinv[mi][i]);
  }
}

extern "C" void kernel_launch(void* const* d_in, const int* in_sizes, int n_in,
                              void* d_out, int out_size, void* d_ws, size_t ws_size,
                              hipStream_t stream) {
  const float* x    = (const float*)d_in[0];
  const float* wqkv = (const float*)d_in[1];
  const float* wo   = (const float*)d_in[2];
  float* out = (float*)d_out;

  char* ws = (char*)d_ws;
  unsigned short* xb    = (unsigned short*)(ws);               // 16.8 MB (reused as attn out)
  unsigned short* wqkvt = (unsigned short*)(ws + 16777216);    // 25.2 MB (dead after gemm1)
  unsigned short* vtg   = (unsigned short*)(ws + 16777216);    // 16.8 MB, overlays wqkvt
  unsigned short* wot   = (unsigned short*)(ws + 41943040);    //  8.4 MB
  unsigned short* qkv   = (unsigned short*)(ws + 50331648);    // 50.3 MB  (end 100.7 MB)
  unsigned short* attn  = xb;   // xb dead after GEMM1

  convert_f32_bf16<<<2048, 256, 0, stream>>>(x, xb, B_ * T_ * D_ / 4);
  transpose_f32_bf16<<<dim3(TD3_ / 32, D_ / 32), 256, 0, stream>>>(wqkv, wqkvt, D_, TD3_);
  transpose_f32_bf16<<<dim3(D_ / 32, D_ / 32), 256, 0, stream>>>(wo, wot, D_, D_);

  gemm_qkv192<<<dim3(512), 512, 0, stream>>>(xb, wqkvt, qkv, B_ * T_, TD3_, D_);
  vtr_kernel<<<dim3(T_ / 64, H_ * 2, B_), 256, 0, stream>>>(qkv, vtg);
  attn_fa<<<dim3(T_ / 128, H_, B_), 256, 0, stream>>>(qkv, vtg, attn);
  gemm_op8<<<dim3(256), 512, 0, stream>>>(attn, wot, out, B_ * T_, D_, D_);
}

// Round 11
// 257.424 us; speedup vs baseline: 1.9894x; 1.1065x over previous
//
#include <hip/hip_runtime.h>
#include <hip/hip_bf16.h>

#define B_   2
#define T_   2048
#define D_   2048
#define H_   16
#define DH_  128
#define TD3_ 6144   // 3*D

typedef __attribute__((ext_vector_type(8))) short   short8;
typedef __attribute__((ext_vector_type(8))) unsigned short ushort8v;
typedef __attribute__((ext_vector_type(4))) float   f32x4;
typedef __attribute__((ext_vector_type(4))) float   f4v;
typedef __attribute__((ext_vector_type(4))) unsigned short u16x4;

static __device__ __forceinline__ unsigned short f2bf(float f) {
  unsigned int u = __builtin_bit_cast(unsigned int, f);
  u += 0x7FFFu + ((u >> 16) & 1u);
  return (unsigned short)(u >> 16);
}
static __device__ __forceinline__ float bf2f(unsigned short u) {
  return __builtin_bit_cast(float, (unsigned int)u << 16);
}
static __device__ __forceinline__ float fexp2(float x) {
  float r; asm("v_exp_f32 %0, %1" : "=v"(r) : "v"(x)); return r;
}

static __device__ __forceinline__ void gload_lds16(const unsigned short* g, unsigned short* l) {
  __builtin_amdgcn_global_load_lds((const __attribute__((address_space(1))) void*)g,
                                   (__attribute__((address_space(3))) void*)l, 16, 0, 0);
}

// ---------------- fp32 -> bf16 elementwise cast (vectorized) ----------------
__global__ __launch_bounds__(256) void convert_f32_bf16(const float* __restrict__ X,
                                                        unsigned short* __restrict__ Y, int n4) {
  for (int i = blockIdx.x * blockDim.x + threadIdx.x; i < n4; i += gridDim.x * blockDim.x) {
    f4v v = ((const f4v*)X)[i];
    u16x4 o;
    o[0] = f2bf(v[0]); o[1] = f2bf(v[1]); o[2] = f2bf(v[2]); o[3] = f2bf(v[3]);
    ((u16x4*)Y)[i] = o;
  }
}

// ---------------- transpose fp32 [K][N] -> bf16 [N][K] ----------------
__global__ __launch_bounds__(256) void transpose_f32_bf16(const float* __restrict__ W,
                                                          unsigned short* __restrict__ WT,
                                                          int K, int N) {
  __shared__ float tile[32][33];
  int n0 = blockIdx.x * 32, k0 = blockIdx.y * 32;
  int tx = threadIdx.x & 31, ty = threadIdx.x >> 5;
#pragma unroll
  for (int r = 0; r < 4; r++)
    tile[ty + 8 * r][tx] = W[(size_t)(k0 + ty + 8 * r) * N + n0 + tx];
  __syncthreads();
#pragma unroll
  for (int r = 0; r < 4; r++)
    WT[(size_t)(n0 + ty + 8 * r) * K + k0 + tx] = f2bf(tile[tx][ty + 8 * r]);
}

// ---------------- V transpose: qkv V-third [b][t][h*DH+dh] -> vtg [b][h][dh][t] ----------------
__global__ __launch_bounds__(256) void vtr_kernel(const unsigned short* __restrict__ qkv,
                                                  unsigned short* __restrict__ vtg) {
  __shared__ unsigned short tile[64][68];
  const int t0 = blockIdx.x * 64;
  const int h = blockIdx.y >> 1, dh0 = (blockIdx.y & 1) * 64;
  const int b = blockIdx.z;
  const int tid = threadIdx.x;
  const unsigned short* src = qkv + (size_t)b * T_ * TD3_ + 2 * D_ + h * DH_ + dh0;
  {
    const int r = tid >> 3, cc = (tid & 7) * 8;
#pragma unroll
    for (int k = 0; k < 2; k++) {
      ushort8v v = *(const ushort8v*)(src + (size_t)(t0 + k * 32 + r) * TD3_ + cc);
      *(ushort8v*)&tile[k * 32 + r][cc] = v;
    }
  }
  __syncthreads();
  unsigned short* dst = vtg + ((size_t)(b * H_ + h) * DH_ + dh0) * T_ + t0;
  {
    const int d = tid >> 3, tc = (tid & 7) * 8;
#pragma unroll
    for (int k = 0; k < 2; k++) {
      ushort8v v;
#pragma unroll
      for (int j = 0; j < 8; j++) v[j] = tile[tc + j][k * 32 + d];
      *(ushort8v*)(dst + (size_t)(k * 32 + d) * T_ + tc) = v;
    }
  }
}

// ---------------- 256x192 2-phase software-pipelined bf16 GEMM (QKV): C bf16 ----------------
__global__ __launch_bounds__(512, 1) void gemm_qkv192(const unsigned short* __restrict__ A,
                                                      const unsigned short* __restrict__ BT,
                                                      unsigned short* __restrict__ C,
                                                      int M, int N, int K) {
  __shared__ unsigned short lA[2][2][128 * 64];   // 64 KiB
  __shared__ unsigned short lB[2][192 * 64];      // 48 KiB

  const int tid = threadIdx.x;
  const int bid = (int)blockIdx.x;
  const int npx = 4;                              // n-tiles per XCD
  const int xcd = bid & 7, idx = bid >> 3;
  const int n0 = (xcd * npx + (idx & 3)) * 192;
  const int m0 = (idx >> 2) * 256;
  const int l = tid & 63, lr = l & 15, lg = l >> 4;
  const int wid = tid >> 6, wm = wid >> 2, wn = wid & 3;
  const int nk = K >> 6;                          // 32 (even; kt+=2 unroll relies on it)

  f32x4 acc[8][3] = {};
  short8 aQ0[4][2], aQ1[4][2], bX[3][2], bY[3][2];

  auto stageA = [&](int buf, int h, int kt) {
#pragma unroll
    for (int q = 0; q < 2; q++) {
      const int n = q * 512 + tid;
      const int row = n >> 3, ch = n & 7;
      gload_lds16(A + (size_t)(m0 + h * 128 + row) * K + kt * 64 + ((ch ^ (row & 7)) << 3),
                  &lA[buf][h][n * 8]);
    }
  };
  auto stageBt = [&](int buf, int third, int kt) {
    const int r = tid >> 3, ch = tid & 7;
    gload_lds16(BT + (size_t)(n0 + third * 64 + r) * K + kt * 64 + ((ch ^ (r & 7)) << 3),
                &lB[buf][third * 4096 + tid * 8]);
  };

#define QKV_STAGE_ALL(BUF, TT)                                                  \
  { stageA(BUF, 0, TT); stageA(BUF, 1, TT);                                     \
    stageBt(BUF, 0, TT); stageBt(BUF, 1, TT); stageBt(BUF, 2, TT); }

#define QKV_READ_A(DST, BUF, QUAD)                                              \
  _Pragma("unroll")                                                             \
  for (int mi = 0; mi < 4; mi++)                                                \
    _Pragma("unroll")                                                           \
    for (int kk = 0; kk < 2; kk++) {                                            \
      const int row = ((QUAD) * 4 + mi) * 16 + lr;                              \
      DST[mi][kk] = *(const short8*)&lA[BUF][wm][row * 64 +                     \
                      (((kk * 4 + lg) ^ (lr & 7)) << 3)];                       \
    }

#define QKV_READ_B(DST, BUF)                                                    \
  _Pragma("unroll")                                                             \
  for (int ni = 0; ni < 3; ni++)                                                \
    _Pragma("unroll")                                                           \
    for (int kk = 0; kk < 2; kk++) {                                            \
      const int row = wn * 48 + ni * 16 + lr;                                   \
      DST[ni][kk] = *(const short8*)&lB[BUF][row * 64 +                         \
                      (((kk * 4 + lg) ^ (lr & 7)) << 3)];                       \
    }

#define QKV_PHASE_A(BUF, BCUR, TT)                                              \
  {                                                                             \
    if ((TT) + 1 < nk) QKV_STAGE_ALL(1 - (BUF), (TT) + 1);                      \
    QKV_READ_A(aQ1, BUF, 1)                                                     \
    __builtin_amdgcn_s_setprio(1);                                              \
    _Pragma("unroll")                                                           \
    for (int mi = 0; mi < 4; mi++)                                              \
      _Pragma("unroll")                                                         \
      for (int ni = 0; ni < 3; ni++)                                            \
        _Pragma("unroll")                                                       \
        for (int kk = 0; kk < 2; kk++)                                          \
          acc[mi][ni] = __builtin_amdgcn_mfma_f32_16x16x32_bf16(                \
              aQ0[mi][kk], BCUR[ni][kk], acc[mi][ni], 0, 0, 0);                 \
    __builtin_amdgcn_s_setprio(0);                                              \
    __builtin_amdgcn_s_barrier();                                               \
  }

#define QKV_PHASE_B(BUF, BCUR, BNXT, TT)                                        \
  {                                                                             \
    __builtin_amdgcn_s_setprio(1);                                              \
    _Pragma("unroll")                                                           \
    for (int mi = 0; mi < 4; mi++)                                              \
      _Pragma("unroll")                                                         \
      for (int ni = 0; ni < 2; ni++)                                            \
        _Pragma("unroll")                                                       \
        for (int kk = 0; kk < 2; kk++)                                          \
          acc[4 + mi][ni] = __builtin_amdgcn_mfma_f32_16x16x32_bf16(            \
              aQ1[mi][kk], BCUR[ni][kk], acc[4 + mi][ni], 0, 0, 0);             \
    __builtin_amdgcn_s_setprio(0);                                              \
    asm volatile("s_waitcnt vmcnt(0)" ::: "memory");                            \
    __builtin_amdgcn_s_barrier();                                               \
    if ((TT) + 1 < nk) {                                                        \
      QKV_READ_A(aQ0, 1 - (BUF), 0)                                             \
      QKV_READ_B(BNXT, 1 - (BUF))                                               \
    }                                                                           \
    __builtin_amdgcn_s_setprio(1);                                              \
    _Pragma("unroll")                                                           \
    for (int mi = 0; mi < 4; mi++)                                              \
      _Pragma("unroll")                                                         \
      for (int kk = 0; kk < 2; kk++)                                            \
        acc[4 + mi][2] = __builtin_amdgcn_mfma_f32_16x16x32_bf16(               \
            aQ1[mi][kk], BCUR[2][kk], acc[4 + mi][2], 0, 0, 0);                 \
    __builtin_amdgcn_s_setprio(0);                                              \
    __builtin_amdgcn_s_barrier();                                               \
  }

  // ---- prologue ----
  QKV_STAGE_ALL(0, 0)
  asm volatile("s_waitcnt vmcnt(0)" ::: "memory");
  __builtin_amdgcn_s_barrier();
  QKV_READ_A(aQ0, 0, 0)
  QKV_READ_B(bX, 0)

  for (int kt = 0; kt < nk; kt += 2) {
    QKV_PHASE_A(0, bX, kt)
    QKV_PHASE_B(0, bX, bY, kt)
    QKV_PHASE_A(1, bY, kt + 1)
    QKV_PHASE_B(1, bY, bX, kt + 1)
  }

#pragma unroll
  for (int mi = 0; mi < 8; mi++)
#pragma unroll
    for (int ni = 0; ni < 3; ni++)
#pragma unroll
      for (int i = 0; i < 4; i++) {
        const int row = m0 + wm * 128 + mi * 16 + lg * 4 + i;
        const int col = n0 + wn * 48 + ni * 16 + lr;
        C[(size_t)row * N + col] = f2bf(acc[mi][ni][i]);
      }
#undef QKV_PHASE_B
#undef QKV_PHASE_A
#undef QKV_READ_B
#undef QKV_READ_A
#undef QKV_STAGE_ALL
}

// ---------------- 128x256 8-phase bf16 GEMM (output proj): C fp32 ----------------
__global__ __launch_bounds__(512, 1) void gemm_op8(const unsigned short* __restrict__ A,
                                                   const unsigned short* __restrict__ BT,
                                                   float* __restrict__ C,
                                                   int M, int N, int K) {
  __shared__ unsigned short lA[2][128 * 64];      // 32 KiB
  __shared__ unsigned short lB[2][2][128 * 64];   // 64 KiB

  const int tid = threadIdx.x;
  const int bid = (int)blockIdx.x;
  const int xcd = bid & 7, idx = bid >> 3;
  const int n0 = xcd * 256, m0 = idx * 128;
  const int l = tid & 63, lr = l & 15, lg = l >> 4;
  const int wid = tid >> 6, wm = wid >> 2, wn = wid & 3;
  const int bh = wn >> 1, br0 = (wn & 1) * 64;
  const int nk = K >> 6;

  f32x4 acc[4][4] = {};

  auto stageA = [&](int buf, int kt) {
#pragma unroll
    for (int q = 0; q < 2; q++) {
      const int n = q * 512 + tid;
      const int row = n >> 3, ch = n & 7;
      gload_lds16(A + (size_t)(m0 + row) * K + kt * 64 + ((ch ^ (row & 7)) << 3),
                  &lA[buf][n * 8]);
    }
  };
  auto stageB = [&](int buf, int h, int kt) {
#pragma unroll
    for (int q = 0; q < 2; q++) {
      const int n = q * 512 + tid;
      const int row = n >> 3, ch = n & 7;
      gload_lds16(BT + (size_t)(n0 + h * 128 + row) * K + kt * 64 + ((ch ^ (row & 7)) << 3),
                  &lB[buf][h][n * 8]);
    }
  };

  stageB(0, 0, 0); stageB(0, 1, 0); stageA(0, 0);
  if (nk > 1) {
    stageB(1, 0, 1); stageB(1, 1, 1); stageA(1, 1);
    asm volatile("s_waitcnt vmcnt(6)" ::: "memory");
  } else {
    asm volatile("s_waitcnt vmcnt(0)" ::: "memory");
  }
  __builtin_amdgcn_s_barrier();

  short8 a[2][2], b0[2][2], b1[2][2];
  for (int kt = 0; kt < nk; kt++) {
    const int buf = kt & 1;

#pragma unroll
    for (int mi = 0; mi < 2; mi++)
#pragma unroll
      for (int kk = 0; kk < 2; kk++) {
        const int row = wm * 64 + mi * 16 + lr;
        a[mi][kk] = *(const short8*)&lA[buf][row * 64 + (((kk * 4 + lg) ^ (lr & 7)) << 3)];
      }
#pragma unroll
    for (int ni = 0; ni < 2; ni++)
#pragma unroll
      for (int kk = 0; kk < 2; kk++) {
        const int row = br0 + ni * 16 + lr;
        b0[ni][kk] = *(const short8*)&lB[buf][bh][row * 64 + (((kk * 4 + lg) ^ (lr & 7)) << 3)];
      }
    __builtin_amdgcn_s_barrier();
    __builtin_amdgcn_s_setprio(1);
#pragma unroll
    for (int mi = 0; mi < 2; mi++)
#pragma unroll
      for (int ni = 0; ni < 2; ni++)
#pragma unroll
        for (int kk = 0; kk < 2; kk++)
          acc[mi][ni] = __builtin_amdgcn_mfma_f32_16x16x32_bf16(a[mi][kk], b0[ni][kk], acc[mi][ni], 0, 0, 0);
    __builtin_amdgcn_s_setprio(0);
    __builtin_amdgcn_s_barrier();

#pragma unroll
    for (int ni = 0; ni < 2; ni++)
#pragma unroll
      for (int kk = 0; kk < 2; kk++) {
        const int row = br0 + (2 + ni) * 16 + lr;
        b1[ni][kk] = *(const short8*)&lB[buf][bh][row * 64 + (((kk * 4 + lg) ^ (lr & 7)) << 3)];
      }
    __builtin_amdgcn_s_barrier();
    __builtin_amdgcn_s_setprio(1);
#pragma unroll
    for (int mi = 0; mi < 2; mi++)
#pragma unroll
      for (int ni = 0; ni < 2; ni++)
#pragma unroll
        for (int kk = 0; kk < 2; kk++)
          acc[mi][2 + ni] = __builtin_amdgcn_mfma_f32_16x16x32_bf16(a[mi][kk], b1[ni][kk], acc[mi][2 + ni], 0, 0, 0);
    __builtin_amdgcn_s_setprio(0);
    __builtin_amdgcn_s_barrier();

#pragma unroll
    for (int mi = 0; mi < 2; mi++)
#pragma unroll
      for (int kk = 0; kk < 2; kk++) {
        const int row = wm * 64 + (2 + mi) * 16 + lr;
        a[mi][kk] = *(const short8*)&lA[buf][row * 64 + (((kk * 4 + lg) ^ (lr & 7)) << 3)];
      }
    if (kt + 2 < nk) stageB(buf, 0, kt + 2);
    __builtin_amdgcn_s_barrier();
    __builtin_amdgcn_s_setprio(1);
#pragma unroll
    for (int mi = 0; mi < 2; mi++)
#pragma unroll
      for (int ni = 0; ni < 2; ni++)
#pragma unroll
        for (int kk = 0; kk < 2; kk++)
          acc[2 + mi][2 + ni] = __builtin_amdgcn_mfma_f32_16x16x32_bf16(a[mi][kk], b1[ni][kk], acc[2 + mi][2 + ni], 0, 0, 0);
    __builtin_amdgcn_s_setprio(0);
    __builtin_amdgcn_s_barrier();

    if (kt + 2 < nk) { stageB(buf, 1, kt + 2); stageA(buf, kt + 2); }
    __builtin_amdgcn_s_barrier();
    __builtin_amdgcn_s_setprio(1);
#pragma unroll
    for (int mi = 0; mi < 2; mi++)
#pragma unroll
      for (int ni = 0; ni < 2; ni++)
#pragma unroll
        for (int kk = 0; kk < 2; kk++)
          acc[2 + mi][ni] = __builtin_amdgcn_mfma_f32_16x16x32_bf16(a[mi][kk], b0[ni][kk], acc[2 + mi][ni], 0, 0, 0);
    __builtin_amdgcn_s_setprio(0);
    if (kt + 2 < nk) asm volatile("s_waitcnt vmcnt(6)" ::: "memory");
    else             asm volatile("s_waitcnt vmcnt(0)" ::: "memory");
    __builtin_amdgcn_s_barrier();
  }

#pragma unroll
  for (int mi = 0; mi < 4; mi++)
#pragma unroll
    for (int ni = 0; ni < 4; ni++)
#pragma unroll
      for (int i = 0; i < 4; i++) {
        const int row = m0 + wm * 64 + mi * 16 + lg * 4 + i;
        const int col = n0 + wn * 64 + ni * 16 + lr;
        C[(size_t)row * N + col] = acc[mi][ni][i];
      }
}

// ---------------- flash attention (causal), QBLK=128, KVBLK=64, 2-phase pipeline ----------------
// Softmax in exp2 domain (Q pre-scaled by 1/sqrt(DH)*log2e); defer-max (THR=8);
// per-lane rsum accumulated across tiles, reduced once at the end.
__global__ __launch_bounds__(256, 2) void attn_fa(const unsigned short* __restrict__ qkv,
                                                  const unsigned short* __restrict__ vtg,
                                                  unsigned short* __restrict__ out) {
  const int x = blockIdx.x, h = blockIdx.y, b = blockIdx.z;
  const int qtl = b ? x : (T_ / 128 - 1 - x);
  const int q0 = qtl * 128;
  const int tid = threadIdx.x, w = tid >> 6, l = tid & 63, lr = l & 15, lg = l >> 4;

  const unsigned short* Qb = qkv + (size_t)b * T_ * TD3_ + h * DH_;
  const unsigned short* Kb = Qb + D_;
  const unsigned short* Vt = vtg + ((size_t)b * H_ + h) * DH_ * T_;

  __shared__ unsigned short klds[2][64 * 128];
  __shared__ unsigned short vt[2][128 * 64];
  __shared__ unsigned short plds[4][32 * 64];

  const float scale2 = 0.12751744519764462f;     // log2(e)/sqrt(128)

  short8 qf[2][4];
#pragma unroll
  for (int mi = 0; mi < 2; mi++) {
    const unsigned short* qrow = Qb + (size_t)(q0 + w * 32 + mi * 16 + lr) * TD3_;
#pragma unroll
    for (int ks = 0; ks < 4; ks++) {
      ushort8v qv = *(const ushort8v*)(qrow + ks * 32 + lg * 8);
      short8 qs;
#pragma unroll
      for (int j = 0; j < 8; j++) qs[j] = (short)f2bf(bf2f(qv[j]) * scale2);
      qf[mi][ks] = qs;
    }
  }

  f32x4 oacc[2][8] = {};
  float mrun[2][4], rsuml[2][4];
#pragma unroll
  for (int mi = 0; mi < 2; mi++)
#pragma unroll
    for (int i = 0; i < 4; i++) { mrun[mi][i] = -__builtin_inff(); rsuml[mi][i] = 0.f; }

  auto STAGE = [&](int buf, int kv0) {
#pragma unroll
    for (int it = 0; it < 4; it++) {
      const int n = it * 256 + tid;
      { const int kv = n >> 4, ch = n & 15;
        gload_lds16(Kb + (size_t)(kv0 + kv) * TD3_ + ((ch ^ (kv & 7)) << 3),
                    &klds[buf][n * 8]); }
      { const int dh = n >> 3, ch = n & 7;
        gload_lds16(Vt + (size_t)dh * T_ + kv0 + ((ch ^ (dh & 7)) << 3),
                    &vt[buf][n * 8]); }
    }
  };

  const int nt = 2 * qtl + 2;
  STAGE(0, 0);
  __syncthreads();

  for (int t = 0; t < nt; t++) {
    const int buf = t & 1;
    if (t + 1 < nt) STAGE(buf ^ 1, (t + 1) * 64);

    const int kv0 = t * 64;
    const bool active = (kv0 <= q0 + w * 32 + 31);
    if (active) {
      // ---- S = Q K^T (log2 domain) ----
      f32x4 s[2][4] = {};
      __builtin_amdgcn_s_setprio(1);
#pragma unroll
      for (int nf = 0; nf < 4; nf++) {
        const int kv = nf * 16 + lr;
#pragma unroll
        for (int ks = 0; ks < 4; ks++) {
          short8 kf = *(const short8*)&klds[buf][kv * 128 + (((ks * 4 + lg) ^ (lr & 7)) << 3)];
#pragma unroll
          for (int mi = 0; mi < 2; mi++)
            s[mi][nf] = __builtin_amdgcn_mfma_f32_16x16x32_bf16(qf[mi][ks], kf, s[mi][nf], 0, 0, 0);
        }
      }
      __builtin_amdgcn_s_setprio(0);

      // ---- causal mask + per-lane max ----
      const bool needmask = (kv0 + 63 > q0 + w * 32);
      float pmax[2][4];
#pragma unroll
      for (int mi = 0; mi < 2; mi++)
#pragma unroll
        for (int i = 0; i < 4; i++) pmax[mi][i] = -__builtin_inff();
#pragma unroll
      for (int mi = 0; mi < 2; mi++)
#pragma unroll
        for (int nf = 0; nf < 4; nf++)
#pragma unroll
          for (int i = 0; i < 4; i++) {
            float xv = s[mi][nf][i];
            if (needmask) {
              const int qr = w * 32 + mi * 16 + lg * 4 + i;
              const int kc = nf * 16 + lr;
              if (kv0 + kc > q0 + qr) xv = -__builtin_inff();
            }
            s[mi][nf][i] = xv;
            pmax[mi][i] = fmaxf(pmax[mi][i], xv);
          }

      // ---- defer-max: only rescale when some lane's max grew past THR ----
      int ok = 1;
#pragma unroll
      for (int mi = 0; mi < 2; mi++)
#pragma unroll
        for (int i = 0; i < 4; i++)
          ok &= (pmax[mi][i] <= mrun[mi][i] + 8.0f) ? 1 : 0;

      if (!__all(ok)) {
#pragma unroll
        for (int m = 1; m < 16; m <<= 1)
#pragma unroll
          for (int mi = 0; mi < 2; mi++)
#pragma unroll
            for (int i = 0; i < 4; i++)
              pmax[mi][i] = fmaxf(pmax[mi][i], __shfl_xor(pmax[mi][i], m));
#pragma unroll
        for (int mi = 0; mi < 2; mi++)
#pragma unroll
          for (int i = 0; i < 4; i++) {
            const float mn = fmaxf(mrun[mi][i], pmax[mi][i]);
            const float al = fexp2(mrun[mi][i] - mn);
            mrun[mi][i] = mn;
            rsuml[mi][i] *= al;
#pragma unroll
            for (int nf = 0; nf < 8; nf++) oacc[mi][nf][i] *= al;
          }
      }

      // ---- P = exp2(S - m); per-lane rsum; P -> LDS ----
#pragma unroll
      for (int mi = 0; mi < 2; mi++)
#pragma unroll
        for (int nf = 0; nf < 4; nf++)
#pragma unroll
          for (int i = 0; i < 4; i++) {
            const float p = fexp2(s[mi][nf][i] - mrun[mi][i]);
            rsuml[mi][i] += p;
            const int prow = mi * 16 + lg * 4 + i;
            plds[w][prow * 64 + ((nf * 16 + lr) ^ ((prow & 7) << 3))] = f2bf(p);
          }

      // ---- O += P V ----
      __builtin_amdgcn_s_setprio(1);
#pragma unroll
      for (int kk = 0; kk < 2; kk++) {
        short8 pa[2];
#pragma unroll
        for (int mi = 0; mi < 2; mi++) {
          const int prow = mi * 16 + lr;
          pa[mi] = *(const short8*)&plds[w][prow * 64 + (((kk * 32 + lg * 8)) ^ ((prow & 7) << 3))];
        }
#pragma unroll
        for (int nf = 0; nf < 8; nf++) {
          const short8 vb = *(const short8*)&vt[buf][(nf * 16 + lr) * 64 + (((kk * 4 + lg) ^ (lr & 7)) << 3)];
#pragma unroll
          for (int mi = 0; mi < 2; mi++)
            oacc[mi][nf] = __builtin_amdgcn_mfma_f32_16x16x32_bf16(pa[mi], vb, oacc[mi][nf], 0, 0, 0);
        }
      }
      __builtin_amdgcn_s_setprio(0);
    }
    __syncthreads();
  }

  // ---- final rsum reduce + normalize + write ----
#pragma unroll
  for (int m = 1; m < 16; m <<= 1)
#pragma unroll
    for (int mi = 0; mi < 2; mi++)
#pragma unroll
      for (int i = 0; i < 4; i++) rsuml[mi][i] += __shfl_xor(rsuml[mi][i], m);

  float rinv[2][4];
#pragma unroll
  for (int mi = 0; mi < 2; mi++)
#pragma unroll
    for (int i = 0; i < 4; i++) rinv[mi][i] = 1.f / rsuml[mi][i];
#pragma unroll
  for (int mi = 0; mi < 2; mi++) {
    unsigned short* orow = out + ((size_t)b * T_ + q0 + w * 32 + mi * 16 + lg * 4) * D_ + h * DH_;
#pragma unroll
    for (int nf = 0; nf < 8; nf++)
#pragma unroll
      for (int i = 0; i < 4; i++)
        orow[(size_t)i * D_ + nf * 16 + lr] = f2bf(oacc[mi][nf][i] * rinv[mi][i]);
  }
}

extern "C" void kernel_launch(void* const* d_in, const int* in_sizes, int n_in,
                              void* d_out, int out_size, void* d_ws, size_t ws_size,
                              hipStream_t stream) {
  const float* x    = (const float*)d_in[0];
  const float* wqkv = (const float*)d_in[1];
  const float* wo   = (const float*)d_in[2];
  float* out = (float*)d_out;

  char* ws = (char*)d_ws;
  unsigned short* xb    = (unsigned short*)(ws);               // 16.8 MB (reused as attn out)
  unsigned short* wqkvt = (unsigned short*)(ws + 16777216);    // 25.2 MB (dead after gemm1)
  unsigned short* vtg   = (unsigned short*)(ws + 16777216);    // 16.8 MB, overlays wqkvt
  unsigned short* wot   = (unsigned short*)(ws + 41943040);    //  8.4 MB
  unsigned short* qkv   = (unsigned short*)(ws + 50331648);    // 50.3 MB  (end 100.7 MB)
  unsigned short* attn  = xb;   // xb dead after GEMM1

  convert_f32_bf16<<<2048, 256, 0, stream>>>(x, xb, B_ * T_ * D_ / 4);
  transpose_f32_bf16<<<dim3(TD3_ / 32, D_ / 32), 256, 0, stream>>>(wqkv, wqkvt, D_, TD3_);
  transpose_f32_bf16<<<dim3(D_ / 32, D_ / 32), 256, 0, stream>>>(wo, wot, D_, D_);

  gemm_qkv192<<<dim3(512), 512, 0, stream>>>(xb, wqkvt, qkv, B_ * T_, TD3_, D_);
  vtr_kernel<<<dim3(T_ / 64, H_ * 2, B_), 256, 0, stream>>>(qkv, vtg);
  attn_fa<<<dim3(T_ / 128, H_, B_), 256, 0, stream>>>(qkv, vtg, attn);
  gemm_op8<<<dim3(256), 512, 0, stream>>>(attn, wot, out, B_ * T_, D_, D_);
}